// Round 6
// baseline (387.548 us; speedup 1.0000x reference)
//
#include <hip/hip_runtime.h>

typedef unsigned short u16;
typedef unsigned int u32;
typedef unsigned long long u64;
typedef __attribute__((ext_vector_type(8))) short short8;
typedef __attribute__((ext_vector_type(4))) float float4v;

#define MFMA16(a, b, c) __builtin_amdgcn_mfma_f32_16x16x32_bf16((a), (b), (c), 0, 0, 0)

// ---------------- helpers ----------------
__device__ __forceinline__ u16 f2b(float x) {
    union { float f; unsigned u; } v; v.f = x;
    unsigned r = v.u + 0x7FFFu + ((v.u >> 16) & 1u);   // RNE
    return (u16)(r >> 16);
}
__device__ __forceinline__ float b2f(u16 u) {
    union { unsigned u; float f; } v; v.u = ((unsigned)u) << 16; return v.f;
}
// pack 2 f32 -> 2 bf16 (RNE) in one instruction
__device__ __forceinline__ u32 cvtpk(float lo, float hi) {
    u32 r;
    asm("v_cvt_pk_bf16_f32 %0, %1, %2" : "=v"(r) : "v"(lo), "v"(hi));
    return r;
}

// constants
#define NH 16
#define S  2048
#define HD 64
#define H  1024
// scale = 1/sqrt(192) * log2(e)  (exp -> exp2 folded into all score terms)
#define SC 0.10412111829775301f

// ---------------- workspace offsets (bytes) ----------------
#define OFF_REB   0ull
#define OFF_HSB   (OFF_REB  + 1048576ull)
#define OFF_WT    (OFF_HSB  + 8388608ull)
#define OFF_QB    (OFF_WT   + 12582912ull)
#define OFF_KB    (OFF_QB   + 8388608ull)
#define OFF_VT    (OFF_KB   + 8388608ull)
#define OFF_PKB   (OFF_VT   + 8388608ull)
#define OFF_PQB   (OFF_PKB  + 1048576ull)
#define OFF_C2P   (OFF_PQB  + 1048576ull)                // 64 MB [bh][q][512]
#define OFF_P2CK  (OFF_C2P  + 67108864ull)               // 64 MB [bh][k][512]  (k-major)
#define OFF_CTX   (OFF_P2CK + 67108864ull)
#define OFF_IDX   (OFF_CTX  + 8388608ull)                // 1344-entry extended idx table
#define OFF_PF    (OFF_IDX  + 8192ull)                   // far columns [2][32][2048] u16 = 256 KB
#define OFF_SP    (OFF_PF   + 262144ull)                 // split-K partials
#define SP_OHALF  4194304ull                             // floats per half (32*2048*64)
#define SP_LBASE  (OFF_SP + 67108864ull)
#define SP_LHALF  65536ull
#define WS_NEED_SPLIT (SP_LBASE + 524288ull)             // ~248.5 MB

// ---------------- extended idx table for rel in [-704, 640) ----------------
// idx monotone nondecreasing, slope <= 1; clamping rel to [-512,511] is EXACT,
// so the extension rows just repeat the clamped value -> no clamp needed at use site.
__global__ void k_build_idx(short* __restrict__ t) {
    int i = blockIdx.x * 256 + threadIdx.x;
    if (i >= 1344) return;
    int rel = i - 704;
    rel = rel < -512 ? -512 : (rel > 511 ? 511 : rel);
    float fr = (float)rel;
    float abs_pos = (rel < 128 && rel > -128) ? 127.0f : fabsf(fr);
    const float LOGC = 1.3843393262841284f;  // float32(ln(511/128))
    float log_pos = ceilf(logf(abs_pos * (1.0f / 128.0f)) / LOGC * 127.0f) + 128.0f;
    float sgn = (fr > 0.f) ? 1.f : ((fr < 0.f) ? -1.f : 0.f);
    float bf = (abs_pos <= 128.0f) ? fr : log_pos * sgn;
    int idx = (int)bf + 256;
    idx = idx < 0 ? 0 : (idx > 511 ? 511 : idx);
    t[i] = (short)idx;
}

// ---------------- LayerNorm of rel_emb -> bf16 ----------------
__global__ __launch_bounds__(256) void k_ln(const float* __restrict__ re,
                                            const float* __restrict__ g,
                                            const float* __restrict__ be,
                                            u16* __restrict__ out) {
    int row = blockIdx.x;
    const float4* x4 = (const float4*)(re + (size_t)row * H);
    int tid = threadIdx.x;
    float4 vv = x4[tid];
    float s = vv.x + vv.y + vv.z + vv.w;
    float s2 = vv.x * vv.x + vv.y * vv.y + vv.z * vv.z + vv.w * vv.w;
    for (int m = 1; m < 64; m <<= 1) {
        s += __shfl_xor(s, m, 64);
        s2 += __shfl_xor(s2, m, 64);
    }
    __shared__ float as[4], as2[4];
    if ((tid & 63) == 0) { as[tid >> 6] = s; as2[tid >> 6] = s2; }
    __syncthreads();
    s = as[0] + as[1] + as[2] + as[3];
    s2 = as2[0] + as2[1] + as2[2] + as2[3];
    float mu = s * (1.f / 1024.f);
    float var = s2 * (1.f / 1024.f) - mu * mu;
    float rstd = rsqrtf(var + 1e-5f);
    float4 gg = ((const float4*)g)[tid];
    float4 bb = ((const float4*)be)[tid];
    ushort4 r4;
    r4.x = f2b((vv.x - mu) * rstd * gg.x + bb.x);
    r4.y = f2b((vv.y - mu) * rstd * gg.y + bb.y);
    r4.z = f2b((vv.z - mu) * rstd * gg.z + bb.z);
    r4.w = f2b((vv.w - mu) * rstd * gg.w + bb.w);
    ((ushort4*)(out + (size_t)row * H))[tid] = r4;
}

// ---------------- fp32 -> bf16 cast ----------------
__global__ __launch_bounds__(256) void k_cast(const float* __restrict__ x, u16* __restrict__ y) {
    int i = blockIdx.x * 256 + threadIdx.x;
    float4 v = ((const float4*)x)[i];
    ushort4 r;
    r.x = f2b(v.x); r.y = f2b(v.y); r.z = f2b(v.z); r.w = f2b(v.w);
    ((ushort4*)y)[i] = r;
}

// ---------------- 6x weight transpose + cast ----------------
__global__ __launch_bounds__(256) void k_wt6(const float* __restrict__ W0, const float* __restrict__ W1,
                                             const float* __restrict__ W2, const float* __restrict__ W3,
                                             const float* __restrict__ W4, const float* __restrict__ W5,
                                             u16* __restrict__ T0, u16* __restrict__ T1,
                                             u16* __restrict__ T2, u16* __restrict__ T3,
                                             u16* __restrict__ T4, u16* __restrict__ T5) {
    const float* W; u16* WT;
    switch (blockIdx.z) {
        case 0: W = W0; WT = T0; break;
        case 1: W = W1; WT = T1; break;
        case 2: W = W2; WT = T2; break;
        case 3: W = W3; WT = T3; break;
        case 4: W = W4; WT = T4; break;
        default: W = W5; WT = T5; break;
    }
    __shared__ float t[64][65];
    int k0 = blockIdx.x * 64, n0 = blockIdx.y * 64;
    int tid = threadIdx.x;
#pragma unroll
    for (int i = 0; i < 16; i++) {
        int lin = tid + 256 * i;
        int r = lin >> 6, c = lin & 63;
        t[r][c] = W[(size_t)(k0 + r) * H + n0 + c];
    }
    __syncthreads();
#pragma unroll
    for (int i = 0; i < 16; i++) {
        int lin = tid + 256 * i;
        int r = lin >> 6, c = lin & 63;
        WT[(size_t)(n0 + r) * H + k0 + c] = f2b(t[c][r]);
    }
}

// ---------------- 128x128-tile GEMM core ----------------
// MODE 0: bf16 row-major; MODE 1: f32 row-major;
// MODE 2: bf16 VT layout (b*1024+n)*2048 + pi2-permuted s within each 64-block
//         (pi2(j) = (j>>5)*32 + (j&15)*2 + ((j>>4)&1); k_attn's P store and PV MFMA
//          use the same permuted k-order, and MFMA sums over k, so this is exact);
// MODE 3: bf16 head-major ((b*16+h)*2048+m)*64+d
template <int MODE>
__device__ __forceinline__ void gemm2_body(const u16* __restrict__ A,
                                           const u16* __restrict__ Bt,
                                           const float* __restrict__ bias,
                                           void* __restrict__ C, int N, int K) {
    __shared__ __align__(16) u16 As[128 * 32];
    __shared__ __align__(16) u16 Bs[128 * 32];
    int tid = threadIdx.x;
    int lane = tid & 63, w = tid >> 6;
    int ln = lane & 15, quad = lane >> 4;
    int m0 = blockIdx.x * 128, n0 = blockIdx.y * 128;
    int wm = (w >> 1) * 64, wn = (w & 1) * 64;
    float4v acc[4][4];
    float4v zero = {0.f, 0.f, 0.f, 0.f};
#pragma unroll
    for (int mi = 0; mi < 4; mi++)
#pragma unroll
        for (int ni = 0; ni < 4; ni++) acc[mi][ni] = zero;

    int r1 = tid >> 2, o1 = (tid & 3) * 8;
    const u16* ga1 = A + (size_t)(m0 + r1) * K + o1;
    const u16* gb1 = Bt + (size_t)(n0 + r1) * K + o1;
    u16* sa1 = &As[r1 * 32 + o1];
    u16* sb1 = &Bs[r1 * 32 + o1];
    size_t step2 = (size_t)64 * K;

    for (int k0 = 0; k0 < K; k0 += 32) {
        short8 va1 = *(const short8*)(ga1 + k0);
        short8 va2 = *(const short8*)(ga1 + step2 + k0);
        short8 vb1 = *(const short8*)(gb1 + k0);
        short8 vb2 = *(const short8*)(gb1 + step2 + k0);
        __syncthreads();
        *(short8*)sa1 = va1; *(short8*)(sa1 + 2048) = va2;
        *(short8*)sb1 = vb1; *(short8*)(sb1 + 2048) = vb2;
        __syncthreads();
        short8 af[4], bf[4];
#pragma unroll
        for (int mi = 0; mi < 4; mi++)
            af[mi] = *(const short8*)&As[(wm + mi * 16 + ln) * 32 + quad * 8];
#pragma unroll
        for (int ni = 0; ni < 4; ni++)
            bf[ni] = *(const short8*)&Bs[(wn + ni * 16 + ln) * 32 + quad * 8];
#pragma unroll
        for (int mi = 0; mi < 4; mi++)
#pragma unroll
            for (int ni = 0; ni < 4; ni++)
                acc[mi][ni] = MFMA16(af[mi], bf[ni], acc[mi][ni]);
    }

#pragma unroll
    for (int mi = 0; mi < 4; mi++) {
        int row0 = m0 + wm + mi * 16 + quad * 4;
#pragma unroll
        for (int ni = 0; ni < 4; ni++) {
            int col = n0 + wn + ni * 16 + ln;
            float bv = bias[col];
            if (MODE == 0) {
                u16* Cb = (u16*)C;
#pragma unroll
                for (int r = 0; r < 4; r++)
                    Cb[(size_t)(row0 + r) * N + col] = f2b(acc[mi][ni][r] + bv);
            } else if (MODE == 1) {
                float* Cf = (float*)C;
#pragma unroll
                for (int r = 0; r < 4; r++)
                    Cf[(size_t)(row0 + r) * N + col] = acc[mi][ni][r] + bv;
            } else if (MODE == 2) {
                u16* Cb = (u16*)C;
                int bb = row0 >> 11, s = row0 & 2047;
                int base64 = s & ~63, j = s & 63;           // j = mi*16 + quad*4 (j%4==0)
                int p0 = ((j >> 5) << 5) + ((j & 15) << 1) + ((j >> 4) & 1);
                u16* dst = Cb + ((size_t)(bb * 1024 + col)) * 2048 + base64;
#pragma unroll
                for (int r = 0; r < 4; r++)
                    dst[p0 + 2 * r] = f2b(acc[mi][ni][r] + bv);
            } else {
                u16* Cb = (u16*)C;
                int bb = row0 >> 11, s = row0 & 2047;
                int h = col >> 6, d = col & 63;
#pragma unroll
                for (int r = 0; r < 4; r++)
                    Cb[((size_t)(bb * 16 + h) * 2048 + s + r) * 64 + d] = f2b(acc[mi][ni][r] + bv);
            }
        }
    }
}

template <int MODE>
__global__ __launch_bounds__(256) void k_gemm2(const u16* __restrict__ A, const u16* __restrict__ Bt,
                                               const float* __restrict__ bias, void* __restrict__ C,
                                               int N, int K) {
    gemm2_body<MODE>(A, Bt, bias, C, N, K);
}

template <int MODE>
__global__ __launch_bounds__(256) void k_gemm2_dual(const u16* __restrict__ A,
                                                    const u16* __restrict__ Bt0, const u16* __restrict__ Bt1,
                                                    const float* __restrict__ b0, const float* __restrict__ b1,
                                                    void* __restrict__ C0, void* __restrict__ C1,
                                                    int N, int K) {
    if (blockIdx.z == 0) gemm2_body<MODE>(A, Bt0, b0, C0, N, K);
    else                 gemm2_body<MODE>(A, Bt1, b1, C1, N, K);
}

// Q/K/V projections in one launch (z: 0=Q head-major, 1=K head-major, 2=V transposed+pi2)
__global__ __launch_bounds__(256) void k_qkv(const u16* __restrict__ A,
                                             const u16* __restrict__ W0, const u16* __restrict__ W1,
                                             const u16* __restrict__ W2,
                                             const float* __restrict__ b0, const float* __restrict__ b1,
                                             const float* __restrict__ b2,
                                             u16* __restrict__ Q, u16* __restrict__ K, u16* __restrict__ VT) {
    if (blockIdx.z == 0)      gemm2_body<3>(A, W0, b0, Q, H, H);
    else if (blockIdx.z == 1) gemm2_body<3>(A, W1, b1, K, H, H);
    else                      gemm2_body<2>(A, W2, b2, VT, H, H);
}

// ---------------- both positional score tables, one launch ----------------
__global__ __launch_bounds__(256) void k_pos_both(const u16* __restrict__ Qh, const u16* __restrict__ Kh,
                                                  const u16* __restrict__ pk, const u16* __restrict__ pq,
                                                  u16* __restrict__ c2p, u16* __restrict__ p2cK,
                                                  u16* __restrict__ pfar) {
    __shared__ __align__(16) u16 smem[2 * 128 * 72];   // As | Bs
    u16* As = smem;
    u16* Bs = smem + 128 * 72;
    int tid = threadIdx.x;
    int lane = tid & 63, w = tid >> 6;
    int ln = lane & 15, quad = lane >> 4;
    int tr = blockIdx.z & 1, z = blockIdx.z >> 1, h = z & 15;
    int m0 = blockIdx.x * 128, n0 = blockIdx.y * 128;
    const u16* A = (tr ? Kh : Qh) + (size_t)z * S * HD;
    const u16* B = (tr ? pq : pk) + h * 64;
    int sr = tid >> 1, scb = (tid & 1) * 32;
    {
        const u16* ga = A + (size_t)(m0 + sr) * HD + scb;
        const u16* gb = B + (size_t)(n0 + sr) * H + scb;
#pragma unroll
        for (int j = 0; j < 4; j++) {
            *(short8*)&As[sr * 72 + scb + j * 8] = *(const short8*)(ga + j * 8);
            *(short8*)&Bs[sr * 72 + scb + j * 8] = *(const short8*)(gb + j * 8);
        }
    }
    __syncthreads();
    int wm = (w >> 1) * 64, wn = (w & 1) * 64;
    float4v acc[4][4];
    float4v zero = {0.f, 0.f, 0.f, 0.f};
#pragma unroll
    for (int mi = 0; mi < 4; mi++)
#pragma unroll
        for (int ni = 0; ni < 4; ni++) acc[mi][ni] = zero;
#pragma unroll
    for (int c = 0; c < 2; c++) {
        short8 af[4], bf[4];
#pragma unroll
        for (int mi = 0; mi < 4; mi++)
            af[mi] = *(const short8*)&As[(wm + mi * 16 + ln) * 72 + c * 32 + quad * 8];
#pragma unroll
        for (int ni = 0; ni < 4; ni++)
            bf[ni] = *(const short8*)&Bs[(wn + ni * 16 + ln) * 72 + c * 32 + quad * 8];
#pragma unroll
        for (int mi = 0; mi < 4; mi++)
#pragma unroll
            for (int ni = 0; ni < 4; ni++)
                acc[mi][ni] = MFMA16(af[mi], bf[ni], acc[mi][ni]);
    }
    u16* Cp = (tr ? p2cK : c2p) + (size_t)z * S * 512;
#pragma unroll
    for (int mi = 0; mi < 4; mi++) {
        int row0 = m0 + wm + mi * 16 + quad * 4;
#pragma unroll
        for (int ni = 0; ni < 4; ni++) {
            int col = n0 + wn + ni * 16 + ln;
#pragma unroll
            for (int r = 0; r < 4; r++)
                Cp[(size_t)(row0 + r) * 512 + col] = f2b(acc[mi][ni][r] * SC);
        }
    }
    if (tr) {
        // far-column extraction (col 0 lives in n0==0 blocks, col 511 in n0==384 blocks)
        if (n0 == 0 && (w & 1) == 0 && ln == 0) {
            u16* dst = pfar + (size_t)z * 2048 + m0 + wm + quad * 4;
#pragma unroll
            for (int mi = 0; mi < 4; mi++)
#pragma unroll
                for (int r = 0; r < 4; r++)
                    dst[mi * 16 + r] = f2b(acc[mi][0][r] * SC);
        }
        if (n0 == 384 && (w & 1) == 1 && ln == 15) {
            u16* dst = pfar + (size_t)(32 + z) * 2048 + m0 + wm + quad * 4;
#pragma unroll
            for (int mi = 0; mi < 4; mi++)
#pragma unroll
                for (int r = 0; r < 4; r++)
                    dst[mi * 16 + r] = f2b(acc[mi][3][r] * SC);
        }
    }
}

// gather c2p+p2c bias for rows r=0..3 at f=F into 4 named floats.
// extended s_idx1 (rel+704, no clamp needed: near-branch rel spans [-639, 575]).
#define GATHER_BIAS(F, B0, B1, B2, B3) do {                                          \
    int ki_ = kk + (F) * 16 + ln;                                                    \
    const u16* pvrow_ = p2cB + (size_t)ki_ * 512;                                    \
    const short* it_ = s_idx1 + (qrow - ki_) + 704;                                  \
    int i0_ = (int)it_[0], i1_ = (int)it_[1], i2_ = (int)it_[2], i3_ = (int)it_[3];  \
    const u32* p32_ = (const u32*)pvrow_;                                            \
    int e_ = i0_ >> 1;                                                               \
    u32 wx_ = p32_[e_], wy_ = p32_[e_ + 1], wz_ = p32_[e_ + 2];                      \
    u64 lov_ = (u64)wx_ | ((u64)wy_ << 32);                                          \
    u64 sft_ = (i0_ & 1) ? ((lov_ >> 16) | ((u64)wz_ << 48)) : lov_;                 \
    u16 c0_ = cvrow[0][i0_], c1_ = cvrow[1][i1_], c2_ = cvrow[2][i2_], c3_ = cvrow[3][i3_]; \
    union { u32 u; float f; } q0_, q1_, q2_, q3_;                                    \
    q0_.u = ((u32)(sft_)) << 16;                                                     \
    q1_.u = ((u32)(sft_ >> ((i1_ - i0_) << 4))) << 16;                               \
    q2_.u = ((u32)(sft_ >> ((i2_ - i0_) << 4))) << 16;                               \
    q3_.u = ((u32)(sft_ >> ((i3_ - i0_) << 4))) << 16;                               \
    B0 = b2f(c0_) + q0_.f;                                                           \
    B1 = b2f(c1_) + q1_.f;                                                           \
    B2 = b2f(c2_) + q2_.f;                                                           \
    B3 = b2f(c3_) + q3_.f;                                                           \
} while (0)

// ---------------- fused attention: K/V tiles staged in LDS (shared by 4 waves) ----------------
// P columns and V columns both live in pi2-permuted k-order (V permuted at VT write time).
// K/V global loads for tile t+1 are issued right after tile t's LDS is ready (T14
// async-STAGE): their HBM latency hides under tile t's compute instead of the loop head.
// NOTE: ocml exp2f retained (round-5 raw v_exp_f32 swap coincided with the absmax failure).
template <int SPLIT>
__global__ __launch_bounds__(256, 4) void k_attn(const u16* __restrict__ Qh,
                                                 const u16* __restrict__ Kh,
                                                 const u16* __restrict__ VT,
                                                 const u16* __restrict__ c2p,
                                                 const u16* __restrict__ p2cK,
                                                 const u16* __restrict__ pfar,
                                                 const short* __restrict__ idxTab,
                                                 float* __restrict__ oP,
                                                 float* __restrict__ lP,
                                                 u16* __restrict__ ctx) {
    __shared__ short s_idx1[1344];
    __shared__ __align__(16) u16 p_lds[4][16][72];
    __shared__ __align__(16) u16 Ks[64][72];
    __shared__ __align__(16) u16 Vs[64][72];
    int tid = threadIdx.x;
    for (int i = tid; i < 1344; i += 256) s_idx1[i] = idxTab[i];
    int lane = tid & 63, w = tid >> 6;
    int ln = lane & 15, quad = lane >> 4;
    int bx = blockIdx.x;
    int half = (SPLIT == 2) ? (bx & 1) : 0;
    int q0 = (SPLIT == 2) ? (bx >> 1) * 64 : bx * 64;
    int bh = blockIdx.y;
    int b = bh >> 4, h = bh & 15;
    int qs = q0 + w * 16;

    const u16* qptr = Qh + ((size_t)bh * S + qs + ln) * HD + quad * 8;
    short8 aq0 = *(const short8*)(qptr);
    short8 aq1 = *(const short8*)(qptr + 32);

    float4v o[4];
    float4v zero = {0.f, 0.f, 0.f, 0.f};
#pragma unroll
    for (int f = 0; f < 4; f++) o[f] = zero;
    float lrw[4] = {0.f, 0.f, 0.f, 0.f};

    const u16* c2pB = c2p + (size_t)bh * S * 512;
    const u16* p2cB = p2cK + (size_t)bh * S * 512;
    int qrow = qs + quad * 4;

    // c2p row pointers: fixed per thread for the whole kernel (16 q-rows per wave -> L1-hot)
    const u16* cvrow[4];
#pragma unroll
    for (int r = 0; r < 4; r++) cvrow[r] = c2pB + (size_t)(qrow + r) * 512;

    // staging map: thread -> (row sr 0..63, col block sc 0..48 step 16)
    int sr = tid >> 2, sc = (tid & 3) * 16;
    const u16* kstg = Kh + ((size_t)bh * S + sr) * HD + sc;              // + kk*HD per tile
    const u16* vstg = VT + (size_t)(b * 1024 + h * 64 + sr) * S + sc;    // + kk per tile (pi2 order)

    const int NT = S / 64 / SPLIT;
    // ---- prologue: load tile 0 into regs ----
    int kk0 = (SPLIT == 2) ? (half << 6) : 0;
    short8 kr0 = *(const short8*)(kstg + (size_t)kk0 * HD);
    short8 kr1 = *(const short8*)(kstg + (size_t)kk0 * HD + 8);
    short8 vr0 = *(const short8*)(vstg + kk0);
    short8 vr1 = *(const short8*)(vstg + kk0 + 8);

    for (int t = 0; t < NT; t++) {
        int kk = (SPLIT == 2) ? (((t << 1) | half) << 6) : (t << 6);
        // ---- write staged tile to LDS ----
        __syncthreads();
        *(short8*)&Ks[sr][sc] = kr0; *(short8*)&Ks[sr][sc + 8] = kr1;
        *(short8*)&Vs[sr][sc] = vr0; *(short8*)&Vs[sr][sc + 8] = vr1;
        __syncthreads();
        // ---- prefetch tile t+1 (clamped on last iter; latency hides under compute) ----
        {
            int tn = (t + 1 < NT) ? t + 1 : t;
            int kkn = (SPLIT == 2) ? (((tn << 1) | half) << 6) : (tn << 6);
            kr0 = *(const short8*)(kstg + (size_t)kkn * HD);
            kr1 = *(const short8*)(kstg + (size_t)kkn * HD + 8);
            vr0 = *(const short8*)(vstg + kkn);
            vr1 = *(const short8*)(vstg + kkn + 8);
        }
        // ---- QK^T from LDS ----
        float4v sa[4];
        __builtin_amdgcn_s_setprio(1);
#pragma unroll
        for (int f = 0; f < 4; f++) {
            short8 b0 = *(const short8*)&Ks[f * 16 + ln][quad * 8];
            short8 b1 = *(const short8*)&Ks[f * 16 + ln][32 + quad * 8];
            float4v tt = zero;
            tt = MFMA16(aq0, b0, tt);
            tt = MFMA16(aq1, b1, tt);
            sa[f] = tt;
        }
        __builtin_amdgcn_s_setprio(0);
        // ---- positional bias + exp2 (fixed max 0) ----
        int rel0 = q0 - kk;
        u32* prow0 = (u32*)&p_lds[w][quad * 4][0];
        if (rel0 >= 569 || rel0 <= -633) {
            // far: idx is constant 0 or 511; pv comes from the pre-extracted column.
            int idx = rel0 > 0 ? 511 : 0;
            const u16* pfb = pfar + (rel0 > 0 ? (size_t)(32 + bh) : (size_t)bh) * 2048 + kk;
            float cvr[4], pvf[4];
#pragma unroll
            for (int r = 0; r < 4; r++)
                cvr[r] = b2f(cvrow[r][idx]);
#pragma unroll
            for (int f = 0; f < 4; f++)
                pvf[f] = b2f(pfb[f * 16 + ln]);
#pragma unroll
            for (int u = 0; u < 2; u++) {
#pragma unroll
                for (int r = 0; r < 4; r++) {
                    float p0 = exp2f(sa[2 * u][r] * SC + cvr[r] + pvf[2 * u]);
                    float p1 = exp2f(sa[2 * u + 1][r] * SC + cvr[r] + pvf[2 * u + 1]);
                    lrw[r] += p0 + p1;
                    prow0[r * 36 + u * 16 + ln] = cvtpk(p0, p1);
                }
            }
        } else {
            // near: f-pair phasing — gather 8 bias floats, then exp2+cvtpk+b32 store.
#pragma unroll
            for (int u = 0; u < 2; u++) {
                float ba0, ba1, ba2, ba3, bb0, bb1, bb2, bb3;
                GATHER_BIAS(2 * u, ba0, ba1, ba2, ba3);
                GATHER_BIAS(2 * u + 1, bb0, bb1, bb2, bb3);
                float p0, p1;
                p0 = exp2f(sa[2 * u][0] * SC + ba0);
                p1 = exp2f(sa[2 * u + 1][0] * SC + bb0);
                lrw[0] += p0 + p1;
                prow0[0 * 36 + u * 16 + ln] = cvtpk(p0, p1);
                p0 = exp2f(sa[2 * u][1] * SC + ba1);
                p1 = exp2f(sa[2 * u + 1][1] * SC + bb1);
                lrw[1] += p0 + p1;
                prow0[1 * 36 + u * 16 + ln] = cvtpk(p0, p1);
                p0 = exp2f(sa[2 * u][2] * SC + ba2);
                p1 = exp2f(sa[2 * u + 1][2] * SC + bb2);
                lrw[2] += p0 + p1;
                prow0[2 * 36 + u * 16 + ln] = cvtpk(p0, p1);
                p0 = exp2f(sa[2 * u][3] * SC + ba3);
                p1 = exp2f(sa[2 * u + 1][3] * SC + bb3);
                lrw[3] += p0 + p1;
                prow0[3 * 36 + u * 16 + ln] = cvtpk(p0, p1);
            }
        }
        // ---- PV from LDS (own-wave P slice, no extra barrier; pi2-consistent) ----
        short8 ap0 = *(const short8*)&p_lds[w][ln][quad * 8];
        short8 ap1 = *(const short8*)&p_lds[w][ln][32 + quad * 8];
        __builtin_amdgcn_s_setprio(1);
#pragma unroll
        for (int f = 0; f < 4; f++) {
            short8 v0 = *(const short8*)&Vs[f * 16 + ln][quad * 8];
            short8 v1 = *(const short8*)&Vs[f * 16 + ln][32 + quad * 8];
            o[f] = MFMA16(ap0, v0, o[f]);
            o[f] = MFMA16(ap1, v1, o[f]);
        }
        __builtin_amdgcn_s_setprio(0);
    }
    // ---- single end-of-loop l reduction (within 16-lane quad) ----
#pragma unroll
    for (int r = 0; r < 4; r++) {
        lrw[r] += __shfl_xor(lrw[r], 1, 16);
        lrw[r] += __shfl_xor(lrw[r], 2, 16);
        lrw[r] += __shfl_xor(lrw[r], 4, 16);
        lrw[r] += __shfl_xor(lrw[r], 8, 16);
    }
    if (SPLIT == 1) {
        float inv_l[4];
#pragma unroll
        for (int r = 0; r < 4; r++) inv_l[r] = 1.f / lrw[r];
#pragma unroll
        for (int f = 0; f < 4; f++)
#pragma unroll
            for (int r = 0; r < 4; r++) {
                int qi = qs + quad * 4 + r;
                ctx[(size_t)(b * S + qi) * H + h * 64 + f * 16 + ln] = f2b(o[f][r] * inv_l[r]);
            }
    } else {
        float* oH = oP + (size_t)half * SP_OHALF;
#pragma unroll
        for (int f = 0; f < 4; f++)
#pragma unroll
            for (int r = 0; r < 4; r++) {
                int qi = qs + quad * 4 + r;
                oH[((size_t)bh * S + qi) * 64 + f * 16 + ln] = o[f][r];
            }
        if (ln == 0) {
            float* lH = lP + (size_t)half * SP_LHALF;
#pragma unroll
            for (int r = 0; r < 4; r++)
                lH[(size_t)bh * S + qs + quad * 4 + r] = lrw[r];
        }
    }
}

// ---------------- merge split-K partials -> ctx bf16 ----------------
__global__ __launch_bounds__(256) void k_merge(const float* __restrict__ oP,
                                               const float* __restrict__ lP,
                                               u16* __restrict__ ctx) {
    int t = blockIdx.x * 256 + threadIdx.x;
    int d4 = (t & 15) * 4;
    int h  = (t >> 4) & 15;
    int qq = (t >> 8) & 2047;
    int b  = t >> 19;
    int bh = b * 16 + h;
    size_t base = ((size_t)bh * S + qq) * 64 + d4;
    float4 o0 = *(const float4*)(oP + base);
    float4 o1 = *(const float4*)(oP + SP_OHALF + base);
    float l0 = lP[(size_t)bh * S + qq];
    float l1 = lP[SP_LHALF + (size_t)bh * S + qq];
    float inv = 1.f / (l0 + l1);
    ushort4 r4;
    r4.x = f2b((o0.x + o1.x) * inv);
    r4.y = f2b((o0.y + o1.y) * inv);
    r4.z = f2b((o0.z + o1.z) * inv);
    r4.w = f2b((o0.w + o1.w) * inv);
    *(ushort4*)(ctx + (((size_t)(b * S + qq)) * 16 + h) * 64 + d4) = r4;
}

// ---------------- launch ----------------
extern "C" void kernel_launch(void* const* d_in, const int* in_sizes, int n_in,
                              void* d_out, int out_size, void* d_ws, size_t ws_size,
                              hipStream_t stream) {
    const float* hs  = (const float*)d_in[0];
    const float* Wq  = (const float*)d_in[1];
    const float* bq  = (const float*)d_in[2];
    const float* Wk  = (const float*)d_in[3];
    const float* bk  = (const float*)d_in[4];
    const float* Wv  = (const float*)d_in[5];
    const float* bv  = (const float*)d_in[6];
    const float* Wo  = (const float*)d_in[7];
    const float* bo  = (const float*)d_in[8];
    const float* Wpk = (const float*)d_in[9];
    const float* bpk = (const float*)d_in[10];
    const float* Wpq = (const float*)d_in[11];
    const float* bpq = (const float*)d_in[12];
    const float* rel = (const float*)d_in[13];
    const float* lng = (const float*)d_in[14];
    const float* lnb = (const float*)d_in[15];

    char* ws = (char*)d_ws;
    u16* re_b   = (u16*)(ws + OFF_REB);
    u16* hs_b   = (u16*)(ws + OFF_HSB);
    u16* wt0    = (u16*)(ws + OFF_WT);
    u16* wt1    = (u16*)(ws + OFF_WT + 2097152ull);
    u16* wt2    = (u16*)(ws + OFF_WT + 2ull * 2097152ull);
    u16* wt3    = (u16*)(ws + OFF_WT + 3ull * 2097152ull);
    u16* wt4    = (u16*)(ws + OFF_WT + 4ull * 2097152ull);
    u16* wt5    = (u16*)(ws + OFF_WT + 5ull * 2097152ull);
    u16* Q_b    = (u16*)(ws + OFF_QB);
    u16* K_b    = (u16*)(ws + OFF_KB);
    u16* VT_b   = (u16*)(ws + OFF_VT);
    u16* posk_b = (u16*)(ws + OFF_PKB);
    u16* posq_b = (u16*)(ws + OFF_PQB);
    u16* c2p_b  = (u16*)(ws + OFF_C2P);
    u16* p2cK_b = (u16*)(ws + OFF_P2CK);
    u16* ctx_b  = (u16*)(ws + OFF_CTX);
    short* idx_t = (short*)(ws + OFF_IDX);
    u16* pfar_b = (u16*)(ws + OFF_PF);
    float* oP   = (float*)(ws + OFF_SP);
    float* lP   = (float*)(ws + SP_LBASE);

    dim3 blk(256);
    k_build_idx<<<dim3(6), blk, 0, stream>>>(idx_t);
    k_ln<<<dim3(512), blk, 0, stream>>>(rel, lng, lnb, re_b);
    k_cast<<<dim3(4096), blk, 0, stream>>>(hs, hs_b);
    k_wt6<<<dim3(16, 16, 6), blk, 0, stream>>>(Wq, Wk, Wv, Wo, Wpk, Wpq,
                                               wt0, wt1, wt2, wt3, wt4, wt5);

    // projections
    k_qkv<<<dim3(32, 8, 3), blk, 0, stream>>>(hs_b, wt0, wt1, wt2, bq, bk, bv, Q_b, K_b, VT_b);
    k_gemm2_dual<0><<<dim3(4, 8, 2), blk, 0, stream>>>(re_b, wt4, wt5, bpk, bpq, posk_b, posq_b, H, H);

    // positional score tables (scale incl. log2e folded in)
    k_pos_both<<<dim3(16, 4, 64), blk, 0, stream>>>(Q_b, K_b, posk_b, posq_b, c2p_b, p2cK_b, pfar_b);

    // fused attention (split-K x2 interleaved when workspace allows)
    if (ws_size >= WS_NEED_SPLIT) {
        k_attn<2><<<dim3(64, 32), blk, 0, stream>>>(Q_b, K_b, VT_b, c2p_b, p2cK_b, pfar_b, idx_t, oP, lP, ctx_b);
        k_merge<<<dim3(4096), blk, 0, stream>>>(oP, lP, ctx_b);
    } else {
        k_attn<1><<<dim3(32, 32), blk, 0, stream>>>(Q_b, K_b, VT_b, c2p_b, p2cK_b, pfar_b, idx_t, oP, lP, ctx_b);
    }

    // output projection (fp32 out)
    k_gemm2<1><<<dim3(32, 8), blk, 0, stream>>>(ctx_b, wt3, bo, d_out, H, H);
}

// Round 9
// 369.768 us; speedup vs baseline: 1.0481x; 1.0481x over previous
//
#include <hip/hip_runtime.h>

typedef unsigned short u16;
typedef unsigned int u32;
typedef unsigned long long u64;
typedef __attribute__((ext_vector_type(8))) short short8;
typedef __attribute__((ext_vector_type(4))) float float4v;

#define MFMA16(a, b, c) __builtin_amdgcn_mfma_f32_16x16x32_bf16((a), (b), (c), 0, 0, 0)

// ---------------- helpers ----------------
__device__ __forceinline__ u16 f2b(float x) {
    union { float f; unsigned u; } v; v.f = x;
    unsigned r = v.u + 0x7FFFu + ((v.u >> 16) & 1u);   // RNE
    return (u16)(r >> 16);
}
__device__ __forceinline__ float b2f(u16 u) {
    union { unsigned u; float f; } v; v.u = ((unsigned)u) << 16; return v.f;
}
// pack 2 f32 -> 2 bf16 (RNE) in one instruction
__device__ __forceinline__ u32 cvtpk(float lo, float hi) {
    u32 r;
    asm("v_cvt_pk_bf16_f32 %0, %1, %2" : "=v"(r) : "v"(lo), "v"(hi));
    return r;
}

// constants
#define NH 16
#define S  2048
#define HD 64
#define H  1024
// scale = 1/sqrt(192) * log2(e)  (exp -> exp2 folded into all score terms)
#define SC 0.10412111829775301f

// ---------------- workspace offsets (bytes) ----------------
#define OFF_REB   0ull
#define OFF_HSB   (OFF_REB  + 1048576ull)
#define OFF_WT    (OFF_HSB  + 8388608ull)
#define OFF_QB    (OFF_WT   + 12582912ull)
#define OFF_KB    (OFF_QB   + 8388608ull)
#define OFF_VT    (OFF_KB   + 8388608ull)
#define OFF_PKB   (OFF_VT   + 8388608ull)
#define OFF_PQB   (OFF_PKB  + 1048576ull)
#define OFF_C2P   (OFF_PQB  + 1048576ull)                // 64 MB [bh][q][512]
#define OFF_P2CK  (OFF_C2P  + 67108864ull)               // 64 MB [bh][k][512]  (k-major)
#define OFF_CTX   (OFF_P2CK + 67108864ull)
#define OFF_IDX   (OFF_CTX  + 8388608ull)
#define OFF_PF    (OFF_IDX  + 8192ull)                   // far columns [2][32][2048] u16 = 256 KB
#define OFF_SP    (OFF_PF   + 262144ull)                 // split-K partials
#define SP_OHALF  4194304ull                             // floats per half (32*2048*64)
#define SP_LBASE  (OFF_SP + 67108864ull)
#define SP_LHALF  65536ull
#define WS_NEED_SPLIT (SP_LBASE + 524288ull)             // ~248.5 MB

// ---------------- idx table for rel in [-512, 511] ----------------
// idx monotone nondecreasing, slope <= 1; clamping rel to [-512,511] is EXACT.
__global__ void k_build_idx(short* __restrict__ t) {
    int i = blockIdx.x * 256 + threadIdx.x;
    if (i >= 1024) return;
    int rel = i - 512;
    float fr = (float)rel;
    float abs_pos = (rel < 128 && rel > -128) ? 127.0f : fabsf(fr);
    const float LOGC = 1.3843393262841284f;  // float32(ln(511/128))
    float log_pos = ceilf(logf(abs_pos * (1.0f / 128.0f)) / LOGC * 127.0f) + 128.0f;
    float sgn = (fr > 0.f) ? 1.f : ((fr < 0.f) ? -1.f : 0.f);
    float bf = (abs_pos <= 128.0f) ? fr : log_pos * sgn;
    int idx = (int)bf + 256;
    idx = idx < 0 ? 0 : (idx > 511 ? 511 : idx);
    t[i] = (short)idx;
}

// ---------------- LayerNorm of rel_emb -> bf16 ----------------
__global__ __launch_bounds__(256) void k_ln(const float* __restrict__ re,
                                            const float* __restrict__ g,
                                            const float* __restrict__ be,
                                            u16* __restrict__ out) {
    int row = blockIdx.x;
    const float4* x4 = (const float4*)(re + (size_t)row * H);
    int tid = threadIdx.x;
    float4 vv = x4[tid];
    float s = vv.x + vv.y + vv.z + vv.w;
    float s2 = vv.x * vv.x + vv.y * vv.y + vv.z * vv.z + vv.w * vv.w;
    for (int m = 1; m < 64; m <<= 1) {
        s += __shfl_xor(s, m, 64);
        s2 += __shfl_xor(s2, m, 64);
    }
    __shared__ float as[4], as2[4];
    if ((tid & 63) == 0) { as[tid >> 6] = s; as2[tid >> 6] = s2; }
    __syncthreads();
    s = as[0] + as[1] + as[2] + as[3];
    s2 = as2[0] + as2[1] + as2[2] + as2[3];
    float mu = s * (1.f / 1024.f);
    float var = s2 * (1.f / 1024.f) - mu * mu;
    float rstd = rsqrtf(var + 1e-5f);
    float4 gg = ((const float4*)g)[tid];
    float4 bb = ((const float4*)be)[tid];
    ushort4 r4;
    r4.x = f2b((vv.x - mu) * rstd * gg.x + bb.x);
    r4.y = f2b((vv.y - mu) * rstd * gg.y + bb.y);
    r4.z = f2b((vv.z - mu) * rstd * gg.z + bb.z);
    r4.w = f2b((vv.w - mu) * rstd * gg.w + bb.w);
    ((ushort4*)(out + (size_t)row * H))[tid] = r4;
}

// ---------------- fp32 -> bf16 cast ----------------
__global__ __launch_bounds__(256) void k_cast(const float* __restrict__ x, u16* __restrict__ y) {
    int i = blockIdx.x * 256 + threadIdx.x;
    float4 v = ((const float4*)x)[i];
    ushort4 r;
    r.x = f2b(v.x); r.y = f2b(v.y); r.z = f2b(v.z); r.w = f2b(v.w);
    ((ushort4*)y)[i] = r;
}

// ---------------- 6x weight transpose + cast ----------------
__global__ __launch_bounds__(256) void k_wt6(const float* __restrict__ W0, const float* __restrict__ W1,
                                             const float* __restrict__ W2, const float* __restrict__ W3,
                                             const float* __restrict__ W4, const float* __restrict__ W5,
                                             u16* __restrict__ T0, u16* __restrict__ T1,
                                             u16* __restrict__ T2, u16* __restrict__ T3,
                                             u16* __restrict__ T4, u16* __restrict__ T5) {
    const float* W; u16* WT;
    switch (blockIdx.z) {
        case 0: W = W0; WT = T0; break;
        case 1: W = W1; WT = T1; break;
        case 2: W = W2; WT = T2; break;
        case 3: W = W3; WT = T3; break;
        case 4: W = W4; WT = T4; break;
        default: W = W5; WT = T5; break;
    }
    __shared__ float t[64][65];
    int k0 = blockIdx.x * 64, n0 = blockIdx.y * 64;
    int tid = threadIdx.x;
#pragma unroll
    for (int i = 0; i < 16; i++) {
        int lin = tid + 256 * i;
        int r = lin >> 6, c = lin & 63;
        t[r][c] = W[(size_t)(k0 + r) * H + n0 + c];
    }
    __syncthreads();
#pragma unroll
    for (int i = 0; i < 16; i++) {
        int lin = tid + 256 * i;
        int r = lin >> 6, c = lin & 63;
        WT[(size_t)(n0 + r) * H + k0 + c] = f2b(t[c][r]);
    }
}

// ---------------- 128x128-tile GEMM core ----------------
// MODE 0: bf16 row-major; MODE 1: f32 row-major;
// MODE 2: bf16 VT layout (b*1024+n)*2048 + pi2-permuted s within each 64-block
//         (pi2(j) = (j>>5)*32 + (j&15)*2 + ((j>>4)&1); k_attn's P store and PV MFMA
//          use the same permuted k-order, and MFMA sums over k, so this is exact);
// MODE 3: bf16 head-major ((b*16+h)*2048+m)*64+d
template <int MODE>
__device__ __forceinline__ void gemm2_body(const u16* __restrict__ A,
                                           const u16* __restrict__ Bt,
                                           const float* __restrict__ bias,
                                           void* __restrict__ C, int N, int K) {
    __shared__ __align__(16) u16 As[128 * 32];
    __shared__ __align__(16) u16 Bs[128 * 32];
    int tid = threadIdx.x;
    int lane = tid & 63, w = tid >> 6;
    int ln = lane & 15, quad = lane >> 4;
    int m0 = blockIdx.x * 128, n0 = blockIdx.y * 128;
    int wm = (w >> 1) * 64, wn = (w & 1) * 64;
    float4v acc[4][4];
    float4v zero = {0.f, 0.f, 0.f, 0.f};
#pragma unroll
    for (int mi = 0; mi < 4; mi++)
#pragma unroll
        for (int ni = 0; ni < 4; ni++) acc[mi][ni] = zero;

    int r1 = tid >> 2, o1 = (tid & 3) * 8;
    const u16* ga1 = A + (size_t)(m0 + r1) * K + o1;
    const u16* gb1 = Bt + (size_t)(n0 + r1) * K + o1;
    u16* sa1 = &As[r1 * 32 + o1];
    u16* sb1 = &Bs[r1 * 32 + o1];
    size_t step2 = (size_t)64 * K;

    for (int k0 = 0; k0 < K; k0 += 32) {
        short8 va1 = *(const short8*)(ga1 + k0);
        short8 va2 = *(const short8*)(ga1 + step2 + k0);
        short8 vb1 = *(const short8*)(gb1 + k0);
        short8 vb2 = *(const short8*)(gb1 + step2 + k0);
        __syncthreads();
        *(short8*)sa1 = va1; *(short8*)(sa1 + 2048) = va2;
        *(short8*)sb1 = vb1; *(short8*)(sb1 + 2048) = vb2;
        __syncthreads();
        short8 af[4], bf[4];
#pragma unroll
        for (int mi = 0; mi < 4; mi++)
            af[mi] = *(const short8*)&As[(wm + mi * 16 + ln) * 32 + quad * 8];
#pragma unroll
        for (int ni = 0; ni < 4; ni++)
            bf[ni] = *(const short8*)&Bs[(wn + ni * 16 + ln) * 32 + quad * 8];
#pragma unroll
        for (int mi = 0; mi < 4; mi++)
#pragma unroll
            for (int ni = 0; ni < 4; ni++)
                acc[mi][ni] = MFMA16(af[mi], bf[ni], acc[mi][ni]);
    }

#pragma unroll
    for (int mi = 0; mi < 4; mi++) {
        int row0 = m0 + wm + mi * 16 + quad * 4;
#pragma unroll
        for (int ni = 0; ni < 4; ni++) {
            int col = n0 + wn + ni * 16 + ln;
            float bv = bias[col];
            if (MODE == 0) {
                u16* Cb = (u16*)C;
#pragma unroll
                for (int r = 0; r < 4; r++)
                    Cb[(size_t)(row0 + r) * N + col] = f2b(acc[mi][ni][r] + bv);
            } else if (MODE == 1) {
                float* Cf = (float*)C;
#pragma unroll
                for (int r = 0; r < 4; r++)
                    Cf[(size_t)(row0 + r) * N + col] = acc[mi][ni][r] + bv;
            } else if (MODE == 2) {
                u16* Cb = (u16*)C;
                int bb = row0 >> 11, s = row0 & 2047;
                int base64 = s & ~63, j = s & 63;           // j = mi*16 + quad*4 (j%4==0)
                int p0 = ((j >> 5) << 5) + ((j & 15) << 1) + ((j >> 4) & 1);
                u16* dst = Cb + ((size_t)(bb * 1024 + col)) * 2048 + base64;
#pragma unroll
                for (int r = 0; r < 4; r++)
                    dst[p0 + 2 * r] = f2b(acc[mi][ni][r] + bv);
            } else {
                u16* Cb = (u16*)C;
                int bb = row0 >> 11, s = row0 & 2047;
                int h = col >> 6, d = col & 63;
#pragma unroll
                for (int r = 0; r < 4; r++)
                    Cb[((size_t)(bb * 16 + h) * 2048 + s + r) * 64 + d] = f2b(acc[mi][ni][r] + bv);
            }
        }
    }
}

template <int MODE>
__global__ __launch_bounds__(256) void k_gemm2(const u16* __restrict__ A, const u16* __restrict__ Bt,
                                               const float* __restrict__ bias, void* __restrict__ C,
                                               int N, int K) {
    gemm2_body<MODE>(A, Bt, bias, C, N, K);
}

template <int MODE>
__global__ __launch_bounds__(256) void k_gemm2_dual(const u16* __restrict__ A,
                                                    const u16* __restrict__ Bt0, const u16* __restrict__ Bt1,
                                                    const float* __restrict__ b0, const float* __restrict__ b1,
                                                    void* __restrict__ C0, void* __restrict__ C1,
                                                    int N, int K) {
    if (blockIdx.z == 0) gemm2_body<MODE>(A, Bt0, b0, C0, N, K);
    else                 gemm2_body<MODE>(A, Bt1, b1, C1, N, K);
}

// Q/K/V projections in one launch (z: 0=Q head-major, 1=K head-major, 2=V transposed+pi2)
__global__ __launch_bounds__(256) void k_qkv(const u16* __restrict__ A,
                                             const u16* __restrict__ W0, const u16* __restrict__ W1,
                                             const u16* __restrict__ W2,
                                             const float* __restrict__ b0, const float* __restrict__ b1,
                                             const float* __restrict__ b2,
                                             u16* __restrict__ Q, u16* __restrict__ K, u16* __restrict__ VT) {
    if (blockIdx.z == 0)      gemm2_body<3>(A, W0, b0, Q, H, H);
    else if (blockIdx.z == 1) gemm2_body<3>(A, W1, b1, K, H, H);
    else                      gemm2_body<2>(A, W2, b2, VT, H, H);
}

// ---------------- both positional score tables, one launch ----------------
__global__ __launch_bounds__(256) void k_pos_both(const u16* __restrict__ Qh, const u16* __restrict__ Kh,
                                                  const u16* __restrict__ pk, const u16* __restrict__ pq,
                                                  u16* __restrict__ c2p, u16* __restrict__ p2cK,
                                                  u16* __restrict__ pfar) {
    __shared__ __align__(16) u16 smem[2 * 128 * 72];   // As | Bs
    u16* As = smem;
    u16* Bs = smem + 128 * 72;
    int tid = threadIdx.x;
    int lane = tid & 63, w = tid >> 6;
    int ln = lane & 15, quad = lane >> 4;
    int tr = blockIdx.z & 1, z = blockIdx.z >> 1, h = z & 15;
    int m0 = blockIdx.x * 128, n0 = blockIdx.y * 128;
    const u16* A = (tr ? Kh : Qh) + (size_t)z * S * HD;
    const u16* B = (tr ? pq : pk) + h * 64;
    int sr = tid >> 1, scb = (tid & 1) * 32;
    {
        const u16* ga = A + (size_t)(m0 + sr) * HD + scb;
        const u16* gb = B + (size_t)(n0 + sr) * H + scb;
#pragma unroll
        for (int j = 0; j < 4; j++) {
            *(short8*)&As[sr * 72 + scb + j * 8] = *(const short8*)(ga + j * 8);
            *(short8*)&Bs[sr * 72 + scb + j * 8] = *(const short8*)(gb + j * 8);
        }
    }
    __syncthreads();
    int wm = (w >> 1) * 64, wn = (w & 1) * 64;
    float4v acc[4][4];
    float4v zero = {0.f, 0.f, 0.f, 0.f};
#pragma unroll
    for (int mi = 0; mi < 4; mi++)
#pragma unroll
        for (int ni = 0; ni < 4; ni++) acc[mi][ni] = zero;
#pragma unroll
    for (int c = 0; c < 2; c++) {
        short8 af[4], bf[4];
#pragma unroll
        for (int mi = 0; mi < 4; mi++)
            af[mi] = *(const short8*)&As[(wm + mi * 16 + ln) * 72 + c * 32 + quad * 8];
#pragma unroll
        for (int ni = 0; ni < 4; ni++)
            bf[ni] = *(const short8*)&Bs[(wn + ni * 16 + ln) * 72 + c * 32 + quad * 8];
#pragma unroll
        for (int mi = 0; mi < 4; mi++)
#pragma unroll
            for (int ni = 0; ni < 4; ni++)
                acc[mi][ni] = MFMA16(af[mi], bf[ni], acc[mi][ni]);
    }
    u16* Cp = (tr ? p2cK : c2p) + (size_t)z * S * 512;
#pragma unroll
    for (int mi = 0; mi < 4; mi++) {
        int row0 = m0 + wm + mi * 16 + quad * 4;
#pragma unroll
        for (int ni = 0; ni < 4; ni++) {
            int col = n0 + wn + ni * 16 + ln;
#pragma unroll
            for (int r = 0; r < 4; r++)
                Cp[(size_t)(row0 + r) * 512 + col] = f2b(acc[mi][ni][r] * SC);
        }
    }
    if (tr) {
        // far-column extraction (col 0 lives in n0==0 blocks, col 511 in n0==384 blocks)
        if (n0 == 0 && (w & 1) == 0 && ln == 0) {
            u16* dst = pfar + (size_t)z * 2048 + m0 + wm + quad * 4;
#pragma unroll
            for (int mi = 0; mi < 4; mi++)
#pragma unroll
                for (int r = 0; r < 4; r++)
                    dst[mi * 16 + r] = f2b(acc[mi][0][r] * SC);
        }
        if (n0 == 384 && (w & 1) == 1 && ln == 15) {
            u16* dst = pfar + (size_t)(32 + z) * 2048 + m0 + wm + quad * 4;
#pragma unroll
            for (int mi = 0; mi < 4; mi++)
#pragma unroll
                for (int r = 0; r < 4; r++)
                    dst[mi * 16 + r] = f2b(acc[mi][3][r] * SC);
        }
    }
}

// gather c2p+p2c bias for rows r=0..3 at f=F into 4 named floats (no runtime array idx)
#define GATHER_BIAS(F, B0, B1, B2, B3) do {                                          \
    int ki_ = kk + (F) * 16 + ln;                                                    \
    const u16* pvrow_ = p2cB + (size_t)ki_ * 512;                                    \
    int relb_ = qrow - ki_;                                                          \
    int i0_, i1_, i2_, i3_;                                                          \
    { int rel = relb_;     rel = rel < -512 ? -512 : (rel > 511 ? 511 : rel); i0_ = (int)s_idx1[rel + 512]; } \
    { int rel = relb_ + 1; rel = rel < -512 ? -512 : (rel > 511 ? 511 : rel); i1_ = (int)s_idx1[rel + 512]; } \
    { int rel = relb_ + 2; rel = rel < -512 ? -512 : (rel > 511 ? 511 : rel); i2_ = (int)s_idx1[rel + 512]; } \
    { int rel = relb_ + 3; rel = rel < -512 ? -512 : (rel > 511 ? 511 : rel); i3_ = (int)s_idx1[rel + 512]; } \
    const u32* p32_ = (const u32*)pvrow_;                                            \
    int e_ = i0_ >> 1;                                                               \
    u32 wx_ = p32_[e_], wy_ = p32_[e_ + 1], wz_ = p32_[e_ + 2];                      \
    u64 lov_ = (u64)wx_ | ((u64)wy_ << 32);                                          \
    u64 sft_ = (i0_ & 1) ? ((lov_ >> 16) | ((u64)wz_ << 48)) : lov_;                 \
    u16 c0_ = cvrow[0][i0_], c1_ = cvrow[1][i1_], c2_ = cvrow[2][i2_], c3_ = cvrow[3][i3_]; \
    union { u32 u; float f; } q0_, q1_, q2_, q3_;                                    \
    q0_.u = ((u32)(sft_)) << 16;                                                     \
    q1_.u = ((u32)(sft_ >> ((i1_ - i0_) << 4))) << 16;                               \
    q2_.u = ((u32)(sft_ >> ((i2_ - i0_) << 4))) << 16;                               \
    q3_.u = ((u32)(sft_ >> ((i3_ - i0_) << 4))) << 16;                               \
    B0 = b2f(c0_) + q0_.f;                                                           \
    B1 = b2f(c1_) + q1_.f;                                                           \
    B2 = b2f(c2_) + q2_.f;                                                           \
    B3 = b2f(c3_) + q3_.f;                                                           \
} while (0)

// ---------------- fused attention: K/V tiles staged in LDS (shared by 4 waves) ----------------
// P columns and V columns both live in pi2-permuted k-order (V permuted at VT write time):
// each lane's (f,f+1) P values are ADJACENT -> v_cvt_pk_bf16_f32 + single b32 store.
template <int SPLIT>
__global__ __launch_bounds__(256, 4) void k_attn(const u16* __restrict__ Qh,
                                                 const u16* __restrict__ Kh,
                                                 const u16* __restrict__ VT,
                                                 const u16* __restrict__ c2p,
                                                 const u16* __restrict__ p2cK,
                                                 const u16* __restrict__ pfar,
                                                 const short* __restrict__ idxTab,
                                                 float* __restrict__ oP,
                                                 float* __restrict__ lP,
                                                 u16* __restrict__ ctx) {
    __shared__ short s_idx1[1024];
    __shared__ __align__(16) u16 p_lds[4][16][72];
    __shared__ __align__(16) u16 Ks[64][72];
    __shared__ __align__(16) u16 Vs[64][72];
    int tid = threadIdx.x;
    for (int i = tid; i < 1024; i += 256) s_idx1[i] = idxTab[i];
    int lane = tid & 63, w = tid >> 6;
    int ln = lane & 15, quad = lane >> 4;
    int bx = blockIdx.x;
    int half = (SPLIT == 2) ? (bx & 1) : 0;
    int q0 = (SPLIT == 2) ? (bx >> 1) * 64 : bx * 64;
    int bh = blockIdx.y;
    int b = bh >> 4, h = bh & 15;
    int qs = q0 + w * 16;

    const u16* qptr = Qh + ((size_t)bh * S + qs + ln) * HD + quad * 8;
    short8 aq0 = *(const short8*)(qptr);
    short8 aq1 = *(const short8*)(qptr + 32);

    float4v o[4];
    float4v zero = {0.f, 0.f, 0.f, 0.f};
#pragma unroll
    for (int f = 0; f < 4; f++) o[f] = zero;
    float lrw[4] = {0.f, 0.f, 0.f, 0.f};

    const u16* c2pB = c2p + (size_t)bh * S * 512;
    const u16* p2cB = p2cK + (size_t)bh * S * 512;
    int qrow = qs + quad * 4;

    // c2p row pointers: fixed per thread for the whole kernel (16 q-rows per wave -> L1-hot)
    const u16* cvrow[4];
#pragma unroll
    for (int r = 0; r < 4; r++) cvrow[r] = c2pB + (size_t)(qrow + r) * 512;

    // staging map: thread -> (row sr 0..63, col block sc 0..48 step 16)
    int sr = tid >> 2, sc = (tid & 3) * 16;
    const u16* kstg = Kh + ((size_t)bh * S + sr) * HD + sc;              // + kk*HD per tile
    const u16* vstg = VT + (size_t)(b * 1024 + h * 64 + sr) * S + sc;    // + kk per tile (pi2 order)

    const int NT = S / 64 / SPLIT;
    for (int t = 0; t < NT; t++) {
        int kk = (SPLIT == 2) ? (((t << 1) | half) << 6) : (t << 6);
        // ---- stage K,V tile (all waves cooperate) ----
        short8 kr0 = *(const short8*)(kstg + (size_t)kk * HD);
        short8 kr1 = *(const short8*)(kstg + (size_t)kk * HD + 8);
        short8 vr0 = *(const short8*)(vstg + kk);
        short8 vr1 = *(const short8*)(vstg + kk + 8);
        __syncthreads();
        *(short8*)&Ks[sr][sc] = kr0; *(short8*)&Ks[sr][sc + 8] = kr1;
        *(short8*)&Vs[sr][sc] = vr0; *(short8*)&Vs[sr][sc + 8] = vr1;
        __syncthreads();
        // ---- QK^T from LDS ----
        float4v sa[4];
        __builtin_amdgcn_s_setprio(1);
#pragma unroll
        for (int f = 0; f < 4; f++) {
            short8 b0 = *(const short8*)&Ks[f * 16 + ln][quad * 8];
            short8 b1 = *(const short8*)&Ks[f * 16 + ln][32 + quad * 8];
            float4v tt = zero;
            tt = MFMA16(aq0, b0, tt);
            tt = MFMA16(aq1, b1, tt);
            sa[f] = tt;
        }
        __builtin_amdgcn_s_setprio(0);
        // ---- positional bias + exp2 (fixed max 0) ----
        int rel0 = q0 - kk;
        u32* prow0 = (u32*)&p_lds[w][quad * 4][0];
        if (rel0 >= 569 || rel0 <= -633) {
            // far: idx is constant 0 or 511; pv comes from the pre-extracted column.
            int idx = rel0 > 0 ? 511 : 0;
            const u16* pfb = pfar + (rel0 > 0 ? (size_t)(32 + bh) : (size_t)bh) * 2048 + kk;
            float cvr[4], pvf[4];
#pragma unroll
            for (int r = 0; r < 4; r++)
                cvr[r] = b2f(cvrow[r][idx]);
#pragma unroll
            for (int f = 0; f < 4; f++)
                pvf[f] = b2f(pfb[f * 16 + ln]);
#pragma unroll
            for (int u = 0; u < 2; u++) {
#pragma unroll
                for (int r = 0; r < 4; r++) {
                    float p0 = exp2f(sa[2 * u][r] * SC + cvr[r] + pvf[2 * u]);
                    float p1 = exp2f(sa[2 * u + 1][r] * SC + cvr[r] + pvf[2 * u + 1]);
                    lrw[r] += p0 + p1;
                    u32* prow = prow0 + r * 36;
                    prow[u * 16 + ln] = cvtpk(p0, p1);
                }
            }
        } else {
            // near: f-pair phasing — gather 8 bias floats, then exp2+cvtpk+b32 store.
            // (keeps liveness low: the round-3 bias[4][4] buffer spilled to scratch)
#pragma unroll
            for (int u = 0; u < 2; u++) {
                float ba0, ba1, ba2, ba3, bb0, bb1, bb2, bb3;
                GATHER_BIAS(2 * u, ba0, ba1, ba2, ba3);
                GATHER_BIAS(2 * u + 1, bb0, bb1, bb2, bb3);
                float p0, p1;
                p0 = exp2f(sa[2 * u][0] * SC + ba0);
                p1 = exp2f(sa[2 * u + 1][0] * SC + bb0);
                lrw[0] += p0 + p1;
                prow0[0 * 36 + u * 16 + ln] = cvtpk(p0, p1);
                p0 = exp2f(sa[2 * u][1] * SC + ba1);
                p1 = exp2f(sa[2 * u + 1][1] * SC + bb1);
                lrw[1] += p0 + p1;
                prow0[1 * 36 + u * 16 + ln] = cvtpk(p0, p1);
                p0 = exp2f(sa[2 * u][2] * SC + ba2);
                p1 = exp2f(sa[2 * u + 1][2] * SC + bb2);
                lrw[2] += p0 + p1;
                prow0[2 * 36 + u * 16 + ln] = cvtpk(p0, p1);
                p0 = exp2f(sa[2 * u][3] * SC + ba3);
                p1 = exp2f(sa[2 * u + 1][3] * SC + bb3);
                lrw[3] += p0 + p1;
                prow0[3 * 36 + u * 16 + ln] = cvtpk(p0, p1);
            }
        }
        // ---- PV from LDS (own-wave P slice, no extra barrier; pi2-consistent) ----
        short8 ap0 = *(const short8*)&p_lds[w][ln][quad * 8];
        short8 ap1 = *(const short8*)&p_lds[w][ln][32 + quad * 8];
        __builtin_amdgcn_s_setprio(1);
#pragma unroll
        for (int f = 0; f < 4; f++) {
            short8 v0 = *(const short8*)&Vs[f * 16 + ln][quad * 8];
            short8 v1 = *(const short8*)&Vs[f * 16 + ln][32 + quad * 8];
            o[f] = MFMA16(ap0, v0, o[f]);
            o[f] = MFMA16(ap1, v1, o[f]);
        }
        __builtin_amdgcn_s_setprio(0);
    }
    // ---- single end-of-loop l reduction (within 16-lane quad) ----
#pragma unroll
    for (int r = 0; r < 4; r++) {
        lrw[r] += __shfl_xor(lrw[r], 1, 16);
        lrw[r] += __shfl_xor(lrw[r], 2, 16);
        lrw[r] += __shfl_xor(lrw[r], 4, 16);
        lrw[r] += __shfl_xor(lrw[r], 8, 16);
    }
    if (SPLIT == 1) {
        float inv_l[4];
#pragma unroll
        for (int r = 0; r < 4; r++) inv_l[r] = 1.f / lrw[r];
#pragma unroll
        for (int f = 0; f < 4; f++)
#pragma unroll
            for (int r = 0; r < 4; r++) {
                int qi = qs + quad * 4 + r;
                ctx[(size_t)(b * S + qi) * H + h * 64 + f * 16 + ln] = f2b(o[f][r] * inv_l[r]);
            }
    } else {
        float* oH = oP + (size_t)half * SP_OHALF;
#pragma unroll
        for (int f = 0; f < 4; f++)
#pragma unroll
            for (int r = 0; r < 4; r++) {
                int qi = qs + quad * 4 + r;
                oH[((size_t)bh * S + qi) * 64 + f * 16 + ln] = o[f][r];
            }
        if (ln == 0) {
            float* lH = lP + (size_t)half * SP_LHALF;
#pragma unroll
            for (int r = 0; r < 4; r++)
                lH[(size_t)bh * S + qs + quad * 4 + r] = lrw[r];
        }
    }
}

// ---------------- merge split-K partials -> ctx bf16 ----------------
__global__ __launch_bounds__(256) void k_merge(const float* __restrict__ oP,
                                               const float* __restrict__ lP,
                                               u16* __restrict__ ctx) {
    int t = blockIdx.x * 256 + threadIdx.x;
    int d4 = (t & 15) * 4;
    int h  = (t >> 4) & 15;
    int qq = (t >> 8) & 2047;
    int b  = t >> 19;
    int bh = b * 16 + h;
    size_t base = ((size_t)bh * S + qq) * 64 + d4;
    float4 o0 = *(const float4*)(oP + base);
    float4 o1 = *(const float4*)(oP + SP_OHALF + base);
    float l0 = lP[(size_t)bh * S + qq];
    float l1 = lP[SP_LHALF + (size_t)bh * S + qq];
    float inv = 1.f / (l0 + l1);
    ushort4 r4;
    r4.x = f2b((o0.x + o1.x) * inv);
    r4.y = f2b((o0.y + o1.y) * inv);
    r4.z = f2b((o0.z + o1.z) * inv);
    r4.w = f2b((o0.w + o1.w) * inv);
    *(ushort4*)(ctx + (((size_t)(b * S + qq)) * 16 + h) * 64 + d4) = r4;
}

// ---------------- launch ----------------
extern "C" void kernel_launch(void* const* d_in, const int* in_sizes, int n_in,
                              void* d_out, int out_size, void* d_ws, size_t ws_size,
                              hipStream_t stream) {
    const float* hs  = (const float*)d_in[0];
    const float* Wq  = (const float*)d_in[1];
    const float* bq  = (const float*)d_in[2];
    const float* Wk  = (const float*)d_in[3];
    const float* bk  = (const float*)d_in[4];
    const float* Wv  = (const float*)d_in[5];
    const float* bv  = (const float*)d_in[6];
    const float* Wo  = (const float*)d_in[7];
    const float* bo  = (const float*)d_in[8];
    const float* Wpk = (const float*)d_in[9];
    const float* bpk = (const float*)d_in[10];
    const float* Wpq = (const float*)d_in[11];
    const float* bpq = (const float*)d_in[12];
    const float* rel = (const float*)d_in[13];
    const float* lng = (const float*)d_in[14];
    const float* lnb = (const float*)d_in[15];

    char* ws = (char*)d_ws;
    u16* re_b   = (u16*)(ws + OFF_REB);
    u16* hs_b   = (u16*)(ws + OFF_HSB);
    u16* wt0    = (u16*)(ws + OFF_WT);
    u16* wt1    = (u16*)(ws + OFF_WT + 2097152ull);
    u16* wt2    = (u16*)(ws + OFF_WT + 2ull * 2097152ull);
    u16* wt3    = (u16*)(ws + OFF_WT + 3ull * 2097152ull);
    u16* wt4    = (u16*)(ws + OFF_WT + 4ull * 2097152ull);
    u16* wt5    = (u16*)(ws + OFF_WT + 5ull * 2097152ull);
    u16* Q_b    = (u16*)(ws + OFF_QB);
    u16* K_b    = (u16*)(ws + OFF_KB);
    u16* VT_b   = (u16*)(ws + OFF_VT);
    u16* posk_b = (u16*)(ws + OFF_PKB);
    u16* posq_b = (u16*)(ws + OFF_PQB);
    u16* c2p_b  = (u16*)(ws + OFF_C2P);
    u16* p2cK_b = (u16*)(ws + OFF_P2CK);
    u16* ctx_b  = (u16*)(ws + OFF_CTX);
    short* idx_t = (short*)(ws + OFF_IDX);
    u16* pfar_b = (u16*)(ws + OFF_PF);
    float* oP   = (float*)(ws + OFF_SP);
    float* lP   = (float*)(ws + SP_LBASE);

    dim3 blk(256);
    k_build_idx<<<dim3(4), blk, 0, stream>>>(idx_t);
    k_ln<<<dim3(512), blk, 0, stream>>>(rel, lng, lnb, re_b);
    k_cast<<<dim3(4096), blk, 0, stream>>>(hs, hs_b);
    k_wt6<<<dim3(16, 16, 6), blk, 0, stream>>>(Wq, Wk, Wv, Wo, Wpk, Wpq,
                                               wt0, wt1, wt2, wt3, wt4, wt5);

    // projections
    k_qkv<<<dim3(32, 8, 3), blk, 0, stream>>>(hs_b, wt0, wt1, wt2, bq, bk, bv, Q_b, K_b, VT_b);
    k_gemm2_dual<0><<<dim3(4, 8, 2), blk, 0, stream>>>(re_b, wt4, wt5, bpk, bpq, posk_b, posq_b, H, H);

    // positional score tables (scale incl. log2e folded in)
    k_pos_both<<<dim3(16, 4, 64), blk, 0, stream>>>(Q_b, K_b, posk_b, posq_b, c2p_b, p2cK_b, pfar_b);

    // fused attention (split-K x2 interleaved when workspace allows)
    if (ws_size >= WS_NEED_SPLIT) {
        k_attn<2><<<dim3(64, 32), blk, 0, stream>>>(Q_b, K_b, VT_b, c2p_b, p2cK_b, pfar_b, idx_t, oP, lP, ctx_b);
        k_merge<<<dim3(4096), blk, 0, stream>>>(oP, lP, ctx_b);
    } else {
        k_attn<1><<<dim3(32, 32), blk, 0, stream>>>(Q_b, K_b, VT_b, c2p_b, p2cK_b, pfar_b, idx_t, oP, lP, ctx_b);
    }

    // output projection (fp32 out)
    k_gemm2<1><<<dim3(32, 8), blk, 0, stream>>>(ctx_b, wt3, bo, d_out, H, H);
}

// Round 10
// 365.513 us; speedup vs baseline: 1.0603x; 1.0116x over previous
//
#include <hip/hip_runtime.h>

typedef unsigned short u16;
typedef unsigned int u32;
typedef unsigned long long u64;
typedef __attribute__((ext_vector_type(8))) short short8;
typedef __attribute__((ext_vector_type(4))) float float4v;

#define MFMA16(a, b, c) __builtin_amdgcn_mfma_f32_16x16x32_bf16((a), (b), (c), 0, 0, 0)

// ---------------- helpers ----------------
__device__ __forceinline__ u16 f2b(float x) {
    union { float f; unsigned u; } v; v.f = x;
    unsigned r = v.u + 0x7FFFu + ((v.u >> 16) & 1u);   // RNE
    return (u16)(r >> 16);
}
__device__ __forceinline__ float b2f(u16 u) {
    union { unsigned u; float f; } v; v.u = ((unsigned)u) << 16; return v.f;
}
// pack 2 f32 -> 2 bf16 (RNE) in one instruction
__device__ __forceinline__ u32 cvtpk(float lo, float hi) {
    u32 r;
    asm("v_cvt_pk_bf16_f32 %0, %1, %2" : "=v"(r) : "v"(lo), "v"(hi));
    return r;
}
// async global->LDS, 16 bytes per lane; dest = wave-uniform base + lane*16
__device__ __forceinline__ void gload16(const u16* g, u16* l) {
    __builtin_amdgcn_global_load_lds(
        (__attribute__((address_space(1))) void*)g,
        (__attribute__((address_space(3))) void*)l, 16, 0, 0);
}

// constants
#define NH 16
#define S  2048
#define HD 64
#define H  1024
// scale = 1/sqrt(192) * log2(e)  (exp -> exp2 folded into all score terms)
#define SC 0.10412111829775301f

// ---------------- workspace offsets (bytes) ----------------
#define OFF_REB   0ull
#define OFF_HSB   (OFF_REB  + 1048576ull)
#define OFF_WT    (OFF_HSB  + 8388608ull)
#define OFF_QB    (OFF_WT   + 12582912ull)
#define OFF_KB    (OFF_QB   + 8388608ull)
#define OFF_VT    (OFF_KB   + 8388608ull)
#define OFF_PKB   (OFF_VT   + 8388608ull)
#define OFF_PQB   (OFF_PKB  + 1048576ull)
#define OFF_C2P   (OFF_PQB  + 1048576ull)                // 64 MB [bh][q][512]
#define OFF_P2CK  (OFF_C2P  + 67108864ull)               // 64 MB [bh][k][512]  (k-major)
#define OFF_CTX   (OFF_P2CK + 67108864ull)
#define OFF_IDX   (OFF_CTX  + 8388608ull)
#define OFF_PF    (OFF_IDX  + 8192ull)                   // far columns [2][32][2048] u16 = 256 KB
#define OFF_SP    (OFF_PF   + 262144ull)                 // split-K partials
#define SP_OHALF  4194304ull                             // floats per half (32*2048*64)
#define SP_LBASE  (OFF_SP + 67108864ull)
#define SP_LHALF  65536ull
#define WS_NEED_SPLIT (SP_LBASE + 524288ull)             // ~248.5 MB

// ---------------- idx table for rel in [-512, 511] ----------------
// idx monotone nondecreasing, slope <= 1; clamping rel to [-512,511] is EXACT.
__global__ void k_build_idx(short* __restrict__ t) {
    int i = blockIdx.x * 256 + threadIdx.x;
    if (i >= 1024) return;
    int rel = i - 512;
    float fr = (float)rel;
    float abs_pos = (rel < 128 && rel > -128) ? 127.0f : fabsf(fr);
    const float LOGC = 1.3843393262841284f;  // float32(ln(511/128))
    float log_pos = ceilf(logf(abs_pos * (1.0f / 128.0f)) / LOGC * 127.0f) + 128.0f;
    float sgn = (fr > 0.f) ? 1.f : ((fr < 0.f) ? -1.f : 0.f);
    float bf = (abs_pos <= 128.0f) ? fr : log_pos * sgn;
    int idx = (int)bf + 256;
    idx = idx < 0 ? 0 : (idx > 511 ? 511 : idx);
    t[i] = (short)idx;
}

// ---------------- LayerNorm of rel_emb -> bf16 ----------------
__global__ __launch_bounds__(256) void k_ln(const float* __restrict__ re,
                                            const float* __restrict__ g,
                                            const float* __restrict__ be,
                                            u16* __restrict__ out) {
    int row = blockIdx.x;
    const float4* x4 = (const float4*)(re + (size_t)row * H);
    int tid = threadIdx.x;
    float4 vv = x4[tid];
    float s = vv.x + vv.y + vv.z + vv.w;
    float s2 = vv.x * vv.x + vv.y * vv.y + vv.z * vv.z + vv.w * vv.w;
    for (int m = 1; m < 64; m <<= 1) {
        s += __shfl_xor(s, m, 64);
        s2 += __shfl_xor(s2, m, 64);
    }
    __shared__ float as[4], as2[4];
    if ((tid & 63) == 0) { as[tid >> 6] = s; as2[tid >> 6] = s2; }
    __syncthreads();
    s = as[0] + as[1] + as[2] + as[3];
    s2 = as2[0] + as2[1] + as2[2] + as2[3];
    float mu = s * (1.f / 1024.f);
    float var = s2 * (1.f / 1024.f) - mu * mu;
    float rstd = rsqrtf(var + 1e-5f);
    float4 gg = ((const float4*)g)[tid];
    float4 bb = ((const float4*)be)[tid];
    ushort4 r4;
    r4.x = f2b((vv.x - mu) * rstd * gg.x + bb.x);
    r4.y = f2b((vv.y - mu) * rstd * gg.y + bb.y);
    r4.z = f2b((vv.z - mu) * rstd * gg.z + bb.z);
    r4.w = f2b((vv.w - mu) * rstd * gg.w + bb.w);
    ((ushort4*)(out + (size_t)row * H))[tid] = r4;
}

// ---------------- fp32 -> bf16 cast ----------------
__global__ __launch_bounds__(256) void k_cast(const float* __restrict__ x, u16* __restrict__ y) {
    int i = blockIdx.x * 256 + threadIdx.x;
    float4 v = ((const float4*)x)[i];
    ushort4 r;
    r.x = f2b(v.x); r.y = f2b(v.y); r.z = f2b(v.z); r.w = f2b(v.w);
    ((ushort4*)y)[i] = r;
}

// ---------------- 6x weight transpose + cast ----------------
__global__ __launch_bounds__(256) void k_wt6(const float* __restrict__ W0, const float* __restrict__ W1,
                                             const float* __restrict__ W2, const float* __restrict__ W3,
                                             const float* __restrict__ W4, const float* __restrict__ W5,
                                             u16* __restrict__ T0, u16* __restrict__ T1,
                                             u16* __restrict__ T2, u16* __restrict__ T3,
                                             u16* __restrict__ T4, u16* __restrict__ T5) {
    const float* W; u16* WT;
    switch (blockIdx.z) {
        case 0: W = W0; WT = T0; break;
        case 1: W = W1; WT = T1; break;
        case 2: W = W2; WT = T2; break;
        case 3: W = W3; WT = T3; break;
        case 4: W = W4; WT = T4; break;
        default: W = W5; WT = T5; break;
    }
    __shared__ float t[64][65];
    int k0 = blockIdx.x * 64, n0 = blockIdx.y * 64;
    int tid = threadIdx.x;
#pragma unroll
    for (int i = 0; i < 16; i++) {
        int lin = tid + 256 * i;
        int r = lin >> 6, c = lin & 63;
        t[r][c] = W[(size_t)(k0 + r) * H + n0 + c];
    }
    __syncthreads();
#pragma unroll
    for (int i = 0; i < 16; i++) {
        int lin = tid + 256 * i;
        int r = lin >> 6, c = lin & 63;
        WT[(size_t)(n0 + r) * H + k0 + c] = f2b(t[c][r]);
    }
}

// ---------------- 128x128-tile GEMM core ----------------
// Staging via global_load_lds width=16 (m97 ladder step: compiler never auto-emits it).
// Layout math: thread tid's old store landed at byte tid*16 of As (unpadded [128][32] u16),
// so HW scatter (wave-uniform base + lane*16) with base = As + 1024*w reproduces the
// IDENTICAL LDS layout; per-lane global addresses unchanged. Applies to k_qkv / k_gemm2 /
// k_gemm2_dual. k_pos_both keeps its padded reg-staged path (incompatible layout).
// MODE 0: bf16 row-major; MODE 1: f32 row-major;
// MODE 2: bf16 VT layout (b*1024+n)*2048 + pi2-permuted s within each 64-block
//         (pi2(j) = (j>>5)*32 + (j&15)*2 + ((j>>4)&1); k_attn's P store and PV MFMA
//          use the same permuted k-order, and MFMA sums over k, so this is exact);
// MODE 3: bf16 head-major ((b*16+h)*2048+m)*64+d
template <int MODE>
__device__ __forceinline__ void gemm2_body(const u16* __restrict__ A,
                                           const u16* __restrict__ Bt,
                                           const float* __restrict__ bias,
                                           void* __restrict__ C, int N, int K) {
    __shared__ __align__(16) u16 As[128 * 32];
    __shared__ __align__(16) u16 Bs[128 * 32];
    int tid = threadIdx.x;
    int lane = tid & 63, w = tid >> 6;
    int ln = lane & 15, quad = lane >> 4;
    int m0 = blockIdx.x * 128, n0 = blockIdx.y * 128;
    int wm = (w >> 1) * 64, wn = (w & 1) * 64;
    float4v acc[4][4];
    float4v zero = {0.f, 0.f, 0.f, 0.f};
#pragma unroll
    for (int mi = 0; mi < 4; mi++)
#pragma unroll
        for (int ni = 0; ni < 4; ni++) acc[mi][ni] = zero;

    int r1 = tid >> 2, o1 = (tid & 3) * 8;
    const u16* ga1 = A + (size_t)(m0 + r1) * K + o1;
    const u16* gb1 = Bt + (size_t)(n0 + r1) * K + o1;
    // wave-uniform LDS bases (lane l lands at base + l*16 bytes = original tid*16 layout)
    u16* asw = &As[w * 512];
    u16* bsw = &Bs[w * 512];
    size_t step2 = (size_t)64 * K;

    for (int k0 = 0; k0 < K; k0 += 32) {
        __syncthreads();
        gload16(ga1 + k0,          asw);
        gload16(ga1 + step2 + k0,  asw + 2048);
        gload16(gb1 + k0,          bsw);
        gload16(gb1 + step2 + k0,  bsw + 2048);
        __syncthreads();
        short8 af[4], bf[4];
#pragma unroll
        for (int mi = 0; mi < 4; mi++)
            af[mi] = *(const short8*)&As[(wm + mi * 16 + ln) * 32 + quad * 8];
#pragma unroll
        for (int ni = 0; ni < 4; ni++)
            bf[ni] = *(const short8*)&Bs[(wn + ni * 16 + ln) * 32 + quad * 8];
#pragma unroll
        for (int mi = 0; mi < 4; mi++)
#pragma unroll
            for (int ni = 0; ni < 4; ni++)
                acc[mi][ni] = MFMA16(af[mi], bf[ni], acc[mi][ni]);
    }

#pragma unroll
    for (int mi = 0; mi < 4; mi++) {
        int row0 = m0 + wm + mi * 16 + quad * 4;
#pragma unroll
        for (int ni = 0; ni < 4; ni++) {
            int col = n0 + wn + ni * 16 + ln;
            float bv = bias[col];
            if (MODE == 0) {
                u16* Cb = (u16*)C;
#pragma unroll
                for (int r = 0; r < 4; r++)
                    Cb[(size_t)(row0 + r) * N + col] = f2b(acc[mi][ni][r] + bv);
            } else if (MODE == 1) {
                float* Cf = (float*)C;
#pragma unroll
                for (int r = 0; r < 4; r++)
                    Cf[(size_t)(row0 + r) * N + col] = acc[mi][ni][r] + bv;
            } else if (MODE == 2) {
                u16* Cb = (u16*)C;
                int bb = row0 >> 11, s = row0 & 2047;
                int base64 = s & ~63, j = s & 63;           // j = mi*16 + quad*4 (j%4==0)
                int p0 = ((j >> 5) << 5) + ((j & 15) << 1) + ((j >> 4) & 1);
                u16* dst = Cb + ((size_t)(bb * 1024 + col)) * 2048 + base64;
#pragma unroll
                for (int r = 0; r < 4; r++)
                    dst[p0 + 2 * r] = f2b(acc[mi][ni][r] + bv);
            } else {
                u16* Cb = (u16*)C;
                int bb = row0 >> 11, s = row0 & 2047;
                int h = col >> 6, d = col & 63;
#pragma unroll
                for (int r = 0; r < 4; r++)
                    Cb[((size_t)(bb * 16 + h) * 2048 + s + r) * 64 + d] = f2b(acc[mi][ni][r] + bv);
            }
        }
    }
}

template <int MODE>
__global__ __launch_bounds__(256) void k_gemm2(const u16* __restrict__ A, const u16* __restrict__ Bt,
                                               const float* __restrict__ bias, void* __restrict__ C,
                                               int N, int K) {
    gemm2_body<MODE>(A, Bt, bias, C, N, K);
}

template <int MODE>
__global__ __launch_bounds__(256) void k_gemm2_dual(const u16* __restrict__ A,
                                                    const u16* __restrict__ Bt0, const u16* __restrict__ Bt1,
                                                    const float* __restrict__ b0, const float* __restrict__ b1,
                                                    void* __restrict__ C0, void* __restrict__ C1,
                                                    int N, int K) {
    if (blockIdx.z == 0) gemm2_body<MODE>(A, Bt0, b0, C0, N, K);
    else                 gemm2_body<MODE>(A, Bt1, b1, C1, N, K);
}

// Q/K/V projections in one launch (z: 0=Q head-major, 1=K head-major, 2=V transposed+pi2)
__global__ __launch_bounds__(256) void k_qkv(const u16* __restrict__ A,
                                             const u16* __restrict__ W0, const u16* __restrict__ W1,
                                             const u16* __restrict__ W2,
                                             const float* __restrict__ b0, const float* __restrict__ b1,
                                             const float* __restrict__ b2,
                                             u16* __restrict__ Q, u16* __restrict__ K, u16* __restrict__ VT) {
    if (blockIdx.z == 0)      gemm2_body<3>(A, W0, b0, Q, H, H);
    else if (blockIdx.z == 1) gemm2_body<3>(A, W1, b1, K, H, H);
    else                      gemm2_body<2>(A, W2, b2, VT, H, H);
}

// ---------------- both positional score tables, one launch ----------------
__global__ __launch_bounds__(256) void k_pos_both(const u16* __restrict__ Qh, const u16* __restrict__ Kh,
                                                  const u16* __restrict__ pk, const u16* __restrict__ pq,
                                                  u16* __restrict__ c2p, u16* __restrict__ p2cK,
                                                  u16* __restrict__ pfar) {
    __shared__ __align__(16) u16 smem[2 * 128 * 72];   // As | Bs
    u16* As = smem;
    u16* Bs = smem + 128 * 72;
    int tid = threadIdx.x;
    int lane = tid & 63, w = tid >> 6;
    int ln = lane & 15, quad = lane >> 4;
    int tr = blockIdx.z & 1, z = blockIdx.z >> 1, h = z & 15;
    int m0 = blockIdx.x * 128, n0 = blockIdx.y * 128;
    const u16* A = (tr ? Kh : Qh) + (size_t)z * S * HD;
    const u16* B = (tr ? pq : pk) + h * 64;
    int sr = tid >> 1, scb = (tid & 1) * 32;
    {
        const u16* ga = A + (size_t)(m0 + sr) * HD + scb;
        const u16* gb = B + (size_t)(n0 + sr) * H + scb;
#pragma unroll
        for (int j = 0; j < 4; j++) {
            *(short8*)&As[sr * 72 + scb + j * 8] = *(const short8*)(ga + j * 8);
            *(short8*)&Bs[sr * 72 + scb + j * 8] = *(const short8*)(gb + j * 8);
        }
    }
    __syncthreads();
    int wm = (w >> 1) * 64, wn = (w & 1) * 64;
    float4v acc[4][4];
    float4v zero = {0.f, 0.f, 0.f, 0.f};
#pragma unroll
    for (int mi = 0; mi < 4; mi++)
#pragma unroll
        for (int ni = 0; ni < 4; ni++) acc[mi][ni] = zero;
#pragma unroll
    for (int c = 0; c < 2; c++) {
        short8 af[4], bf[4];
#pragma unroll
        for (int mi = 0; mi < 4; mi++)
            af[mi] = *(const short8*)&As[(wm + mi * 16 + ln) * 72 + c * 32 + quad * 8];
#pragma unroll
        for (int ni = 0; ni < 4; ni++)
            bf[ni] = *(const short8*)&Bs[(wn + ni * 16 + ln) * 72 + c * 32 + quad * 8];
#pragma unroll
        for (int mi = 0; mi < 4; mi++)
#pragma unroll
            for (int ni = 0; ni < 4; ni++)
                acc[mi][ni] = MFMA16(af[mi], bf[ni], acc[mi][ni]);
    }
    u16* Cp = (tr ? p2cK : c2p) + (size_t)z * S * 512;
#pragma unroll
    for (int mi = 0; mi < 4; mi++) {
        int row0 = m0 + wm + mi * 16 + quad * 4;
#pragma unroll
        for (int ni = 0; ni < 4; ni++) {
            int col = n0 + wn + ni * 16 + ln;
#pragma unroll
            for (int r = 0; r < 4; r++)
                Cp[(size_t)(row0 + r) * 512 + col] = f2b(acc[mi][ni][r] * SC);
        }
    }
    if (tr) {
        // far-column extraction (col 0 lives in n0==0 blocks, col 511 in n0==384 blocks)
        if (n0 == 0 && (w & 1) == 0 && ln == 0) {
            u16* dst = pfar + (size_t)z * 2048 + m0 + wm + quad * 4;
#pragma unroll
            for (int mi = 0; mi < 4; mi++)
#pragma unroll
                for (int r = 0; r < 4; r++)
                    dst[mi * 16 + r] = f2b(acc[mi][0][r] * SC);
        }
        if (n0 == 384 && (w & 1) == 1 && ln == 15) {
            u16* dst = pfar + (size_t)(32 + z) * 2048 + m0 + wm + quad * 4;
#pragma unroll
            for (int mi = 0; mi < 4; mi++)
#pragma unroll
                for (int r = 0; r < 4; r++)
                    dst[mi * 16 + r] = f2b(acc[mi][3][r] * SC);
        }
    }
}

// gather c2p+p2c bias for rows r=0..3 at f=F into 4 named floats (no runtime array idx)
#define GATHER_BIAS(F, B0, B1, B2, B3) do {                                          \
    int ki_ = kk + (F) * 16 + ln;                                                    \
    const u16* pvrow_ = p2cB + (size_t)ki_ * 512;                                    \
    int relb_ = qrow - ki_;                                                          \
    int i0_, i1_, i2_, i3_;                                                          \
    { int rel = relb_;     rel = rel < -512 ? -512 : (rel > 511 ? 511 : rel); i0_ = (int)s_idx1[rel + 512]; } \
    { int rel = relb_ + 1; rel = rel < -512 ? -512 : (rel > 511 ? 511 : rel); i1_ = (int)s_idx1[rel + 512]; } \
    { int rel = relb_ + 2; rel = rel < -512 ? -512 : (rel > 511 ? 511 : rel); i2_ = (int)s_idx1[rel + 512]; } \
    { int rel = relb_ + 3; rel = rel < -512 ? -512 : (rel > 511 ? 511 : rel); i3_ = (int)s_idx1[rel + 512]; } \
    const u32* p32_ = (const u32*)pvrow_;                                            \
    int e_ = i0_ >> 1;                                                               \
    u32 wx_ = p32_[e_], wy_ = p32_[e_ + 1], wz_ = p32_[e_ + 2];                      \
    u64 lov_ = (u64)wx_ | ((u64)wy_ << 32);                                          \
    u64 sft_ = (i0_ & 1) ? ((lov_ >> 16) | ((u64)wz_ << 48)) : lov_;                 \
    u16 c0_ = cvrow[0][i0_], c1_ = cvrow[1][i1_], c2_ = cvrow[2][i2_], c3_ = cvrow[3][i3_]; \
    union { u32 u; float f; } q0_, q1_, q2_, q3_;                                    \
    q0_.u = ((u32)(sft_)) << 16;                                                     \
    q1_.u = ((u32)(sft_ >> ((i1_ - i0_) << 4))) << 16;                               \
    q2_.u = ((u32)(sft_ >> ((i2_ - i0_) << 4))) << 16;                               \
    q3_.u = ((u32)(sft_ >> ((i3_ - i0_) << 4))) << 16;                               \
    B0 = b2f(c0_) + q0_.f;                                                           \
    B1 = b2f(c1_) + q1_.f;                                                           \
    B2 = b2f(c2_) + q2_.f;                                                           \
    B3 = b2f(c3_) + q3_.f;                                                           \
} while (0)

// ---------------- fused attention: K/V tiles staged in LDS (shared by 4 waves) ----------------
// P columns and V columns both live in pi2-permuted k-order (V permuted at VT write time):
// each lane's (f,f+1) P values are ADJACENT -> v_cvt_pk_bf16_f32 + single b32 store.
// BYTE-IDENTICAL to the round-9 green kernel (changes this round are gemm2_body-only).
template <int SPLIT>
__global__ __launch_bounds__(256, 4) void k_attn(const u16* __restrict__ Qh,
                                                 const u16* __restrict__ Kh,
                                                 const u16* __restrict__ VT,
                                                 const u16* __restrict__ c2p,
                                                 const u16* __restrict__ p2cK,
                                                 const u16* __restrict__ pfar,
                                                 const short* __restrict__ idxTab,
                                                 float* __restrict__ oP,
                                                 float* __restrict__ lP,
                                                 u16* __restrict__ ctx) {
    __shared__ short s_idx1[1024];
    __shared__ __align__(16) u16 p_lds[4][16][72];
    __shared__ __align__(16) u16 Ks[64][72];
    __shared__ __align__(16) u16 Vs[64][72];
    int tid = threadIdx.x;
    for (int i = tid; i < 1024; i += 256) s_idx1[i] = idxTab[i];
    int lane = tid & 63, w = tid >> 6;
    int ln = lane & 15, quad = lane >> 4;
    int bx = blockIdx.x;
    int half = (SPLIT == 2) ? (bx & 1) : 0;
    int q0 = (SPLIT == 2) ? (bx >> 1) * 64 : bx * 64;
    int bh = blockIdx.y;
    int b = bh >> 4, h = bh & 15;
    int qs = q0 + w * 16;

    const u16* qptr = Qh + ((size_t)bh * S + qs + ln) * HD + quad * 8;
    short8 aq0 = *(const short8*)(qptr);
    short8 aq1 = *(const short8*)(qptr + 32);

    float4v o[4];
    float4v zero = {0.f, 0.f, 0.f, 0.f};
#pragma unroll
    for (int f = 0; f < 4; f++) o[f] = zero;
    float lrw[4] = {0.f, 0.f, 0.f, 0.f};

    const u16* c2pB = c2p + (size_t)bh * S * 512;
    const u16* p2cB = p2cK + (size_t)bh * S * 512;
    int qrow = qs + quad * 4;

    // c2p row pointers: fixed per thread for the whole kernel (16 q-rows per wave -> L1-hot)
    const u16* cvrow[4];
#pragma unroll
    for (int r = 0; r < 4; r++) cvrow[r] = c2pB + (size_t)(qrow + r) * 512;

    // staging map: thread -> (row sr 0..63, col block sc 0..48 step 16)
    int sr = tid >> 2, sc = (tid & 3) * 16;
    const u16* kstg = Kh + ((size_t)bh * S + sr) * HD + sc;              // + kk*HD per tile
    const u16* vstg = VT + (size_t)(b * 1024 + h * 64 + sr) * S + sc;    // + kk per tile (pi2 order)

    const int NT = S / 64 / SPLIT;
    for (int t = 0; t < NT; t++) {
        int kk = (SPLIT == 2) ? (((t << 1) | half) << 6) : (t << 6);
        // ---- stage K,V tile (all waves cooperate) ----
        short8 kr0 = *(const short8*)(kstg + (size_t)kk * HD);
        short8 kr1 = *(const short8*)(kstg + (size_t)kk * HD + 8);
        short8 vr0 = *(const short8*)(vstg + kk);
        short8 vr1 = *(const short8*)(vstg + kk + 8);
        __syncthreads();
        *(short8*)&Ks[sr][sc] = kr0; *(short8*)&Ks[sr][sc + 8] = kr1;
        *(short8*)&Vs[sr][sc] = vr0; *(short8*)&Vs[sr][sc + 8] = vr1;
        __syncthreads();
        // ---- QK^T from LDS ----
        float4v sa[4];
        __builtin_amdgcn_s_setprio(1);
#pragma unroll
        for (int f = 0; f < 4; f++) {
            short8 b0 = *(const short8*)&Ks[f * 16 + ln][quad * 8];
            short8 b1 = *(const short8*)&Ks[f * 16 + ln][32 + quad * 8];
            float4v tt = zero;
            tt = MFMA16(aq0, b0, tt);
            tt = MFMA16(aq1, b1, tt);
            sa[f] = tt;
        }
        __builtin_amdgcn_s_setprio(0);
        // ---- positional bias + exp2 (fixed max 0) ----
        int rel0 = q0 - kk;
        u32* prow0 = (u32*)&p_lds[w][quad * 4][0];
        if (rel0 >= 569 || rel0 <= -633) {
            // far: idx is constant 0 or 511; pv comes from the pre-extracted column.
            int idx = rel0 > 0 ? 511 : 0;
            const u16* pfb = pfar + (rel0 > 0 ? (size_t)(32 + bh) : (size_t)bh) * 2048 + kk;
            float cvr[4], pvf[4];
#pragma unroll
            for (int r = 0; r < 4; r++)
                cvr[r] = b2f(cvrow[r][idx]);
#pragma unroll
            for (int f = 0; f < 4; f++)
                pvf[f] = b2f(pfb[f * 16 + ln]);
#pragma unroll
            for (int u = 0; u < 2; u++) {
#pragma unroll
                for (int r = 0; r < 4; r++) {
                    float p0 = exp2f(sa[2 * u][r] * SC + cvr[r] + pvf[2 * u]);
                    float p1 = exp2f(sa[2 * u + 1][r] * SC + cvr[r] + pvf[2 * u + 1]);
                    lrw[r] += p0 + p1;
                    u32* prow = prow0 + r * 36;
                    prow[u * 16 + ln] = cvtpk(p0, p1);
                }
            }
        } else {
            // near: f-pair phasing — gather 8 bias floats, then exp2+cvtpk+b32 store.
            // (keeps liveness low: the round-3 bias[4][4] buffer spilled to scratch)
#pragma unroll
            for (int u = 0; u < 2; u++) {
                float ba0, ba1, ba2, ba3, bb0, bb1, bb2, bb3;
                GATHER_BIAS(2 * u, ba0, ba1, ba2, ba3);
                GATHER_BIAS(2 * u + 1, bb0, bb1, bb2, bb3);
                float p0, p1;
                p0 = exp2f(sa[2 * u][0] * SC + ba0);
                p1 = exp2f(sa[2 * u + 1][0] * SC + bb0);
                lrw[0] += p0 + p1;
                prow0[0 * 36 + u * 16 + ln] = cvtpk(p0, p1);
                p0 = exp2f(sa[2 * u][1] * SC + ba1);
                p1 = exp2f(sa[2 * u + 1][1] * SC + bb1);
                lrw[1] += p0 + p1;
                prow0[1 * 36 + u * 16 + ln] = cvtpk(p0, p1);
                p0 = exp2f(sa[2 * u][2] * SC + ba2);
                p1 = exp2f(sa[2 * u + 1][2] * SC + bb2);
                lrw[2] += p0 + p1;
                prow0[2 * 36 + u * 16 + ln] = cvtpk(p0, p1);
                p0 = exp2f(sa[2 * u][3] * SC + ba3);
                p1 = exp2f(sa[2 * u + 1][3] * SC + bb3);
                lrw[3] += p0 + p1;
                prow0[3 * 36 + u * 16 + ln] = cvtpk(p0, p1);
            }
        }
        // ---- PV from LDS (own-wave P slice, no extra barrier; pi2-consistent) ----
        short8 ap0 = *(const short8*)&p_lds[w][ln][quad * 8];
        short8 ap1 = *(const short8*)&p_lds[w][ln][32 + quad * 8];
        __builtin_amdgcn_s_setprio(1);
#pragma unroll
        for (int f = 0; f < 4; f++) {
            short8 v0 = *(const short8*)&Vs[f * 16 + ln][quad * 8];
            short8 v1 = *(const short8*)&Vs[f * 16 + ln][32 + quad * 8];
            o[f] = MFMA16(ap0, v0, o[f]);
            o[f] = MFMA16(ap1, v1, o[f]);
        }
        __builtin_amdgcn_s_setprio(0);
    }
    // ---- single end-of-loop l reduction (within 16-lane quad) ----
#pragma unroll
    for (int r = 0; r < 4; r++) {
        lrw[r] += __shfl_xor(lrw[r], 1, 16);
        lrw[r] += __shfl_xor(lrw[r], 2, 16);
        lrw[r] += __shfl_xor(lrw[r], 4, 16);
        lrw[r] += __shfl_xor(lrw[r], 8, 16);
    }
    if (SPLIT == 1) {
        float inv_l[4];
#pragma unroll
        for (int r = 0; r < 4; r++) inv_l[r] = 1.f / lrw[r];
#pragma unroll
        for (int f = 0; f < 4; f++)
#pragma unroll
            for (int r = 0; r < 4; r++) {
                int qi = qs + quad * 4 + r;
                ctx[(size_t)(b * S + qi) * H + h * 64 + f * 16 + ln] = f2b(o[f][r] * inv_l[r]);
            }
    } else {
        float* oH = oP + (size_t)half * SP_OHALF;
#pragma unroll
        for (int f = 0; f < 4; f++)
#pragma unroll
            for (int r = 0; r < 4; r++) {
                int qi = qs + quad * 4 + r;
                oH[((size_t)bh * S + qi) * 64 + f * 16 + ln] = o[f][r];
            }
        if (ln == 0) {
            float* lH = lP + (size_t)half * SP_LHALF;
#pragma unroll
            for (int r = 0; r < 4; r++)
                lH[(size_t)bh * S + qs + quad * 4 + r] = lrw[r];
        }
    }
}

// ---------------- merge split-K partials -> ctx bf16 ----------------
__global__ __launch_bounds__(256) void k_merge(const float* __restrict__ oP,
                                               const float* __restrict__ lP,
                                               u16* __restrict__ ctx) {
    int t = blockIdx.x * 256 + threadIdx.x;
    int d4 = (t & 15) * 4;
    int h  = (t >> 4) & 15;
    int qq = (t >> 8) & 2047;
    int b  = t >> 19;
    int bh = b * 16 + h;
    size_t base = ((size_t)bh * S + qq) * 64 + d4;
    float4 o0 = *(const float4*)(oP + base);
    float4 o1 = *(const float4*)(oP + SP_OHALF + base);
    float l0 = lP[(size_t)bh * S + qq];
    float l1 = lP[SP_LHALF + (size_t)bh * S + qq];
    float inv = 1.f / (l0 + l1);
    ushort4 r4;
    r4.x = f2b((o0.x + o1.x) * inv);
    r4.y = f2b((o0.y + o1.y) * inv);
    r4.z = f2b((o0.z + o1.z) * inv);
    r4.w = f2b((o0.w + o1.w) * inv);
    *(ushort4*)(ctx + (((size_t)(b * S + qq)) * 16 + h) * 64 + d4) = r4;
}

// ---------------- launch ----------------
extern "C" void kernel_launch(void* const* d_in, const int* in_sizes, int n_in,
                              void* d_out, int out_size, void* d_ws, size_t ws_size,
                              hipStream_t stream) {
    const float* hs  = (const float*)d_in[0];
    const float* Wq  = (const float*)d_in[1];
    const float* bq  = (const float*)d_in[2];
    const float* Wk  = (const float*)d_in[3];
    const float* bk  = (const float*)d_in[4];
    const float* Wv  = (const float*)d_in[5];
    const float* bv  = (const float*)d_in[6];
    const float* Wo  = (const float*)d_in[7];
    const float* bo  = (const float*)d_in[8];
    const float* Wpk = (const float*)d_in[9];
    const float* bpk = (const float*)d_in[10];
    const float* Wpq = (const float*)d_in[11];
    const float* bpq = (const float*)d_in[12];
    const float* rel = (const float*)d_in[13];
    const float* lng = (const float*)d_in[14];
    const float* lnb = (const float*)d_in[15];

    char* ws = (char*)d_ws;
    u16* re_b   = (u16*)(ws + OFF_REB);
    u16* hs_b   = (u16*)(ws + OFF_HSB);
    u16* wt0    = (u16*)(ws + OFF_WT);
    u16* wt1    = (u16*)(ws + OFF_WT + 2097152ull);
    u16* wt2    = (u16*)(ws + OFF_WT + 2ull * 2097152ull);
    u16* wt3    = (u16*)(ws + OFF_WT + 3ull * 2097152ull);
    u16* wt4    = (u16*)(ws + OFF_WT + 4ull * 2097152ull);
    u16* wt5    = (u16*)(ws + OFF_WT + 5ull * 2097152ull);
    u16* Q_b    = (u16*)(ws + OFF_QB);
    u16* K_b    = (u16*)(ws + OFF_KB);
    u16* VT_b   = (u16*)(ws + OFF_VT);
    u16* posk_b = (u16*)(ws + OFF_PKB);
    u16* posq_b = (u16*)(ws + OFF_PQB);
    u16* c2p_b  = (u16*)(ws + OFF_C2P);
    u16* p2cK_b = (u16*)(ws + OFF_P2CK);
    u16* ctx_b  = (u16*)(ws + OFF_CTX);
    short* idx_t = (short*)(ws + OFF_IDX);
    u16* pfar_b = (u16*)(ws + OFF_PF);
    float* oP   = (float*)(ws + OFF_SP);
    float* lP   = (float*)(ws + SP_LBASE);

    dim3 blk(256);
    k_build_idx<<<dim3(4), blk, 0, stream>>>(idx_t);
    k_ln<<<dim3(512), blk, 0, stream>>>(rel, lng, lnb, re_b);
    k_cast<<<dim3(4096), blk, 0, stream>>>(hs, hs_b);
    k_wt6<<<dim3(16, 16, 6), blk, 0, stream>>>(Wq, Wk, Wv, Wo, Wpk, Wpq,
                                               wt0, wt1, wt2, wt3, wt4, wt5);

    // projections
    k_qkv<<<dim3(32, 8, 3), blk, 0, stream>>>(hs_b, wt0, wt1, wt2, bq, bk, bv, Q_b, K_b, VT_b);
    k_gemm2_dual<0><<<dim3(4, 8, 2), blk, 0, stream>>>(re_b, wt4, wt5, bpk, bpq, posk_b, posq_b, H, H);

    // positional score tables (scale incl. log2e folded in)
    k_pos_both<<<dim3(16, 4, 64), blk, 0, stream>>>(Q_b, K_b, posk_b, posq_b, c2p_b, p2cK_b, pfar_b);

    // fused attention (split-K x2 interleaved when workspace allows)
    if (ws_size >= WS_NEED_SPLIT) {
        k_attn<2><<<dim3(64, 32), blk, 0, stream>>>(Q_b, K_b, VT_b, c2p_b, p2cK_b, pfar_b, idx_t, oP, lP, ctx_b);
        k_merge<<<dim3(4096), blk, 0, stream>>>(oP, lP, ctx_b);
    } else {
        k_attn<1><<<dim3(32, 32), blk, 0, stream>>>(Q_b, K_b, VT_b, c2p_b, p2cK_b, pfar_b, idx_t, oP, lP, ctx_b);
    }

    // output projection (fp32 out)
    k_gemm2<1><<<dim3(32, 8), blk, 0, stream>>>(ctx_b, wt3, bo, d_out, H, H);
}

// Round 11
// 358.497 us; speedup vs baseline: 1.0810x; 1.0196x over previous
//
#include <hip/hip_runtime.h>

typedef unsigned short u16;
typedef unsigned int u32;
typedef unsigned long long u64;
typedef __attribute__((ext_vector_type(8))) short short8;
typedef __attribute__((ext_vector_type(4))) float float4v;

#define MFMA16(a, b, c) __builtin_amdgcn_mfma_f32_16x16x32_bf16((a), (b), (c), 0, 0, 0)

// ---------------- helpers ----------------
__device__ __forceinline__ u16 f2b(float x) {
    union { float f; unsigned u; } v; v.f = x;
    unsigned r = v.u + 0x7FFFu + ((v.u >> 16) & 1u);   // RNE
    return (u16)(r >> 16);
}
__device__ __forceinline__ float b2f(u16 u) {
    union { unsigned u; float f; } v; v.u = ((unsigned)u) << 16; return v.f;
}
// pack 2 f32 -> 2 bf16 (RNE) in one instruction
__device__ __forceinline__ u32 cvtpk(float lo, float hi) {
    u32 r;
    asm("v_cvt_pk_bf16_f32 %0, %1, %2" : "=v"(r) : "v"(lo), "v"(hi));
    return r;
}
// async global->LDS, 16 bytes per lane; dest = wave-uniform base + lane*16
__device__ __forceinline__ void gload16(const u16* g, u16* l) {
    __builtin_amdgcn_global_load_lds(
        (__attribute__((address_space(1))) void*)g,
        (__attribute__((address_space(3))) void*)l, 16, 0, 0);
}

// constants
#define NH 16
#define S  2048
#define HD 64
#define H  1024
// scale = 1/sqrt(192) * log2(e)  (exp -> exp2 folded into all score terms)
#define SC 0.10412111829775301f

// ---------------- workspace offsets (bytes) ----------------
#define OFF_REB   0ull
#define OFF_HSB   (OFF_REB  + 1048576ull)
#define OFF_WT    (OFF_HSB  + 8388608ull)
#define OFF_QB    (OFF_WT   + 12582912ull)
#define OFF_KB    (OFF_QB   + 8388608ull)
#define OFF_VT    (OFF_KB   + 8388608ull)
#define OFF_PKB   (OFF_VT   + 8388608ull)
#define OFF_PQB   (OFF_PKB  + 1048576ull)
#define OFF_C2P   (OFF_PQB  + 1048576ull)                // 64 MB [bh][q][512]
#define OFF_P2CK  (OFF_C2P  + 67108864ull)               // 64 MB [bh][k][512]  (k-major)
#define OFF_CTX   (OFF_P2CK + 67108864ull)
#define OFF_IDX   (OFF_CTX  + 8388608ull)
#define OFF_PF    (OFF_IDX  + 8192ull)                   // far columns [2][32][2048] u16 = 256 KB
#define OFF_SP    (OFF_PF   + 262144ull)                 // split-K partials
#define SP_OHALF  4194304ull                             // floats per half (32*2048*64)
#define SP_LBASE  (OFF_SP + 67108864ull)
#define SP_LHALF  65536ull
#define WS_NEED_SPLIT (SP_LBASE + 524288ull)             // ~248.5 MB

// ---------------- fused preprocessing: cast | wt6 | ln | idx-table ----------------
// One launch instead of four (all four are mutually independent; whole blocks branch
// uniformly). Block ranges: [0,4096) cast, [4096,5632) wt6, [5632,6144) ln, [6144,6148) idx.
__global__ __launch_bounds__(256) void k_pre(const float* __restrict__ hs, u16* __restrict__ hsb,
                                             const float* __restrict__ W0, const float* __restrict__ W1,
                                             const float* __restrict__ W2, const float* __restrict__ W3,
                                             const float* __restrict__ W4, const float* __restrict__ W5,
                                             u16* __restrict__ T0, u16* __restrict__ T1,
                                             u16* __restrict__ T2, u16* __restrict__ T3,
                                             u16* __restrict__ T4, u16* __restrict__ T5,
                                             const float* __restrict__ re, const float* __restrict__ g,
                                             const float* __restrict__ be, u16* __restrict__ reb,
                                             short* __restrict__ idxt) {
    __shared__ float t[64][65];          // wt6 tile (union; others use none / tiny)
    __shared__ float as[4], as2[4];      // ln partials
    int bx = blockIdx.x, tid = threadIdx.x;
    if (bx < 4096) {
        // ---- fp32 -> bf16 cast of hidden_states ----
        int i = bx * 256 + tid;
        float4 v = ((const float4*)hs)[i];
        ushort4 r;
        r.x = f2b(v.x); r.y = f2b(v.y); r.z = f2b(v.z); r.w = f2b(v.w);
        ((ushort4*)hsb)[i] = r;
    } else if (bx < 5632) {
        // ---- 6x weight transpose + cast ----
        int idx = bx - 4096;
        int mz = idx >> 8, rem = idx & 255;
        int k0 = (rem >> 4) * 64, n0 = (rem & 15) * 64;
        const float* W; u16* WT;
        switch (mz) {
            case 0: W = W0; WT = T0; break;
            case 1: W = W1; WT = T1; break;
            case 2: W = W2; WT = T2; break;
            case 3: W = W3; WT = T3; break;
            case 4: W = W4; WT = T4; break;
            default: W = W5; WT = T5; break;
        }
#pragma unroll
        for (int i = 0; i < 16; i++) {
            int lin = tid + 256 * i;
            int r = lin >> 6, c = lin & 63;
            t[r][c] = W[(size_t)(k0 + r) * H + n0 + c];
        }
        __syncthreads();
#pragma unroll
        for (int i = 0; i < 16; i++) {
            int lin = tid + 256 * i;
            int r = lin >> 6, c = lin & 63;
            WT[(size_t)(n0 + r) * H + k0 + c] = f2b(t[c][r]);
        }
    } else if (bx < 6144) {
        // ---- LayerNorm of rel_emb -> bf16 ----
        int row = bx - 5632;
        const float4* x4 = (const float4*)(re + (size_t)row * H);
        float4 vv = x4[tid];
        float s = vv.x + vv.y + vv.z + vv.w;
        float s2 = vv.x * vv.x + vv.y * vv.y + vv.z * vv.z + vv.w * vv.w;
        for (int m = 1; m < 64; m <<= 1) {
            s += __shfl_xor(s, m, 64);
            s2 += __shfl_xor(s2, m, 64);
        }
        if ((tid & 63) == 0) { as[tid >> 6] = s; as2[tid >> 6] = s2; }
        __syncthreads();
        s = as[0] + as[1] + as[2] + as[3];
        s2 = as2[0] + as2[1] + as2[2] + as2[3];
        float mu = s * (1.f / 1024.f);
        float var = s2 * (1.f / 1024.f) - mu * mu;
        float rstd = rsqrtf(var + 1e-5f);
        float4 gg = ((const float4*)g)[tid];
        float4 bb = ((const float4*)be)[tid];
        ushort4 r4;
        r4.x = f2b((vv.x - mu) * rstd * gg.x + bb.x);
        r4.y = f2b((vv.y - mu) * rstd * gg.y + bb.y);
        r4.z = f2b((vv.z - mu) * rstd * gg.z + bb.z);
        r4.w = f2b((vv.w - mu) * rstd * gg.w + bb.w);
        ((ushort4*)(reb + (size_t)row * H))[tid] = r4;
    } else {
        // ---- idx table for rel in [-512, 511] (monotone, slope<=1; clamp EXACT) ----
        int i = (bx - 6144) * 256 + tid;
        if (i >= 1024) return;
        int rel = i - 512;
        float fr = (float)rel;
        float abs_pos = (rel < 128 && rel > -128) ? 127.0f : fabsf(fr);
        const float LOGC = 1.3843393262841284f;  // float32(ln(511/128))
        float log_pos = ceilf(logf(abs_pos * (1.0f / 128.0f)) / LOGC * 127.0f) + 128.0f;
        float sgn = (fr > 0.f) ? 1.f : ((fr < 0.f) ? -1.f : 0.f);
        float bf = (abs_pos <= 128.0f) ? fr : log_pos * sgn;
        int ix = (int)bf + 256;
        ix = ix < 0 ? 0 : (ix > 511 ? 511 : ix);
        idxt[i] = (short)ix;
    }
}

// ---------------- 128x128-tile GEMM core ----------------
// Staging via global_load_lds width=16 (m97 ladder step: compiler never auto-emits it).
// Layout math: thread tid's store lands at byte tid*16 of As (unpadded [128][32] u16), so
// HW scatter (wave-uniform base + lane*16) with base = As + 1024*w reproduces the layout.
// MODE 0: bf16 row-major; MODE 1: f32 row-major;
// MODE 2: bf16 VT layout (b*1024+n)*2048 + pi2-permuted s within each 64-block
//         (pi2(j) = (j>>5)*32 + (j&15)*2 + ((j>>4)&1); k_attn's P store and PV MFMA
//          use the same permuted k-order, and MFMA sums over k, so this is exact);
// MODE 3: bf16 head-major ((b*16+h)*2048+m)*64+d
template <int MODE>
__device__ __forceinline__ void gemm2_body(const u16* __restrict__ A,
                                           const u16* __restrict__ Bt,
                                           const float* __restrict__ bias,
                                           void* __restrict__ C, int N, int K) {
    __shared__ __align__(16) u16 As[128 * 32];
    __shared__ __align__(16) u16 Bs[128 * 32];
    int tid = threadIdx.x;
    int lane = tid & 63, w = tid >> 6;
    int ln = lane & 15, quad = lane >> 4;
    int m0 = blockIdx.x * 128, n0 = blockIdx.y * 128;
    int wm = (w >> 1) * 64, wn = (w & 1) * 64;
    float4v acc[4][4];
    float4v zero = {0.f, 0.f, 0.f, 0.f};
#pragma unroll
    for (int mi = 0; mi < 4; mi++)
#pragma unroll
        for (int ni = 0; ni < 4; ni++) acc[mi][ni] = zero;

    int r1 = tid >> 2, o1 = (tid & 3) * 8;
    const u16* ga1 = A + (size_t)(m0 + r1) * K + o1;
    const u16* gb1 = Bt + (size_t)(n0 + r1) * K + o1;
    // wave-uniform LDS bases (lane l lands at base + l*16 bytes = original tid*16 layout)
    u16* asw = &As[w * 512];
    u16* bsw = &Bs[w * 512];
    size_t step2 = (size_t)64 * K;

    for (int k0 = 0; k0 < K; k0 += 32) {
        __syncthreads();
        gload16(ga1 + k0,          asw);
        gload16(ga1 + step2 + k0,  asw + 2048);
        gload16(gb1 + k0,          bsw);
        gload16(gb1 + step2 + k0,  bsw + 2048);
        __syncthreads();
        short8 af[4], bf[4];
#pragma unroll
        for (int mi = 0; mi < 4; mi++)
            af[mi] = *(const short8*)&As[(wm + mi * 16 + ln) * 32 + quad * 8];
#pragma unroll
        for (int ni = 0; ni < 4; ni++)
            bf[ni] = *(const short8*)&Bs[(wn + ni * 16 + ln) * 32 + quad * 8];
#pragma unroll
        for (int mi = 0; mi < 4; mi++)
#pragma unroll
            for (int ni = 0; ni < 4; ni++)
                acc[mi][ni] = MFMA16(af[mi], bf[ni], acc[mi][ni]);
    }

#pragma unroll
    for (int mi = 0; mi < 4; mi++) {
        int row0 = m0 + wm + mi * 16 + quad * 4;
#pragma unroll
        for (int ni = 0; ni < 4; ni++) {
            int col = n0 + wn + ni * 16 + ln;
            float bv = bias[col];
            if (MODE == 0) {
                u16* Cb = (u16*)C;
#pragma unroll
                for (int r = 0; r < 4; r++)
                    Cb[(size_t)(row0 + r) * N + col] = f2b(acc[mi][ni][r] + bv);
            } else if (MODE == 1) {
                float* Cf = (float*)C;
#pragma unroll
                for (int r = 0; r < 4; r++)
                    Cf[(size_t)(row0 + r) * N + col] = acc[mi][ni][r] + bv;
            } else if (MODE == 2) {
                u16* Cb = (u16*)C;
                int bb = row0 >> 11, s = row0 & 2047;
                int base64 = s & ~63, j = s & 63;           // j = mi*16 + quad*4 (j%4==0)
                int p0 = ((j >> 5) << 5) + ((j & 15) << 1) + ((j >> 4) & 1);
                u16* dst = Cb + ((size_t)(bb * 1024 + col)) * 2048 + base64;
#pragma unroll
                for (int r = 0; r < 4; r++)
                    dst[p0 + 2 * r] = f2b(acc[mi][ni][r] + bv);
            } else {
                u16* Cb = (u16*)C;
                int bb = row0 >> 11, s = row0 & 2047;
                int h = col >> 6, d = col & 63;
#pragma unroll
                for (int r = 0; r < 4; r++)
                    Cb[((size_t)(bb * 16 + h) * 2048 + s + r) * 64 + d] = f2b(acc[mi][ni][r] + bv);
            }
        }
    }
}

template <int MODE>
__global__ __launch_bounds__(256) void k_gemm2(const u16* __restrict__ A, const u16* __restrict__ Bt,
                                               const float* __restrict__ bias, void* __restrict__ C,
                                               int N, int K) {
    gemm2_body<MODE>(A, Bt, bias, C, N, K);
}

// Q/K/V projections AND both positional-embedding GEMMs in ONE launch.
// z: 0=Q head-major, 1=K head-major, 2=V transposed+pi2, 3=posk (bx<4), 4=posq (bx<4).
// Previously the pos GEMMs (64 blocks, 25% CU coverage) ran fully serialized AFTER qkv;
// fused they fill idle CUs concurrently.
__global__ __launch_bounds__(256) void k_qkvpos(const u16* __restrict__ A,
                                                const u16* __restrict__ W0, const u16* __restrict__ W1,
                                                const u16* __restrict__ W2,
                                                const float* __restrict__ b0, const float* __restrict__ b1,
                                                const float* __restrict__ b2,
                                                u16* __restrict__ Q, u16* __restrict__ K, u16* __restrict__ VT,
                                                const u16* __restrict__ RE,
                                                const u16* __restrict__ W4, const u16* __restrict__ W5,
                                                const float* __restrict__ b4, const float* __restrict__ b5,
                                                u16* __restrict__ PK, u16* __restrict__ PQ) {
    int z = blockIdx.z;
    if (z == 0)      gemm2_body<3>(A, W0, b0, Q, H, H);
    else if (z == 1) gemm2_body<3>(A, W1, b1, K, H, H);
    else if (z == 2) gemm2_body<2>(A, W2, b2, VT, H, H);
    else if (z == 3) { if (blockIdx.x >= 4) return; gemm2_body<0>(RE, W4, b4, PK, H, H); }
    else             { if (blockIdx.x >= 4) return; gemm2_body<0>(RE, W5, b5, PQ, H, H); }
}

// ---------------- both positional score tables, one launch ----------------
__global__ __launch_bounds__(256) void k_pos_both(const u16* __restrict__ Qh, const u16* __restrict__ Kh,
                                                  const u16* __restrict__ pk, const u16* __restrict__ pq,
                                                  u16* __restrict__ c2p, u16* __restrict__ p2cK,
                                                  u16* __restrict__ pfar) {
    __shared__ __align__(16) u16 smem[2 * 128 * 72];   // As | Bs
    u16* As = smem;
    u16* Bs = smem + 128 * 72;
    int tid = threadIdx.x;
    int lane = tid & 63, w = tid >> 6;
    int ln = lane & 15, quad = lane >> 4;
    int tr = blockIdx.z & 1, z = blockIdx.z >> 1, h = z & 15;
    int m0 = blockIdx.x * 128, n0 = blockIdx.y * 128;
    const u16* A = (tr ? Kh : Qh) + (size_t)z * S * HD;
    const u16* B = (tr ? pq : pk) + h * 64;
    int sr = tid >> 1, scb = (tid & 1) * 32;
    {
        const u16* ga = A + (size_t)(m0 + sr) * HD + scb;
        const u16* gb = B + (size_t)(n0 + sr) * H + scb;
#pragma unroll
        for (int j = 0; j < 4; j++) {
            *(short8*)&As[sr * 72 + scb + j * 8] = *(const short8*)(ga + j * 8);
            *(short8*)&Bs[sr * 72 + scb + j * 8] = *(const short8*)(gb + j * 8);
        }
    }
    __syncthreads();
    int wm = (w >> 1) * 64, wn = (w & 1) * 64;
    float4v acc[4][4];
    float4v zero = {0.f, 0.f, 0.f, 0.f};
#pragma unroll
    for (int mi = 0; mi < 4; mi++)
#pragma unroll
        for (int ni = 0; ni < 4; ni++) acc[mi][ni] = zero;
#pragma unroll
    for (int c = 0; c < 2; c++) {
        short8 af[4], bf[4];
#pragma unroll
        for (int mi = 0; mi < 4; mi++)
            af[mi] = *(const short8*)&As[(wm + mi * 16 + ln) * 72 + c * 32 + quad * 8];
#pragma unroll
        for (int ni = 0; ni < 4; ni++)
            bf[ni] = *(const short8*)&Bs[(wn + ni * 16 + ln) * 72 + c * 32 + quad * 8];
#pragma unroll
        for (int mi = 0; mi < 4; mi++)
#pragma unroll
            for (int ni = 0; ni < 4; ni++)
                acc[mi][ni] = MFMA16(af[mi], bf[ni], acc[mi][ni]);
    }
    u16* Cp = (tr ? p2cK : c2p) + (size_t)z * S * 512;
#pragma unroll
    for (int mi = 0; mi < 4; mi++) {
        int row0 = m0 + wm + mi * 16 + quad * 4;
#pragma unroll
        for (int ni = 0; ni < 4; ni++) {
            int col = n0 + wn + ni * 16 + ln;
#pragma unroll
            for (int r = 0; r < 4; r++)
                Cp[(size_t)(row0 + r) * 512 + col] = f2b(acc[mi][ni][r] * SC);
        }
    }
    if (tr) {
        // far-column extraction (col 0 lives in n0==0 blocks, col 511 in n0==384 blocks)
        if (n0 == 0 && (w & 1) == 0 && ln == 0) {
            u16* dst = pfar + (size_t)z * 2048 + m0 + wm + quad * 4;
#pragma unroll
            for (int mi = 0; mi < 4; mi++)
#pragma unroll
                for (int r = 0; r < 4; r++)
                    dst[mi * 16 + r] = f2b(acc[mi][0][r] * SC);
        }
        if (n0 == 384 && (w & 1) == 1 && ln == 15) {
            u16* dst = pfar + (size_t)(32 + z) * 2048 + m0 + wm + quad * 4;
#pragma unroll
            for (int mi = 0; mi < 4; mi++)
#pragma unroll
                for (int r = 0; r < 4; r++)
                    dst[mi * 16 + r] = f2b(acc[mi][3][r] * SC);
        }
    }
}

// gather c2p+p2c bias for rows r=0..3 at f=F into 4 named floats (no runtime array idx)
#define GATHER_BIAS(F, B0, B1, B2, B3) do {                                          \
    int ki_ = kk + (F) * 16 + ln;                                                    \
    const u16* pvrow_ = p2cB + (size_t)ki_ * 512;                                    \
    int relb_ = qrow - ki_;                                                          \
    int i0_, i1_, i2_, i3_;                                                          \
    { int rel = relb_;     rel = rel < -512 ? -512 : (rel > 511 ? 511 : rel); i0_ = (int)s_idx1[rel + 512]; } \
    { int rel = relb_ + 1; rel = rel < -512 ? -512 : (rel > 511 ? 511 : rel); i1_ = (int)s_idx1[rel + 512]; } \
    { int rel = relb_ + 2; rel = rel < -512 ? -512 : (rel > 511 ? 511 : rel); i2_ = (int)s_idx1[rel + 512]; } \
    { int rel = relb_ + 3; rel = rel < -512 ? -512 : (rel > 511 ? 511 : rel); i3_ = (int)s_idx1[rel + 512]; } \
    const u32* p32_ = (const u32*)pvrow_;                                            \
    int e_ = i0_ >> 1;                                                               \
    u32 wx_ = p32_[e_], wy_ = p32_[e_ + 1], wz_ = p32_[e_ + 2];                      \
    u64 lov_ = (u64)wx_ | ((u64)wy_ << 32);                                          \
    u64 sft_ = (i0_ & 1) ? ((lov_ >> 16) | ((u64)wz_ << 48)) : lov_;                 \
    u16 c0_ = cvrow[0][i0_], c1_ = cvrow[1][i1_], c2_ = cvrow[2][i2_], c3_ = cvrow[3][i3_]; \
    union { u32 u; float f; } q0_, q1_, q2_, q3_;                                    \
    q0_.u = ((u32)(sft_)) << 16;                                                     \
    q1_.u = ((u32)(sft_ >> ((i1_ - i0_) << 4))) << 16;                               \
    q2_.u = ((u32)(sft_ >> ((i2_ - i0_) << 4))) << 16;                               \
    q3_.u = ((u32)(sft_ >> ((i3_ - i0_) << 4))) << 16;                               \
    B0 = b2f(c0_) + q0_.f;                                                           \
    B1 = b2f(c1_) + q1_.f;                                                           \
    B2 = b2f(c2_) + q2_.f;                                                           \
    B3 = b2f(c3_) + q3_.f;                                                           \
} while (0)

// ---------------- fused attention: K/V tiles staged in LDS (shared by 4 waves) ----------------
// P columns and V columns both live in pi2-permuted k-order (V permuted at VT write time):
// each lane's (f,f+1) P values are ADJACENT -> v_cvt_pk_bf16_f32 + single b32 store.
// BYTE-IDENTICAL to the round-9/10 green kernel (changes this round are dispatch-only).
template <int SPLIT>
__global__ __launch_bounds__(256, 4) void k_attn(const u16* __restrict__ Qh,
                                                 const u16* __restrict__ Kh,
                                                 const u16* __restrict__ VT,
                                                 const u16* __restrict__ c2p,
                                                 const u16* __restrict__ p2cK,
                                                 const u16* __restrict__ pfar,
                                                 const short* __restrict__ idxTab,
                                                 float* __restrict__ oP,
                                                 float* __restrict__ lP,
                                                 u16* __restrict__ ctx) {
    __shared__ short s_idx1[1024];
    __shared__ __align__(16) u16 p_lds[4][16][72];
    __shared__ __align__(16) u16 Ks[64][72];
    __shared__ __align__(16) u16 Vs[64][72];
    int tid = threadIdx.x;
    for (int i = tid; i < 1024; i += 256) s_idx1[i] = idxTab[i];
    int lane = tid & 63, w = tid >> 6;
    int ln = lane & 15, quad = lane >> 4;
    int bx = blockIdx.x;
    int half = (SPLIT == 2) ? (bx & 1) : 0;
    int q0 = (SPLIT == 2) ? (bx >> 1) * 64 : bx * 64;
    int bh = blockIdx.y;
    int b = bh >> 4, h = bh & 15;
    int qs = q0 + w * 16;

    const u16* qptr = Qh + ((size_t)bh * S + qs + ln) * HD + quad * 8;
    short8 aq0 = *(const short8*)(qptr);
    short8 aq1 = *(const short8*)(qptr + 32);

    float4v o[4];
    float4v zero = {0.f, 0.f, 0.f, 0.f};
#pragma unroll
    for (int f = 0; f < 4; f++) o[f] = zero;
    float lrw[4] = {0.f, 0.f, 0.f, 0.f};

    const u16* c2pB = c2p + (size_t)bh * S * 512;
    const u16* p2cB = p2cK + (size_t)bh * S * 512;
    int qrow = qs + quad * 4;

    // c2p row pointers: fixed per thread for the whole kernel (16 q-rows per wave -> L1-hot)
    const u16* cvrow[4];
#pragma unroll
    for (int r = 0; r < 4; r++) cvrow[r] = c2pB + (size_t)(qrow + r) * 512;

    // staging map: thread -> (row sr 0..63, col block sc 0..48 step 16)
    int sr = tid >> 2, sc = (tid & 3) * 16;
    const u16* kstg = Kh + ((size_t)bh * S + sr) * HD + sc;              // + kk*HD per tile
    const u16* vstg = VT + (size_t)(b * 1024 + h * 64 + sr) * S + sc;    // + kk per tile (pi2 order)

    const int NT = S / 64 / SPLIT;
    for (int t = 0; t < NT; t++) {
        int kk = (SPLIT == 2) ? (((t << 1) | half) << 6) : (t << 6);
        // ---- stage K,V tile (all waves cooperate) ----
        short8 kr0 = *(const short8*)(kstg + (size_t)kk * HD);
        short8 kr1 = *(const short8*)(kstg + (size_t)kk * HD + 8);
        short8 vr0 = *(const short8*)(vstg + kk);
        short8 vr1 = *(const short8*)(vstg + kk + 8);
        __syncthreads();
        *(short8*)&Ks[sr][sc] = kr0; *(short8*)&Ks[sr][sc + 8] = kr1;
        *(short8*)&Vs[sr][sc] = vr0; *(short8*)&Vs[sr][sc + 8] = vr1;
        __syncthreads();
        // ---- QK^T from LDS ----
        float4v sa[4];
        __builtin_amdgcn_s_setprio(1);
#pragma unroll
        for (int f = 0; f < 4; f++) {
            short8 b0 = *(const short8*)&Ks[f * 16 + ln][quad * 8];
            short8 b1 = *(const short8*)&Ks[f * 16 + ln][32 + quad * 8];
            float4v tt = zero;
            tt = MFMA16(aq0, b0, tt);
            tt = MFMA16(aq1, b1, tt);
            sa[f] = tt;
        }
        __builtin_amdgcn_s_setprio(0);
        // ---- positional bias + exp2 (fixed max 0) ----
        int rel0 = q0 - kk;
        u32* prow0 = (u32*)&p_lds[w][quad * 4][0];
        if (rel0 >= 569 || rel0 <= -633) {
            // far: idx is constant 0 or 511; pv comes from the pre-extracted column.
            int idx = rel0 > 0 ? 511 : 0;
            const u16* pfb = pfar + (rel0 > 0 ? (size_t)(32 + bh) : (size_t)bh) * 2048 + kk;
            float cvr[4], pvf[4];
#pragma unroll
            for (int r = 0; r < 4; r++)
                cvr[r] = b2f(cvrow[r][idx]);
#pragma unroll
            for (int f = 0; f < 4; f++)
                pvf[f] = b2f(pfb[f * 16 + ln]);
#pragma unroll
            for (int u = 0; u < 2; u++) {
#pragma unroll
                for (int r = 0; r < 4; r++) {
                    float p0 = exp2f(sa[2 * u][r] * SC + cvr[r] + pvf[2 * u]);
                    float p1 = exp2f(sa[2 * u + 1][r] * SC + cvr[r] + pvf[2 * u + 1]);
                    lrw[r] += p0 + p1;
                    u32* prow = prow0 + r * 36;
                    prow[u * 16 + ln] = cvtpk(p0, p1);
                }
            }
        } else {
            // near: f-pair phasing — gather 8 bias floats, then exp2+cvtpk+b32 store.
            // (keeps liveness low: the round-3 bias[4][4] buffer spilled to scratch)
#pragma unroll
            for (int u = 0; u < 2; u++) {
                float ba0, ba1, ba2, ba3, bb0, bb1, bb2, bb3;
                GATHER_BIAS(2 * u, ba0, ba1, ba2, ba3);
                GATHER_BIAS(2 * u + 1, bb0, bb1, bb2, bb3);
                float p0, p1;
                p0 = exp2f(sa[2 * u][0] * SC + ba0);
                p1 = exp2f(sa[2 * u + 1][0] * SC + bb0);
                lrw[0] += p0 + p1;
                prow0[0 * 36 + u * 16 + ln] = cvtpk(p0, p1);
                p0 = exp2f(sa[2 * u][1] * SC + ba1);
                p1 = exp2f(sa[2 * u + 1][1] * SC + bb1);
                lrw[1] += p0 + p1;
                prow0[1 * 36 + u * 16 + ln] = cvtpk(p0, p1);
                p0 = exp2f(sa[2 * u][2] * SC + ba2);
                p1 = exp2f(sa[2 * u + 1][2] * SC + bb2);
                lrw[2] += p0 + p1;
                prow0[2 * 36 + u * 16 + ln] = cvtpk(p0, p1);
                p0 = exp2f(sa[2 * u][3] * SC + ba3);
                p1 = exp2f(sa[2 * u + 1][3] * SC + bb3);
                lrw[3] += p0 + p1;
                prow0[3 * 36 + u * 16 + ln] = cvtpk(p0, p1);
            }
        }
        // ---- PV from LDS (own-wave P slice, no extra barrier; pi2-consistent) ----
        short8 ap0 = *(const short8*)&p_lds[w][ln][quad * 8];
        short8 ap1 = *(const short8*)&p_lds[w][ln][32 + quad * 8];
        __builtin_amdgcn_s_setprio(1);
#pragma unroll
        for (int f = 0; f < 4; f++) {
            short8 v0 = *(const short8*)&Vs[f * 16 + ln][quad * 8];
            short8 v1 = *(const short8*)&Vs[f * 16 + ln][32 + quad * 8];
            o[f] = MFMA16(ap0, v0, o[f]);
            o[f] = MFMA16(ap1, v1, o[f]);
        }
        __builtin_amdgcn_s_setprio(0);
    }
    // ---- single end-of-loop l reduction (within 16-lane quad) ----
#pragma unroll
    for (int r = 0; r < 4; r++) {
        lrw[r] += __shfl_xor(lrw[r], 1, 16);
        lrw[r] += __shfl_xor(lrw[r], 2, 16);
        lrw[r] += __shfl_xor(lrw[r], 4, 16);
        lrw[r] += __shfl_xor(lrw[r], 8, 16);
    }
    if (SPLIT == 1) {
        float inv_l[4];
#pragma unroll
        for (int r = 0; r < 4; r++) inv_l[r] = 1.f / lrw[r];
#pragma unroll
        for (int f = 0; f < 4; f++)
#pragma unroll
            for (int r = 0; r < 4; r++) {
                int qi = qs + quad * 4 + r;
                ctx[(size_t)(b * S + qi) * H + h * 64 + f * 16 + ln] = f2b(o[f][r] * inv_l[r]);
            }
    } else {
        float* oH = oP + (size_t)half * SP_OHALF;
#pragma unroll
        for (int f = 0; f < 4; f++)
#pragma unroll
            for (int r = 0; r < 4; r++) {
                int qi = qs + quad * 4 + r;
                oH[((size_t)bh * S + qi) * 64 + f * 16 + ln] = o[f][r];
            }
        if (ln == 0) {
            float* lH = lP + (size_t)half * SP_LHALF;
#pragma unroll
            for (int r = 0; r < 4; r++)
                lH[(size_t)bh * S + qs + quad * 4 + r] = lrw[r];
        }
    }
}

// ---------------- merge split-K partials -> ctx bf16 ----------------
__global__ __launch_bounds__(256) void k_merge(const float* __restrict__ oP,
                                               const float* __restrict__ lP,
                                               u16* __restrict__ ctx) {
    int t = blockIdx.x * 256 + threadIdx.x;
    int d4 = (t & 15) * 4;
    int h  = (t >> 4) & 15;
    int qq = (t >> 8) & 2047;
    int b  = t >> 19;
    int bh = b * 16 + h;
    size_t base = ((size_t)bh * S + qq) * 64 + d4;
    float4 o0 = *(const float4*)(oP + base);
    float4 o1 = *(const float4*)(oP + SP_OHALF + base);
    float l0 = lP[(size_t)bh * S + qq];
    float l1 = lP[SP_LHALF + (size_t)bh * S + qq];
    float inv = 1.f / (l0 + l1);
    ushort4 r4;
    r4.x = f2b((o0.x + o1.x) * inv);
    r4.y = f2b((o0.y + o1.y) * inv);
    r4.z = f2b((o0.z + o1.z) * inv);
    r4.w = f2b((o0.w + o1.w) * inv);
    *(ushort4*)(ctx + (((size_t)(b * S + qq)) * 16 + h) * 64 + d4) = r4;
}

// ---------------- launch ----------------
extern "C" void kernel_launch(void* const* d_in, const int* in_sizes, int n_in,
                              void* d_out, int out_size, void* d_ws, size_t ws_size,
                              hipStream_t stream) {
    const float* hs  = (const float*)d_in[0];
    const float* Wq  = (const float*)d_in[1];
    const float* bq  = (const float*)d_in[2];
    const float* Wk  = (const float*)d_in[3];
    const float* bk  = (const float*)d_in[4];
    const float* Wv  = (const float*)d_in[5];
    const float* bv  = (const float*)d_in[6];
    const float* Wo  = (const float*)d_in[7];
    const float* bo  = (const float*)d_in[8];
    const float* Wpk = (const float*)d_in[9];
    const float* bpk = (const float*)d_in[10];
    const float* Wpq = (const float*)d_in[11];
    const float* bpq = (const float*)d_in[12];
    const float* rel = (const float*)d_in[13];
    const float* lng = (const float*)d_in[14];
    const float* lnb = (const float*)d_in[15];

    char* ws = (char*)d_ws;
    u16* re_b   = (u16*)(ws + OFF_REB);
    u16* hs_b   = (u16*)(ws + OFF_HSB);
    u16* wt0    = (u16*)(ws + OFF_WT);
    u16* wt1    = (u16*)(ws + OFF_WT + 2097152ull);
    u16* wt2    = (u16*)(ws + OFF_WT + 2ull * 2097152ull);
    u16* wt3    = (u16*)(ws + OFF_WT + 3ull * 2097152ull);
    u16* wt4    = (u16*)(ws + OFF_WT + 4ull * 2097152ull);
    u16* wt5    = (u16*)(ws + OFF_WT + 5ull * 2097152ull);
    u16* Q_b    = (u16*)(ws + OFF_QB);
    u16* K_b    = (u16*)(ws + OFF_KB);
    u16* VT_b   = (u16*)(ws + OFF_VT);
    u16* posk_b = (u16*)(ws + OFF_PKB);
    u16* posq_b = (u16*)(ws + OFF_PQB);
    u16* c2p_b  = (u16*)(ws + OFF_C2P);
    u16* p2cK_b = (u16*)(ws + OFF_P2CK);
    u16* ctx_b  = (u16*)(ws + OFF_CTX);
    short* idx_t = (short*)(ws + OFF_IDX);
    u16* pfar_b = (u16*)(ws + OFF_PF);
    float* oP   = (float*)(ws + OFF_SP);
    float* lP   = (float*)(ws + SP_LBASE);

    dim3 blk(256);
    // fused preprocessing (cast | wt6 | ln | idx) — one launch
    k_pre<<<dim3(6148), blk, 0, stream>>>(hs, hs_b, Wq, Wk, Wv, Wo, Wpk, Wpq,
                                          wt0, wt1, wt2, wt3, wt4, wt5,
                                          rel, lng, lnb, re_b, idx_t);

    // projections + positional-embedding GEMMs — one launch (pos fills idle CUs)
    k_qkvpos<<<dim3(32, 8, 5), blk, 0, stream>>>(hs_b, wt0, wt1, wt2, bq, bk, bv,
                                                 Q_b, K_b, VT_b,
                                                 re_b, wt4, wt5, bpk, bpq, posk_b, posq_b);

    // positional score tables (scale incl. log2e folded in)
    k_pos_both<<<dim3(16, 4, 64), blk, 0, stream>>>(Q_b, K_b, posk_b, posq_b, c2p_b, p2cK_b, pfar_b);

    // fused attention (split-K x2 interleaved when workspace allows)
    if (ws_size >= WS_NEED_SPLIT) {
        k_attn<2><<<dim3(64, 32), blk, 0, stream>>>(Q_b, K_b, VT_b, c2p_b, p2cK_b, pfar_b, idx_t, oP, lP, ctx_b);
        k_merge<<<dim3(4096), blk, 0, stream>>>(oP, lP, ctx_b);
    } else {
        k_attn<1><<<dim3(32, 32), blk, 0, stream>>>(Q_b, K_b, VT_b, c2p_b, p2cK_b, pfar_b, idx_t, oP, lP, ctx_b);
    }

    // output projection (fp32 out)
    k_gemm2<1><<<dim3(32, 8), blk, 0, stream>>>(ctx_b, wt3, bo, d_out, H, H);
}

// Round 12
// 348.550 us; speedup vs baseline: 1.1119x; 1.0285x over previous
//
#include <hip/hip_runtime.h>

typedef unsigned short u16;
typedef unsigned int u32;
typedef unsigned long long u64;
typedef __attribute__((ext_vector_type(8))) short short8;
typedef __attribute__((ext_vector_type(4))) float float4v;

#define MFMA16(a, b, c) __builtin_amdgcn_mfma_f32_16x16x32_bf16((a), (b), (c), 0, 0, 0)

// ---------------- helpers ----------------
__device__ __forceinline__ u16 f2b(float x) {
    union { float f; unsigned u; } v; v.f = x;
    unsigned r = v.u + 0x7FFFu + ((v.u >> 16) & 1u);   // RNE
    return (u16)(r >> 16);
}
__device__ __forceinline__ float b2f(u16 u) {
    union { unsigned u; float f; } v; v.u = ((unsigned)u) << 16; return v.f;
}
// pack 2 f32 -> 2 bf16 (RNE) in one instruction
__device__ __forceinline__ u32 cvtpk(float lo, float hi) {
    u32 r;
    asm("v_cvt_pk_bf16_f32 %0, %1, %2" : "=v"(r) : "v"(lo), "v"(hi));
    return r;
}
// async global->LDS, 16 bytes per lane; dest = wave-uniform base + lane*16
__device__ __forceinline__ void gload16(const u16* g, u16* l) {
    __builtin_amdgcn_global_load_lds(
        (__attribute__((address_space(1))) void*)g,
        (__attribute__((address_space(3))) void*)l, 16, 0, 0);
}

// constants
#define NH 16
#define S  2048
#define HD 64
#define H  1024
// scale = 1/sqrt(192) * log2(e)  (exp -> exp2 folded into all score terms)
#define SC 0.10412111829775301f

// ---------------- workspace offsets (bytes) ----------------
#define OFF_REB   0ull
#define OFF_HSB   (OFF_REB  + 1048576ull)
#define OFF_WT    (OFF_HSB  + 8388608ull)
#define OFF_QB    (OFF_WT   + 12582912ull)
#define OFF_KB    (OFF_QB   + 8388608ull)
#define OFF_VT    (OFF_KB   + 8388608ull)
#define OFF_PKB   (OFF_VT   + 8388608ull)
#define OFF_PQB   (OFF_PKB  + 1048576ull)
#define OFF_C2P   (OFF_PQB  + 1048576ull)                // 64 MB [bh][q][512]
#define OFF_P2CK  (OFF_C2P  + 67108864ull)               // 64 MB [bh][k][512]  (k-major)
#define OFF_CTX   (OFF_P2CK + 67108864ull)
#define OFF_IDX   (OFF_CTX  + 8388608ull)
#define OFF_PF    (OFF_IDX  + 8192ull)                   // far columns [2][32][2048] u16 = 256 KB
#define OFF_SP    (OFF_PF   + 262144ull)                 // split-K partials
#define SP_OHALF  4194304ull                             // floats per half (32*2048*64)
#define SP_LBASE  (OFF_SP + 67108864ull)
#define SP_LHALF  65536ull
#define WS_NEED_SPLIT (SP_LBASE + 524288ull)             // ~248.5 MB

// ---------------- fused preprocessing: cast | wt6 | ln | idx-table ----------------
// One launch instead of four (all four are mutually independent; whole blocks branch
// uniformly). Block ranges: [0,4096) cast, [4096,5632) wt6, [5632,6144) ln, [6144,6148) idx.
__global__ __launch_bounds__(256) void k_pre(const float* __restrict__ hs, u16* __restrict__ hsb,
                                             const float* __restrict__ W0, const float* __restrict__ W1,
                                             const float* __restrict__ W2, const float* __restrict__ W3,
                                             const float* __restrict__ W4, const float* __restrict__ W5,
                                             u16* __restrict__ T0, u16* __restrict__ T1,
                                             u16* __restrict__ T2, u16* __restrict__ T3,
                                             u16* __restrict__ T4, u16* __restrict__ T5,
                                             const float* __restrict__ re, const float* __restrict__ g,
                                             const float* __restrict__ be, u16* __restrict__ reb,
                                             short* __restrict__ idxt) {
    __shared__ float t[64][65];          // wt6 tile (union; others use none / tiny)
    __shared__ float as[4], as2[4];      // ln partials
    int bx = blockIdx.x, tid = threadIdx.x;
    if (bx < 4096) {
        // ---- fp32 -> bf16 cast of hidden_states ----
        int i = bx * 256 + tid;
        float4 v = ((const float4*)hs)[i];
        ushort4 r;
        r.x = f2b(v.x); r.y = f2b(v.y); r.z = f2b(v.z); r.w = f2b(v.w);
        ((ushort4*)hsb)[i] = r;
    } else if (bx < 5632) {
        // ---- 6x weight transpose + cast ----
        int idx = bx - 4096;
        int mz = idx >> 8, rem = idx & 255;
        int k0 = (rem >> 4) * 64, n0 = (rem & 15) * 64;
        const float* W; u16* WT;
        switch (mz) {
            case 0: W = W0; WT = T0; break;
            case 1: W = W1; WT = T1; break;
            case 2: W = W2; WT = T2; break;
            case 3: W = W3; WT = T3; break;
            case 4: W = W4; WT = T4; break;
            default: W = W5; WT = T5; break;
        }
#pragma unroll
        for (int i = 0; i < 16; i++) {
            int lin = tid + 256 * i;
            int r = lin >> 6, c = lin & 63;
            t[r][c] = W[(size_t)(k0 + r) * H + n0 + c];
        }
        __syncthreads();
#pragma unroll
        for (int i = 0; i < 16; i++) {
            int lin = tid + 256 * i;
            int r = lin >> 6, c = lin & 63;
            WT[(size_t)(n0 + r) * H + k0 + c] = f2b(t[c][r]);
        }
    } else if (bx < 6144) {
        // ---- LayerNorm of rel_emb -> bf16 ----
        int row = bx - 5632;
        const float4* x4 = (const float4*)(re + (size_t)row * H);
        float4 vv = x4[tid];
        float s = vv.x + vv.y + vv.z + vv.w;
        float s2 = vv.x * vv.x + vv.y * vv.y + vv.z * vv.z + vv.w * vv.w;
        for (int m = 1; m < 64; m <<= 1) {
            s += __shfl_xor(s, m, 64);
            s2 += __shfl_xor(s2, m, 64);
        }
        if ((tid & 63) == 0) { as[tid >> 6] = s; as2[tid >> 6] = s2; }
        __syncthreads();
        s = as[0] + as[1] + as[2] + as[3];
        s2 = as2[0] + as2[1] + as2[2] + as2[3];
        float mu = s * (1.f / 1024.f);
        float var = s2 * (1.f / 1024.f) - mu * mu;
        float rstd = rsqrtf(var + 1e-5f);
        float4 gg = ((const float4*)g)[tid];
        float4 bb = ((const float4*)be)[tid];
        ushort4 r4;
        r4.x = f2b((vv.x - mu) * rstd * gg.x + bb.x);
        r4.y = f2b((vv.y - mu) * rstd * gg.y + bb.y);
        r4.z = f2b((vv.z - mu) * rstd * gg.z + bb.z);
        r4.w = f2b((vv.w - mu) * rstd * gg.w + bb.w);
        ((ushort4*)(reb + (size_t)row * H))[tid] = r4;
    } else {
        // ---- idx table for rel in [-512, 511] (monotone, slope<=1; clamp EXACT) ----
        int i = (bx - 6144) * 256 + tid;
        if (i >= 1024) return;
        int rel = i - 512;
        float fr = (float)rel;
        float abs_pos = (rel < 128 && rel > -128) ? 127.0f : fabsf(fr);
        const float LOGC = 1.3843393262841284f;  // float32(ln(511/128))
        float log_pos = ceilf(logf(abs_pos * (1.0f / 128.0f)) / LOGC * 127.0f) + 128.0f;
        float sgn = (fr > 0.f) ? 1.f : ((fr < 0.f) ? -1.f : 0.f);
        float bf = (abs_pos <= 128.0f) ? fr : log_pos * sgn;
        int ix = (int)bf + 256;
        ix = ix < 0 ? 0 : (ix > 511 ? 511 : ix);
        idxt[i] = (short)ix;
    }
}

// ---------------- 128x128-tile GEMM core ----------------
// Staging via global_load_lds width=16 (m97 ladder step: compiler never auto-emits it).
// Layout math: thread tid's store lands at byte tid*16 of As (unpadded [128][32] u16), so
// HW scatter (wave-uniform base + lane*16) with base = As + 1024*w reproduces the layout.
// MODE 0: bf16 row-major; MODE 1: f32 row-major;
// MODE 2: bf16 VT layout (b*1024+n)*2048 + pi2-permuted s within each 64-block
//         (pi2(j) = (j>>5)*32 + (j&15)*2 + ((j>>4)&1); k_attn's P store and PV MFMA
//          use the same permuted k-order, and MFMA sums over k, so this is exact);
// MODE 3: bf16 head-major ((b*16+h)*2048+m)*64+d
template <int MODE>
__device__ __forceinline__ void gemm2_body(const u16* __restrict__ A,
                                           const u16* __restrict__ Bt,
                                           const float* __restrict__ bias,
                                           void* __restrict__ C, int N, int K) {
    __shared__ __align__(16) u16 As[128 * 32];
    __shared__ __align__(16) u16 Bs[128 * 32];
    int tid = threadIdx.x;
    int lane = tid & 63, w = tid >> 6;
    int ln = lane & 15, quad = lane >> 4;
    int m0 = blockIdx.x * 128, n0 = blockIdx.y * 128;
    int wm = (w >> 1) * 64, wn = (w & 1) * 64;
    float4v acc[4][4];
    float4v zero = {0.f, 0.f, 0.f, 0.f};
#pragma unroll
    for (int mi = 0; mi < 4; mi++)
#pragma unroll
        for (int ni = 0; ni < 4; ni++) acc[mi][ni] = zero;

    int r1 = tid >> 2, o1 = (tid & 3) * 8;
    const u16* ga1 = A + (size_t)(m0 + r1) * K + o1;
    const u16* gb1 = Bt + (size_t)(n0 + r1) * K + o1;
    // wave-uniform LDS bases (lane l lands at base + l*16 bytes = original tid*16 layout)
    u16* asw = &As[w * 512];
    u16* bsw = &Bs[w * 512];
    size_t step2 = (size_t)64 * K;

    for (int k0 = 0; k0 < K; k0 += 32) {
        __syncthreads();
        gload16(ga1 + k0,          asw);
        gload16(ga1 + step2 + k0,  asw + 2048);
        gload16(gb1 + k0,          bsw);
        gload16(gb1 + step2 + k0,  bsw + 2048);
        __syncthreads();
        short8 af[4], bf[4];
#pragma unroll
        for (int mi = 0; mi < 4; mi++)
            af[mi] = *(const short8*)&As[(wm + mi * 16 + ln) * 32 + quad * 8];
#pragma unroll
        for (int ni = 0; ni < 4; ni++)
            bf[ni] = *(const short8*)&Bs[(wn + ni * 16 + ln) * 32 + quad * 8];
#pragma unroll
        for (int mi = 0; mi < 4; mi++)
#pragma unroll
            for (int ni = 0; ni < 4; ni++)
                acc[mi][ni] = MFMA16(af[mi], bf[ni], acc[mi][ni]);
    }

#pragma unroll
    for (int mi = 0; mi < 4; mi++) {
        int row0 = m0 + wm + mi * 16 + quad * 4;
#pragma unroll
        for (int ni = 0; ni < 4; ni++) {
            int col = n0 + wn + ni * 16 + ln;
            float bv = bias[col];
            if (MODE == 0) {
                u16* Cb = (u16*)C;
#pragma unroll
                for (int r = 0; r < 4; r++)
                    Cb[(size_t)(row0 + r) * N + col] = f2b(acc[mi][ni][r] + bv);
            } else if (MODE == 1) {
                float* Cf = (float*)C;
#pragma unroll
                for (int r = 0; r < 4; r++)
                    Cf[(size_t)(row0 + r) * N + col] = acc[mi][ni][r] + bv;
            } else if (MODE == 2) {
                u16* Cb = (u16*)C;
                int bb = row0 >> 11, s = row0 & 2047;
                int base64 = s & ~63, j = s & 63;           // j = mi*16 + quad*4 (j%4==0)
                int p0 = ((j >> 5) << 5) + ((j & 15) << 1) + ((j >> 4) & 1);
                u16* dst = Cb + ((size_t)(bb * 1024 + col)) * 2048 + base64;
#pragma unroll
                for (int r = 0; r < 4; r++)
                    dst[p0 + 2 * r] = f2b(acc[mi][ni][r] + bv);
            } else {
                u16* Cb = (u16*)C;
                int bb = row0 >> 11, s = row0 & 2047;
                int h = col >> 6, d = col & 63;
#pragma unroll
                for (int r = 0; r < 4; r++)
                    Cb[((size_t)(bb * 16 + h) * 2048 + s + r) * 64 + d] = f2b(acc[mi][ni][r] + bv);
            }
        }
    }
}

template <int MODE>
__global__ __launch_bounds__(256) void k_gemm2(const u16* __restrict__ A, const u16* __restrict__ Bt,
                                               const float* __restrict__ bias, void* __restrict__ C,
                                               int N, int K) {
    gemm2_body<MODE>(A, Bt, bias, C, N, K);
}

// Q/K/V projections AND both positional-embedding GEMMs in ONE launch.
// z: 0=Q head-major, 1=K head-major, 2=V transposed+pi2, 3=posk (bx<4), 4=posq (bx<4).
__global__ __launch_bounds__(256) void k_qkvpos(const u16* __restrict__ A,
                                                const u16* __restrict__ W0, const u16* __restrict__ W1,
                                                const u16* __restrict__ W2,
                                                const float* __restrict__ b0, const float* __restrict__ b1,
                                                const float* __restrict__ b2,
                                                u16* __restrict__ Q, u16* __restrict__ K, u16* __restrict__ VT,
                                                const u16* __restrict__ RE,
                                                const u16* __restrict__ W4, const u16* __restrict__ W5,
                                                const float* __restrict__ b4, const float* __restrict__ b5,
                                                u16* __restrict__ PK, u16* __restrict__ PQ) {
    int z = blockIdx.z;
    if (z == 0)      gemm2_body<3>(A, W0, b0, Q, H, H);
    else if (z == 1) gemm2_body<3>(A, W1, b1, K, H, H);
    else if (z == 2) gemm2_body<2>(A, W2, b2, VT, H, H);
    else if (z == 3) { if (blockIdx.x >= 4) return; gemm2_body<0>(RE, W4, b4, PK, H, H); }
    else             { if (blockIdx.x >= 4) return; gemm2_body<0>(RE, W5, b5, PQ, H, H); }
}

// ---------------- both positional score tables, one launch ----------------
__global__ __launch_bounds__(256) void k_pos_both(const u16* __restrict__ Qh, const u16* __restrict__ Kh,
                                                  const u16* __restrict__ pk, const u16* __restrict__ pq,
                                                  u16* __restrict__ c2p, u16* __restrict__ p2cK,
                                                  u16* __restrict__ pfar) {
    __shared__ __align__(16) u16 smem[2 * 128 * 72];   // As | Bs
    u16* As = smem;
    u16* Bs = smem + 128 * 72;
    int tid = threadIdx.x;
    int lane = tid & 63, w = tid >> 6;
    int ln = lane & 15, quad = lane >> 4;
    int tr = blockIdx.z & 1, z = blockIdx.z >> 1, h = z & 15;
    int m0 = blockIdx.x * 128, n0 = blockIdx.y * 128;
    const u16* A = (tr ? Kh : Qh) + (size_t)z * S * HD;
    const u16* B = (tr ? pq : pk) + h * 64;
    int sr = tid >> 1, scb = (tid & 1) * 32;
    {
        const u16* ga = A + (size_t)(m0 + sr) * HD + scb;
        const u16* gb = B + (size_t)(n0 + sr) * H + scb;
#pragma unroll
        for (int j = 0; j < 4; j++) {
            *(short8*)&As[sr * 72 + scb + j * 8] = *(const short8*)(ga + j * 8);
            *(short8*)&Bs[sr * 72 + scb + j * 8] = *(const short8*)(gb + j * 8);
        }
    }
    __syncthreads();
    int wm = (w >> 1) * 64, wn = (w & 1) * 64;
    float4v acc[4][4];
    float4v zero = {0.f, 0.f, 0.f, 0.f};
#pragma unroll
    for (int mi = 0; mi < 4; mi++)
#pragma unroll
        for (int ni = 0; ni < 4; ni++) acc[mi][ni] = zero;
#pragma unroll
    for (int c = 0; c < 2; c++) {
        short8 af[4], bf[4];
#pragma unroll
        for (int mi = 0; mi < 4; mi++)
            af[mi] = *(const short8*)&As[(wm + mi * 16 + ln) * 72 + c * 32 + quad * 8];
#pragma unroll
        for (int ni = 0; ni < 4; ni++)
            bf[ni] = *(const short8*)&Bs[(wn + ni * 16 + ln) * 72 + c * 32 + quad * 8];
#pragma unroll
        for (int mi = 0; mi < 4; mi++)
#pragma unroll
            for (int ni = 0; ni < 4; ni++)
                acc[mi][ni] = MFMA16(af[mi], bf[ni], acc[mi][ni]);
    }
    u16* Cp = (tr ? p2cK : c2p) + (size_t)z * S * 512;
#pragma unroll
    for (int mi = 0; mi < 4; mi++) {
        int row0 = m0 + wm + mi * 16 + quad * 4;
#pragma unroll
        for (int ni = 0; ni < 4; ni++) {
            int col = n0 + wn + ni * 16 + ln;
#pragma unroll
            for (int r = 0; r < 4; r++)
                Cp[(size_t)(row0 + r) * 512 + col] = f2b(acc[mi][ni][r] * SC);
        }
    }
    if (tr) {
        // far-column extraction (col 0 lives in n0==0 blocks, col 511 in n0==384 blocks)
        if (n0 == 0 && (w & 1) == 0 && ln == 0) {
            u16* dst = pfar + (size_t)z * 2048 + m0 + wm + quad * 4;
#pragma unroll
            for (int mi = 0; mi < 4; mi++)
#pragma unroll
                for (int r = 0; r < 4; r++)
                    dst[mi * 16 + r] = f2b(acc[mi][0][r] * SC);
        }
        if (n0 == 384 && (w & 1) == 1 && ln == 15) {
            u16* dst = pfar + (size_t)(32 + z) * 2048 + m0 + wm + quad * 4;
#pragma unroll
            for (int mi = 0; mi < 4; mi++)
#pragma unroll
                for (int r = 0; r < 4; r++)
                    dst[mi * 16 + r] = f2b(acc[mi][3][r] * SC);
        }
    }
}

// gather c2p+p2c bias for rows r=0..3 at f=F into 4 named floats (no runtime array idx)
#define GATHER_BIAS(F, B0, B1, B2, B3) do {                                          \
    int ki_ = kk + (F) * 16 + ln;                                                    \
    const u16* pvrow_ = p2cB + (size_t)ki_ * 512;                                    \
    int relb_ = qrow - ki_;                                                          \
    int i0_, i1_, i2_, i3_;                                                          \
    { int rel = relb_;     rel = rel < -512 ? -512 : (rel > 511 ? 511 : rel); i0_ = (int)s_idx1[rel + 512]; } \
    { int rel = relb_ + 1; rel = rel < -512 ? -512 : (rel > 511 ? 511 : rel); i1_ = (int)s_idx1[rel + 512]; } \
    { int rel = relb_ + 2; rel = rel < -512 ? -512 : (rel > 511 ? 511 : rel); i2_ = (int)s_idx1[rel + 512]; } \
    { int rel = relb_ + 3; rel = rel < -512 ? -512 : (rel > 511 ? 511 : rel); i3_ = (int)s_idx1[rel + 512]; } \
    const u32* p32_ = (const u32*)pvrow_;                                            \
    int e_ = i0_ >> 1;                                                               \
    u32 wx_ = p32_[e_], wy_ = p32_[e_ + 1], wz_ = p32_[e_ + 2];                      \
    u64 lov_ = (u64)wx_ | ((u64)wy_ << 32);                                          \
    u64 sft_ = (i0_ & 1) ? ((lov_ >> 16) | ((u64)wz_ << 48)) : lov_;                 \
    u16 c0_ = cvrow[0][i0_], c1_ = cvrow[1][i1_], c2_ = cvrow[2][i2_], c3_ = cvrow[3][i3_]; \
    union { u32 u; float f; } q0_, q1_, q2_, q3_;                                    \
    q0_.u = ((u32)(sft_)) << 16;                                                     \
    q1_.u = ((u32)(sft_ >> ((i1_ - i0_) << 4))) << 16;                               \
    q2_.u = ((u32)(sft_ >> ((i2_ - i0_) << 4))) << 16;                               \
    q3_.u = ((u32)(sft_ >> ((i3_ - i0_) << 4))) << 16;                               \
    B0 = b2f(c0_) + q0_.f;                                                           \
    B1 = b2f(c1_) + q1_.f;                                                           \
    B2 = b2f(c2_) + q2_.f;                                                           \
    B3 = b2f(c3_) + q3_.f;                                                           \
} while (0)

// ---------------- fused attention: K/V tiles staged in LDS (shared by 4 waves) ----------------
// P columns and V columns both live in pi2-permuted k-order (V permuted at VT write time):
// each lane's (f,f+1) P values are ADJACENT -> v_cvt_pk_bf16_f32 + single b32 store.
// NEW this round: XCD-aware block swizzle (T1). Same-bh blocks share ~4.5 MB of tables
// (c2p 2MB + p2cK 2MB + K/V); default x-fastest round-robin spreads the resident set over
// all 16 live bh per XCD (~64MB >> 4MB L2). Bijective chunked remap (nwg%8==0) gives each
// XCD a contiguous chunk (~4 bh) -> per-XCD working set ~5-9MB. Mapping-only: exact.
template <int SPLIT>
__global__ __launch_bounds__(256, 4) void k_attn(const u16* __restrict__ Qh,
                                                 const u16* __restrict__ Kh,
                                                 const u16* __restrict__ VT,
                                                 const u16* __restrict__ c2p,
                                                 const u16* __restrict__ p2cK,
                                                 const u16* __restrict__ pfar,
                                                 const short* __restrict__ idxTab,
                                                 float* __restrict__ oP,
                                                 float* __restrict__ lP,
                                                 u16* __restrict__ ctx) {
    __shared__ short s_idx1[1024];
    __shared__ __align__(16) u16 p_lds[4][16][72];
    __shared__ __align__(16) u16 Ks[64][72];
    __shared__ __align__(16) u16 Vs[64][72];
    int tid = threadIdx.x;
    for (int i = tid; i < 1024; i += 256) s_idx1[i] = idxTab[i];
    int lane = tid & 63, w = tid >> 6;
    int ln = lane & 15, quad = lane >> 4;
    // ---- XCD-aware bijective swizzle (dispatch-linear id, x fastest) ----
    const int NBX = (SPLIT == 2) ? 64 : 32;
    const int NWG = NBX * 32;
    int bid = blockIdx.x + NBX * blockIdx.y;
    int swz = (bid & 7) * (NWG >> 3) + (bid >> 3);
    int bx = swz % NBX;
    int bh = swz / NBX;
    int half = (SPLIT == 2) ? (bx & 1) : 0;
    int q0 = (SPLIT == 2) ? (bx >> 1) * 64 : bx * 64;
    int b = bh >> 4, h = bh & 15;
    int qs = q0 + w * 16;

    const u16* qptr = Qh + ((size_t)bh * S + qs + ln) * HD + quad * 8;
    short8 aq0 = *(const short8*)(qptr);
    short8 aq1 = *(const short8*)(qptr + 32);

    float4v o[4];
    float4v zero = {0.f, 0.f, 0.f, 0.f};
#pragma unroll
    for (int f = 0; f < 4; f++) o[f] = zero;
    float lrw[4] = {0.f, 0.f, 0.f, 0.f};

    const u16* c2pB = c2p + (size_t)bh * S * 512;
    const u16* p2cB = p2cK + (size_t)bh * S * 512;
    int qrow = qs + quad * 4;

    // c2p row pointers: fixed per thread for the whole kernel (16 q-rows per wave -> L1-hot)
    const u16* cvrow[4];
#pragma unroll
    for (int r = 0; r < 4; r++) cvrow[r] = c2pB + (size_t)(qrow + r) * 512;

    // staging map: thread -> (row sr 0..63, col block sc 0..48 step 16)
    int sr = tid >> 2, sc = (tid & 3) * 16;
    const u16* kstg = Kh + ((size_t)bh * S + sr) * HD + sc;              // + kk*HD per tile
    const u16* vstg = VT + (size_t)(b * 1024 + h * 64 + sr) * S + sc;    // + kk per tile (pi2 order)

    const int NT = S / 64 / SPLIT;
    for (int t = 0; t < NT; t++) {
        int kk = (SPLIT == 2) ? (((t << 1) | half) << 6) : (t << 6);
        // ---- stage K,V tile (all waves cooperate) ----
        short8 kr0 = *(const short8*)(kstg + (size_t)kk * HD);
        short8 kr1 = *(const short8*)(kstg + (size_t)kk * HD + 8);
        short8 vr0 = *(const short8*)(vstg + kk);
        short8 vr1 = *(const short8*)(vstg + kk + 8);
        __syncthreads();
        *(short8*)&Ks[sr][sc] = kr0; *(short8*)&Ks[sr][sc + 8] = kr1;
        *(short8*)&Vs[sr][sc] = vr0; *(short8*)&Vs[sr][sc + 8] = vr1;
        __syncthreads();
        // ---- QK^T from LDS ----
        float4v sa[4];
        __builtin_amdgcn_s_setprio(1);
#pragma unroll
        for (int f = 0; f < 4; f++) {
            short8 b0 = *(const short8*)&Ks[f * 16 + ln][quad * 8];
            short8 b1 = *(const short8*)&Ks[f * 16 + ln][32 + quad * 8];
            float4v tt = zero;
            tt = MFMA16(aq0, b0, tt);
            tt = MFMA16(aq1, b1, tt);
            sa[f] = tt;
        }
        __builtin_amdgcn_s_setprio(0);
        // ---- positional bias + exp2 (fixed max 0) ----
        int rel0 = q0 - kk;
        u32* prow0 = (u32*)&p_lds[w][quad * 4][0];
        if (rel0 >= 569 || rel0 <= -633) {
            // far: idx is constant 0 or 511; pv comes from the pre-extracted column.
            int idx = rel0 > 0 ? 511 : 0;
            const u16* pfb = pfar + (rel0 > 0 ? (size_t)(32 + bh) : (size_t)bh) * 2048 + kk;
            float cvr[4], pvf[4];
#pragma unroll
            for (int r = 0; r < 4; r++)
                cvr[r] = b2f(cvrow[r][idx]);
#pragma unroll
            for (int f = 0; f < 4; f++)
                pvf[f] = b2f(pfb[f * 16 + ln]);
#pragma unroll
            for (int u = 0; u < 2; u++) {
#pragma unroll
                for (int r = 0; r < 4; r++) {
                    float p0 = exp2f(sa[2 * u][r] * SC + cvr[r] + pvf[2 * u]);
                    float p1 = exp2f(sa[2 * u + 1][r] * SC + cvr[r] + pvf[2 * u + 1]);
                    lrw[r] += p0 + p1;
                    u32* prow = prow0 + r * 36;
                    prow[u * 16 + ln] = cvtpk(p0, p1);
                }
            }
        } else {
            // near: f-pair phasing — gather 8 bias floats, then exp2+cvtpk+b32 store.
            // (keeps liveness low: the round-3 bias[4][4] buffer spilled to scratch)
#pragma unroll
            for (int u = 0; u < 2; u++) {
                float ba0, ba1, ba2, ba3, bb0, bb1, bb2, bb3;
                GATHER_BIAS(2 * u, ba0, ba1, ba2, ba3);
                GATHER_BIAS(2 * u + 1, bb0, bb1, bb2, bb3);
                float p0, p1;
                p0 = exp2f(sa[2 * u][0] * SC + ba0);
                p1 = exp2f(sa[2 * u + 1][0] * SC + bb0);
                lrw[0] += p0 + p1;
                prow0[0 * 36 + u * 16 + ln] = cvtpk(p0, p1);
                p0 = exp2f(sa[2 * u][1] * SC + ba1);
                p1 = exp2f(sa[2 * u + 1][1] * SC + bb1);
                lrw[1] += p0 + p1;
                prow0[1 * 36 + u * 16 + ln] = cvtpk(p0, p1);
                p0 = exp2f(sa[2 * u][2] * SC + ba2);
                p1 = exp2f(sa[2 * u + 1][2] * SC + bb2);
                lrw[2] += p0 + p1;
                prow0[2 * 36 + u * 16 + ln] = cvtpk(p0, p1);
                p0 = exp2f(sa[2 * u][3] * SC + ba3);
                p1 = exp2f(sa[2 * u + 1][3] * SC + bb3);
                lrw[3] += p0 + p1;
                prow0[3 * 36 + u * 16 + ln] = cvtpk(p0, p1);
            }
        }
        // ---- PV from LDS (own-wave P slice, no extra barrier; pi2-consistent) ----
        short8 ap0 = *(const short8*)&p_lds[w][ln][quad * 8];
        short8 ap1 = *(const short8*)&p_lds[w][ln][32 + quad * 8];
        __builtin_amdgcn_s_setprio(1);
#pragma unroll
        for (int f = 0; f < 4; f++) {
            short8 v0 = *(const short8*)&Vs[f * 16 + ln][quad * 8];
            short8 v1 = *(const short8*)&Vs[f * 16 + ln][32 + quad * 8];
            o[f] = MFMA16(ap0, v0, o[f]);
            o[f] = MFMA16(ap1, v1, o[f]);
        }
        __builtin_amdgcn_s_setprio(0);
    }
    // ---- single end-of-loop l reduction (within 16-lane quad) ----
#pragma unroll
    for (int r = 0; r < 4; r++) {
        lrw[r] += __shfl_xor(lrw[r], 1, 16);
        lrw[r] += __shfl_xor(lrw[r], 2, 16);
        lrw[r] += __shfl_xor(lrw[r], 4, 16);
        lrw[r] += __shfl_xor(lrw[r], 8, 16);
    }
    if (SPLIT == 1) {
        float inv_l[4];
#pragma unroll
        for (int r = 0; r < 4; r++) inv_l[r] = 1.f / lrw[r];
#pragma unroll
        for (int f = 0; f < 4; f++)
#pragma unroll
            for (int r = 0; r < 4; r++) {
                int qi = qs + quad * 4 + r;
                ctx[(size_t)(b * S + qi) * H + h * 64 + f * 16 + ln] = f2b(o[f][r] * inv_l[r]);
            }
    } else {
        float* oH = oP + (size_t)half * SP_OHALF;
#pragma unroll
        for (int f = 0; f < 4; f++)
#pragma unroll
            for (int r = 0; r < 4; r++) {
                int qi = qs + quad * 4 + r;
                oH[((size_t)bh * S + qi) * 64 + f * 16 + ln] = o[f][r];
            }
        if (ln == 0) {
            float* lH = lP + (size_t)half * SP_LHALF;
#pragma unroll
            for (int r = 0; r < 4; r++)
                lH[(size_t)bh * S + qs + quad * 4 + r] = lrw[r];
        }
    }
}

// ---------------- merge split-K partials -> ctx bf16 ----------------
__global__ __launch_bounds__(256) void k_merge(const float* __restrict__ oP,
                                               const float* __restrict__ lP,
                                               u16* __restrict__ ctx) {
    int t = blockIdx.x * 256 + threadIdx.x;
    int d4 = (t & 15) * 4;
    int h  = (t >> 4) & 15;
    int qq = (t >> 8) & 2047;
    int b  = t >> 19;
    int bh = b * 16 + h;
    size_t base = ((size_t)bh * S + qq) * 64 + d4;
    float4 o0 = *(const float4*)(oP + base);
    float4 o1 = *(const float4*)(oP + SP_OHALF + base);
    float l0 = lP[(size_t)bh * S + qq];
    float l1 = lP[SP_LHALF + (size_t)bh * S + qq];
    float inv = 1.f / (l0 + l1);
    ushort4 r4;
    r4.x = f2b((o0.x + o1.x) * inv);
    r4.y = f2b((o0.y + o1.y) * inv);
    r4.z = f2b((o0.z + o1.z) * inv);
    r4.w = f2b((o0.w + o1.w) * inv);
    *(ushort4*)(ctx + (((size_t)(b * S + qq)) * 16 + h) * 64 + d4) = r4;
}

// ---------------- launch ----------------
extern "C" void kernel_launch(void* const* d_in, const int* in_sizes, int n_in,
                              void* d_out, int out_size, void* d_ws, size_t ws_size,
                              hipStream_t stream) {
    const float* hs  = (const float*)d_in[0];
    const float* Wq  = (const float*)d_in[1];
    const float* bq  = (const float*)d_in[2];
    const float* Wk  = (const float*)d_in[3];
    const float* bk  = (const float*)d_in[4];
    const float* Wv  = (const float*)d_in[5];
    const float* bv  = (const float*)d_in[6];
    const float* Wo  = (const float*)d_in[7];
    const float* bo  = (const float*)d_in[8];
    const float* Wpk = (const float*)d_in[9];
    const float* bpk = (const float*)d_in[10];
    const float* Wpq = (const float*)d_in[11];
    const float* bpq = (const float*)d_in[12];
    const float* rel = (const float*)d_in[13];
    const float* lng = (const float*)d_in[14];
    const float* lnb = (const float*)d_in[15];

    char* ws = (char*)d_ws;
    u16* re_b   = (u16*)(ws + OFF_REB);
    u16* hs_b   = (u16*)(ws + OFF_HSB);
    u16* wt0    = (u16*)(ws + OFF_WT);
    u16* wt1    = (u16*)(ws + OFF_WT + 2097152ull);
    u16* wt2    = (u16*)(ws + OFF_WT + 2ull * 2097152ull);
    u16* wt3    = (u16*)(ws + OFF_WT + 3ull * 2097152ull);
    u16* wt4    = (u16*)(ws + OFF_WT + 4ull * 2097152ull);
    u16* wt5    = (u16*)(ws + OFF_WT + 5ull * 2097152ull);
    u16* Q_b    = (u16*)(ws + OFF_QB);
    u16* K_b    = (u16*)(ws + OFF_KB);
    u16* VT_b   = (u16*)(ws + OFF_VT);
    u16* posk_b = (u16*)(ws + OFF_PKB);
    u16* posq_b = (u16*)(ws + OFF_PQB);
    u16* c2p_b  = (u16*)(ws + OFF_C2P);
    u16* p2cK_b = (u16*)(ws + OFF_P2CK);
    u16* ctx_b  = (u16*)(ws + OFF_CTX);
    short* idx_t = (short*)(ws + OFF_IDX);
    u16* pfar_b = (u16*)(ws + OFF_PF);
    float* oP   = (float*)(ws + OFF_SP);
    float* lP   = (float*)(ws + SP_LBASE);

    dim3 blk(256);
    // fused preprocessing (cast | wt6 | ln | idx) — one launch
    k_pre<<<dim3(6148), blk, 0, stream>>>(hs, hs_b, Wq, Wk, Wv, Wo, Wpk, Wpq,
                                          wt0, wt1, wt2, wt3, wt4, wt5,
                                          rel, lng, lnb, re_b, idx_t);

    // projections + positional-embedding GEMMs — one launch (pos fills idle CUs)
    k_qkvpos<<<dim3(32, 8, 5), blk, 0, stream>>>(hs_b, wt0, wt1, wt2, bq, bk, bv,
                                                 Q_b, K_b, VT_b,
                                                 re_b, wt4, wt5, bpk, bpq, posk_b, posq_b);

    // positional score tables (scale incl. log2e folded in)
    k_pos_both<<<dim3(16, 4, 64), blk, 0, stream>>>(Q_b, K_b, posk_b, posq_b, c2p_b, p2cK_b, pfar_b);

    // fused attention (split-K x2 interleaved when workspace allows)
    if (ws_size >= WS_NEED_SPLIT) {
        k_attn<2><<<dim3(64, 32), blk, 0, stream>>>(Q_b, K_b, VT_b, c2p_b, p2cK_b, pfar_b, idx_t, oP, lP, ctx_b);
        k_merge<<<dim3(4096), blk, 0, stream>>>(oP, lP, ctx_b);
    } else {
        k_attn<1><<<dim3(32, 32), blk, 0, stream>>>(Q_b, K_b, VT_b, c2p_b, p2cK_b, pfar_b, idx_t, oP, lP, ctx_b);
    }

    // output projection (fp32 out)
    k_gemm2<1><<<dim3(32, 8), blk, 0, stream>>>(ctx_b, wt3, bo, d_out, H, H);
}

// Round 13
// 347.916 us; speedup vs baseline: 1.1139x; 1.0018x over previous
//
#include <hip/hip_runtime.h>

typedef unsigned short u16;
typedef unsigned int u32;
typedef unsigned long long u64;
typedef __attribute__((ext_vector_type(8))) short short8;
typedef __attribute__((ext_vector_type(4))) float float4v;

#define MFMA16(a, b, c) __builtin_amdgcn_mfma_f32_16x16x32_bf16((a), (b), (c), 0, 0, 0)

// ---------------- helpers ----------------
__device__ __forceinline__ u16 f2b(float x) {
    union { float f; unsigned u; } v; v.f = x;
    unsigned r = v.u + 0x7FFFu + ((v.u >> 16) & 1u);   // RNE
    return (u16)(r >> 16);
}
__device__ __forceinline__ float b2f(u16 u) {
    union { unsigned u; float f; } v; v.u = ((unsigned)u) << 16; return v.f;
}
// pack 2 f32 -> 2 bf16 (RNE) in one instruction
__device__ __forceinline__ u32 cvtpk(float lo, float hi) {
    u32 r;
    asm("v_cvt_pk_bf16_f32 %0, %1, %2" : "=v"(r) : "v"(lo), "v"(hi));
    return r;
}
// async global->LDS, 16 bytes per lane; dest = wave-uniform base + lane*16
__device__ __forceinline__ void gload16(const u16* g, u16* l) {
    __builtin_amdgcn_global_load_lds(
        (__attribute__((address_space(1))) void*)g,
        (__attribute__((address_space(3))) void*)l, 16, 0, 0);
}

// constants
#define NH 16
#define S  2048
#define HD 64
#define H  1024
// scale = 1/sqrt(192) * log2(e)  (exp -> exp2 folded into all score terms)
#define SC 0.10412111829775301f

// ---------------- workspace offsets (bytes) ----------------
#define OFF_REB   0ull
#define OFF_HSB   (OFF_REB  + 1048576ull)
#define OFF_WT    (OFF_HSB  + 8388608ull)
#define OFF_QB    (OFF_WT   + 12582912ull)
#define OFF_KB    (OFF_QB   + 8388608ull)
#define OFF_VT    (OFF_KB   + 8388608ull)
#define OFF_PKB   (OFF_VT   + 8388608ull)
#define OFF_PQB   (OFF_PKB  + 1048576ull)
#define OFF_C2P   (OFF_PQB  + 1048576ull)                // 64 MB [bh][q][512]
#define OFF_P2CK  (OFF_C2P  + 67108864ull)               // 64 MB [bh][k][512]  (k-major)
#define OFF_CTX   (OFF_P2CK + 67108864ull)
#define OFF_IDX   (OFF_CTX  + 8388608ull)
#define OFF_PF    (OFF_IDX  + 8192ull)                   // far columns [2][32][2048] u16 = 256 KB
#define OFF_SP    (OFF_PF   + 262144ull)                 // split-K partials
#define SP_OHALF  4194304ull                             // floats per half (32*2048*64)
#define SP_LBASE  (OFF_SP + 67108864ull)
#define SP_LHALF  65536ull
#define WS_NEED_SPLIT (SP_LBASE + 524288ull)             // ~248.5 MB

// ---------------- fused preprocessing: cast | wt6 | ln | idx-table ----------------
// One launch instead of four (all four are mutually independent; whole blocks branch
// uniformly). Block ranges: [0,4096) cast, [4096,5632) wt6, [5632,6144) ln, [6144,6148) idx.
__global__ __launch_bounds__(256) void k_pre(const float* __restrict__ hs, u16* __restrict__ hsb,
                                             const float* __restrict__ W0, const float* __restrict__ W1,
                                             const float* __restrict__ W2, const float* __restrict__ W3,
                                             const float* __restrict__ W4, const float* __restrict__ W5,
                                             u16* __restrict__ T0, u16* __restrict__ T1,
                                             u16* __restrict__ T2, u16* __restrict__ T3,
                                             u16* __restrict__ T4, u16* __restrict__ T5,
                                             const float* __restrict__ re, const float* __restrict__ g,
                                             const float* __restrict__ be, u16* __restrict__ reb,
                                             short* __restrict__ idxt) {
    __shared__ float t[64][65];          // wt6 tile (union; others use none / tiny)
    __shared__ float as[4], as2[4];      // ln partials
    int bx = blockIdx.x, tid = threadIdx.x;
    if (bx < 4096) {
        // ---- fp32 -> bf16 cast of hidden_states ----
        int i = bx * 256 + tid;
        float4 v = ((const float4*)hs)[i];
        ushort4 r;
        r.x = f2b(v.x); r.y = f2b(v.y); r.z = f2b(v.z); r.w = f2b(v.w);
        ((ushort4*)hsb)[i] = r;
    } else if (bx < 5632) {
        // ---- 6x weight transpose + cast ----
        int idx = bx - 4096;
        int mz = idx >> 8, rem = idx & 255;
        int k0 = (rem >> 4) * 64, n0 = (rem & 15) * 64;
        const float* W; u16* WT;
        switch (mz) {
            case 0: W = W0; WT = T0; break;
            case 1: W = W1; WT = T1; break;
            case 2: W = W2; WT = T2; break;
            case 3: W = W3; WT = T3; break;
            case 4: W = W4; WT = T4; break;
            default: W = W5; WT = T5; break;
        }
#pragma unroll
        for (int i = 0; i < 16; i++) {
            int lin = tid + 256 * i;
            int r = lin >> 6, c = lin & 63;
            t[r][c] = W[(size_t)(k0 + r) * H + n0 + c];
        }
        __syncthreads();
#pragma unroll
        for (int i = 0; i < 16; i++) {
            int lin = tid + 256 * i;
            int r = lin >> 6, c = lin & 63;
            WT[(size_t)(n0 + r) * H + k0 + c] = f2b(t[c][r]);
        }
    } else if (bx < 6144) {
        // ---- LayerNorm of rel_emb -> bf16 ----
        int row = bx - 5632;
        const float4* x4 = (const float4*)(re + (size_t)row * H);
        float4 vv = x4[tid];
        float s = vv.x + vv.y + vv.z + vv.w;
        float s2 = vv.x * vv.x + vv.y * vv.y + vv.z * vv.z + vv.w * vv.w;
        for (int m = 1; m < 64; m <<= 1) {
            s += __shfl_xor(s, m, 64);
            s2 += __shfl_xor(s2, m, 64);
        }
        if ((tid & 63) == 0) { as[tid >> 6] = s; as2[tid >> 6] = s2; }
        __syncthreads();
        s = as[0] + as[1] + as[2] + as[3];
        s2 = as2[0] + as2[1] + as2[2] + as2[3];
        float mu = s * (1.f / 1024.f);
        float var = s2 * (1.f / 1024.f) - mu * mu;
        float rstd = rsqrtf(var + 1e-5f);
        float4 gg = ((const float4*)g)[tid];
        float4 bb = ((const float4*)be)[tid];
        ushort4 r4;
        r4.x = f2b((vv.x - mu) * rstd * gg.x + bb.x);
        r4.y = f2b((vv.y - mu) * rstd * gg.y + bb.y);
        r4.z = f2b((vv.z - mu) * rstd * gg.z + bb.z);
        r4.w = f2b((vv.w - mu) * rstd * gg.w + bb.w);
        ((ushort4*)(reb + (size_t)row * H))[tid] = r4;
    } else {
        // ---- idx table for rel in [-512, 511] (monotone, slope<=1; clamp EXACT) ----
        int i = (bx - 6144) * 256 + tid;
        if (i >= 1024) return;
        int rel = i - 512;
        float fr = (float)rel;
        float abs_pos = (rel < 128 && rel > -128) ? 127.0f : fabsf(fr);
        const float LOGC = 1.3843393262841284f;  // float32(ln(511/128))
        float log_pos = ceilf(logf(abs_pos * (1.0f / 128.0f)) / LOGC * 127.0f) + 128.0f;
        float sgn = (fr > 0.f) ? 1.f : ((fr < 0.f) ? -1.f : 0.f);
        float bf = (abs_pos <= 128.0f) ? fr : log_pos * sgn;
        int ix = (int)bf + 256;
        ix = ix < 0 ? 0 : (ix > 511 ? 511 : ix);
        idxt[i] = (short)ix;
    }
}

// ---------------- 128x128-tile GEMM core ----------------
// Staging via global_load_lds width=16 (m97 ladder step: compiler never auto-emits it).
// Layout math: thread tid's store lands at byte tid*16 of As (unpadded [128][32] u16), so
// HW scatter (wave-uniform base + lane*16) with base = As + 1024*w reproduces the layout.
// MODE 0: bf16 row-major; MODE 1: f32 row-major;
// MODE 2: bf16 VT layout (b*1024+n)*2048 + pi2-permuted s within each 64-block
//         (pi2(j) = (j>>5)*32 + (j&15)*2 + ((j>>4)&1); k_attn's P store and PV MFMA
//          use the same permuted k-order, and MFMA sums over k, so this is exact);
// MODE 3: bf16 head-major ((b*16+h)*2048+m)*64+d
template <int MODE>
__device__ __forceinline__ void gemm2_body(const u16* __restrict__ A,
                                           const u16* __restrict__ Bt,
                                           const float* __restrict__ bias,
                                           void* __restrict__ C, int N, int K) {
    __shared__ __align__(16) u16 As[128 * 32];
    __shared__ __align__(16) u16 Bs[128 * 32];
    int tid = threadIdx.x;
    int lane = tid & 63, w = tid >> 6;
    int ln = lane & 15, quad = lane >> 4;
    int m0 = blockIdx.x * 128, n0 = blockIdx.y * 128;
    int wm = (w >> 1) * 64, wn = (w & 1) * 64;
    float4v acc[4][4];
    float4v zero = {0.f, 0.f, 0.f, 0.f};
#pragma unroll
    for (int mi = 0; mi < 4; mi++)
#pragma unroll
        for (int ni = 0; ni < 4; ni++) acc[mi][ni] = zero;

    int r1 = tid >> 2, o1 = (tid & 3) * 8;
    const u16* ga1 = A + (size_t)(m0 + r1) * K + o1;
    const u16* gb1 = Bt + (size_t)(n0 + r1) * K + o1;
    // wave-uniform LDS bases (lane l lands at base + l*16 bytes = original tid*16 layout)
    u16* asw = &As[w * 512];
    u16* bsw = &Bs[w * 512];
    size_t step2 = (size_t)64 * K;

    for (int k0 = 0; k0 < K; k0 += 32) {
        __syncthreads();
        gload16(ga1 + k0,          asw);
        gload16(ga1 + step2 + k0,  asw + 2048);
        gload16(gb1 + k0,          bsw);
        gload16(gb1 + step2 + k0,  bsw + 2048);
        __syncthreads();
        short8 af[4], bf[4];
#pragma unroll
        for (int mi = 0; mi < 4; mi++)
            af[mi] = *(const short8*)&As[(wm + mi * 16 + ln) * 32 + quad * 8];
#pragma unroll
        for (int ni = 0; ni < 4; ni++)
            bf[ni] = *(const short8*)&Bs[(wn + ni * 16 + ln) * 32 + quad * 8];
#pragma unroll
        for (int mi = 0; mi < 4; mi++)
#pragma unroll
            for (int ni = 0; ni < 4; ni++)
                acc[mi][ni] = MFMA16(af[mi], bf[ni], acc[mi][ni]);
    }

#pragma unroll
    for (int mi = 0; mi < 4; mi++) {
        int row0 = m0 + wm + mi * 16 + quad * 4;
#pragma unroll
        for (int ni = 0; ni < 4; ni++) {
            int col = n0 + wn + ni * 16 + ln;
            float bv = bias[col];
            if (MODE == 0) {
                u16* Cb = (u16*)C;
#pragma unroll
                for (int r = 0; r < 4; r++)
                    Cb[(size_t)(row0 + r) * N + col] = f2b(acc[mi][ni][r] + bv);
            } else if (MODE == 1) {
                float* Cf = (float*)C;
#pragma unroll
                for (int r = 0; r < 4; r++)
                    Cf[(size_t)(row0 + r) * N + col] = acc[mi][ni][r] + bv;
            } else if (MODE == 2) {
                u16* Cb = (u16*)C;
                int bb = row0 >> 11, s = row0 & 2047;
                int base64 = s & ~63, j = s & 63;           // j = mi*16 + quad*4 (j%4==0)
                int p0 = ((j >> 5) << 5) + ((j & 15) << 1) + ((j >> 4) & 1);
                u16* dst = Cb + ((size_t)(bb * 1024 + col)) * 2048 + base64;
#pragma unroll
                for (int r = 0; r < 4; r++)
                    dst[p0 + 2 * r] = f2b(acc[mi][ni][r] + bv);
            } else {
                u16* Cb = (u16*)C;
                int bb = row0 >> 11, s = row0 & 2047;
                int h = col >> 6, d = col & 63;
#pragma unroll
                for (int r = 0; r < 4; r++)
                    Cb[((size_t)(bb * 16 + h) * 2048 + s + r) * 64 + d] = f2b(acc[mi][ni][r] + bv);
            }
        }
    }
}

template <int MODE>
__global__ __launch_bounds__(256) void k_gemm2(const u16* __restrict__ A, const u16* __restrict__ Bt,
                                               const float* __restrict__ bias, void* __restrict__ C,
                                               int N, int K) {
    gemm2_body<MODE>(A, Bt, bias, C, N, K);
}

// Q/K/V projections AND both positional-embedding GEMMs in ONE launch.
// z: 0=Q head-major, 1=K head-major, 2=V transposed+pi2, 3=posk (bx<4), 4=posq (bx<4).
// NOTE: default dispatch already gives A-tile XCD-locality here (XCD = bx%8, A shared
// across y-strides landing on the same XCD), so no swizzle: analyzed r12.
__global__ __launch_bounds__(256) void k_qkvpos(const u16* __restrict__ A,
                                                const u16* __restrict__ W0, const u16* __restrict__ W1,
                                                const u16* __restrict__ W2,
                                                const float* __restrict__ b0, const float* __restrict__ b1,
                                                const float* __restrict__ b2,
                                                u16* __restrict__ Q, u16* __restrict__ K, u16* __restrict__ VT,
                                                const u16* __restrict__ RE,
                                                const u16* __restrict__ W4, const u16* __restrict__ W5,
                                                const float* __restrict__ b4, const float* __restrict__ b5,
                                                u16* __restrict__ PK, u16* __restrict__ PQ) {
    int z = blockIdx.z;
    if (z == 0)      gemm2_body<3>(A, W0, b0, Q, H, H);
    else if (z == 1) gemm2_body<3>(A, W1, b1, K, H, H);
    else if (z == 2) gemm2_body<2>(A, W2, b2, VT, H, H);
    else if (z == 3) { if (blockIdx.x >= 4) return; gemm2_body<0>(RE, W4, b4, PK, H, H); }
    else             { if (blockIdx.x >= 4) return; gemm2_body<0>(RE, W5, b5, PQ, H, H); }
}

// ---------------- both positional score tables, one launch ----------------
// NEW this round: chunked XCD swizzle (T1). Default linear id = bx+16by+64bz gives
// XCD = bx%8 -> every XCD executes all 64 bz values, re-fetching every Q/K panel
// (256KB x 16 bh) and every pos-table slice (128KB x 32) => ~48MB L2-miss traffic vs
// ~16MB unique. Chunked remap gives each XCD bz in [8c,8c+8): 4 bh + 8 panels ~= 2MB,
// fits the 4MB per-XCD L2. Mapping-only: exact.
__global__ __launch_bounds__(256) void k_pos_both(const u16* __restrict__ Qh, const u16* __restrict__ Kh,
                                                  const u16* __restrict__ pk, const u16* __restrict__ pq,
                                                  u16* __restrict__ c2p, u16* __restrict__ p2cK,
                                                  u16* __restrict__ pfar) {
    __shared__ __align__(16) u16 smem[2 * 128 * 72];   // As | Bs
    u16* As = smem;
    u16* Bs = smem + 128 * 72;
    int tid = threadIdx.x;
    int lane = tid & 63, w = tid >> 6;
    int ln = lane & 15, quad = lane >> 4;
    // ---- chunked XCD swizzle over the 4096-block grid (4096 % 8 == 0: bijective) ----
    int id = blockIdx.x + 16 * blockIdx.y + 64 * blockIdx.z;
    int swz = (id & 7) * 512 + (id >> 3);
    int sbx = swz & 15, sby = (swz >> 4) & 3, sbz = swz >> 6;
    int tr = sbz & 1, z = sbz >> 1, h = z & 15;
    int m0 = sbx * 128, n0 = sby * 128;
    const u16* A = (tr ? Kh : Qh) + (size_t)z * S * HD;
    const u16* B = (tr ? pq : pk) + h * 64;
    int sr = tid >> 1, scb = (tid & 1) * 32;
    {
        const u16* ga = A + (size_t)(m0 + sr) * HD + scb;
        const u16* gb = B + (size_t)(n0 + sr) * H + scb;
#pragma unroll
        for (int j = 0; j < 4; j++) {
            *(short8*)&As[sr * 72 + scb + j * 8] = *(const short8*)(ga + j * 8);
            *(short8*)&Bs[sr * 72 + scb + j * 8] = *(const short8*)(gb + j * 8);
        }
    }
    __syncthreads();
    int wm = (w >> 1) * 64, wn = (w & 1) * 64;
    float4v acc[4][4];
    float4v zero = {0.f, 0.f, 0.f, 0.f};
#pragma unroll
    for (int mi = 0; mi < 4; mi++)
#pragma unroll
        for (int ni = 0; ni < 4; ni++) acc[mi][ni] = zero;
#pragma unroll
    for (int c = 0; c < 2; c++) {
        short8 af[4], bf[4];
#pragma unroll
        for (int mi = 0; mi < 4; mi++)
            af[mi] = *(const short8*)&As[(wm + mi * 16 + ln) * 72 + c * 32 + quad * 8];
#pragma unroll
        for (int ni = 0; ni < 4; ni++)
            bf[ni] = *(const short8*)&Bs[(wn + ni * 16 + ln) * 72 + c * 32 + quad * 8];
#pragma unroll
        for (int mi = 0; mi < 4; mi++)
#pragma unroll
            for (int ni = 0; ni < 4; ni++)
                acc[mi][ni] = MFMA16(af[mi], bf[ni], acc[mi][ni]);
    }
    u16* Cp = (tr ? p2cK : c2p) + (size_t)z * S * 512;
#pragma unroll
    for (int mi = 0; mi < 4; mi++) {
        int row0 = m0 + wm + mi * 16 + quad * 4;
#pragma unroll
        for (int ni = 0; ni < 4; ni++) {
            int col = n0 + wn + ni * 16 + ln;
#pragma unroll
            for (int r = 0; r < 4; r++)
                Cp[(size_t)(row0 + r) * 512 + col] = f2b(acc[mi][ni][r] * SC);
        }
    }
    if (tr) {
        // far-column extraction (col 0 lives in n0==0 blocks, col 511 in n0==384 blocks)
        if (n0 == 0 && (w & 1) == 0 && ln == 0) {
            u16* dst = pfar + (size_t)z * 2048 + m0 + wm + quad * 4;
#pragma unroll
            for (int mi = 0; mi < 4; mi++)
#pragma unroll
                for (int r = 0; r < 4; r++)
                    dst[mi * 16 + r] = f2b(acc[mi][0][r] * SC);
        }
        if (n0 == 384 && (w & 1) == 1 && ln == 15) {
            u16* dst = pfar + (size_t)(32 + z) * 2048 + m0 + wm + quad * 4;
#pragma unroll
            for (int mi = 0; mi < 4; mi++)
#pragma unroll
                for (int r = 0; r < 4; r++)
                    dst[mi * 16 + r] = f2b(acc[mi][3][r] * SC);
        }
    }
}

// gather c2p+p2c bias for rows r=0..3 at f=F into 4 named floats (no runtime array idx)
#define GATHER_BIAS(F, B0, B1, B2, B3) do {                                          \
    int ki_ = kk + (F) * 16 + ln;                                                    \
    const u16* pvrow_ = p2cB + (size_t)ki_ * 512;                                    \
    int relb_ = qrow - ki_;                                                          \
    int i0_, i1_, i2_, i3_;                                                          \
    { int rel = relb_;     rel = rel < -512 ? -512 : (rel > 511 ? 511 : rel); i0_ = (int)s_idx1[rel + 512]; } \
    { int rel = relb_ + 1; rel = rel < -512 ? -512 : (rel > 511 ? 511 : rel); i1_ = (int)s_idx1[rel + 512]; } \
    { int rel = relb_ + 2; rel = rel < -512 ? -512 : (rel > 511 ? 511 : rel); i2_ = (int)s_idx1[rel + 512]; } \
    { int rel = relb_ + 3; rel = rel < -512 ? -512 : (rel > 511 ? 511 : rel); i3_ = (int)s_idx1[rel + 512]; } \
    const u32* p32_ = (const u32*)pvrow_;                                            \
    int e_ = i0_ >> 1;                                                               \
    u32 wx_ = p32_[e_], wy_ = p32_[e_ + 1], wz_ = p32_[e_ + 2];                      \
    u64 lov_ = (u64)wx_ | ((u64)wy_ << 32);                                          \
    u64 sft_ = (i0_ & 1) ? ((lov_ >> 16) | ((u64)wz_ << 48)) : lov_;                 \
    u16 c0_ = cvrow[0][i0_], c1_ = cvrow[1][i1_], c2_ = cvrow[2][i2_], c3_ = cvrow[3][i3_]; \
    union { u32 u; float f; } q0_, q1_, q2_, q3_;                                    \
    q0_.u = ((u32)(sft_)) << 16;                                                     \
    q1_.u = ((u32)(sft_ >> ((i1_ - i0_) << 4))) << 16;                               \
    q2_.u = ((u32)(sft_ >> ((i2_ - i0_) << 4))) << 16;                               \
    q3_.u = ((u32)(sft_ >> ((i3_ - i0_) << 4))) << 16;                               \
    B0 = b2f(c0_) + q0_.f;                                                           \
    B1 = b2f(c1_) + q1_.f;                                                           \
    B2 = b2f(c2_) + q2_.f;                                                           \
    B3 = b2f(c3_) + q3_.f;                                                           \
} while (0)

// ---------------- fused attention: K/V tiles staged in LDS (shared by 4 waves) ----------------
// P columns and V columns both live in pi2-permuted k-order (V permuted at VT write time):
// each lane's (f,f+1) P values are ADJACENT -> v_cvt_pk_bf16_f32 + single b32 store.
// XCD-aware chunked block swizzle (r12: FETCH 233->75 MB). BYTE-IDENTICAL to round 12.
template <int SPLIT>
__global__ __launch_bounds__(256, 4) void k_attn(const u16* __restrict__ Qh,
                                                 const u16* __restrict__ Kh,
                                                 const u16* __restrict__ VT,
                                                 const u16* __restrict__ c2p,
                                                 const u16* __restrict__ p2cK,
                                                 const u16* __restrict__ pfar,
                                                 const short* __restrict__ idxTab,
                                                 float* __restrict__ oP,
                                                 float* __restrict__ lP,
                                                 u16* __restrict__ ctx) {
    __shared__ short s_idx1[1024];
    __shared__ __align__(16) u16 p_lds[4][16][72];
    __shared__ __align__(16) u16 Ks[64][72];
    __shared__ __align__(16) u16 Vs[64][72];
    int tid = threadIdx.x;
    for (int i = tid; i < 1024; i += 256) s_idx1[i] = idxTab[i];
    int lane = tid & 63, w = tid >> 6;
    int ln = lane & 15, quad = lane >> 4;
    // ---- XCD-aware bijective swizzle (dispatch-linear id, x fastest) ----
    const int NBX = (SPLIT == 2) ? 64 : 32;
    const int NWG = NBX * 32;
    int bid = blockIdx.x + NBX * blockIdx.y;
    int swz = (bid & 7) * (NWG >> 3) + (bid >> 3);
    int bx = swz % NBX;
    int bh = swz / NBX;
    int half = (SPLIT == 2) ? (bx & 1) : 0;
    int q0 = (SPLIT == 2) ? (bx >> 1) * 64 : bx * 64;
    int b = bh >> 4, h = bh & 15;
    int qs = q0 + w * 16;

    const u16* qptr = Qh + ((size_t)bh * S + qs + ln) * HD + quad * 8;
    short8 aq0 = *(const short8*)(qptr);
    short8 aq1 = *(const short8*)(qptr + 32);

    float4v o[4];
    float4v zero = {0.f, 0.f, 0.f, 0.f};
#pragma unroll
    for (int f = 0; f < 4; f++) o[f] = zero;
    float lrw[4] = {0.f, 0.f, 0.f, 0.f};

    const u16* c2pB = c2p + (size_t)bh * S * 512;
    const u16* p2cB = p2cK + (size_t)bh * S * 512;
    int qrow = qs + quad * 4;

    // c2p row pointers: fixed per thread for the whole kernel (16 q-rows per wave -> L1-hot)
    const u16* cvrow[4];
#pragma unroll
    for (int r = 0; r < 4; r++) cvrow[r] = c2pB + (size_t)(qrow + r) * 512;

    // staging map: thread -> (row sr 0..63, col block sc 0..48 step 16)
    int sr = tid >> 2, sc = (tid & 3) * 16;
    const u16* kstg = Kh + ((size_t)bh * S + sr) * HD + sc;              // + kk*HD per tile
    const u16* vstg = VT + (size_t)(b * 1024 + h * 64 + sr) * S + sc;    // + kk per tile (pi2 order)

    const int NT = S / 64 / SPLIT;
    for (int t = 0; t < NT; t++) {
        int kk = (SPLIT == 2) ? (((t << 1) | half) << 6) : (t << 6);
        // ---- stage K,V tile (all waves cooperate) ----
        short8 kr0 = *(const short8*)(kstg + (size_t)kk * HD);
        short8 kr1 = *(const short8*)(kstg + (size_t)kk * HD + 8);
        short8 vr0 = *(const short8*)(vstg + kk);
        short8 vr1 = *(const short8*)(vstg + kk + 8);
        __syncthreads();
        *(short8*)&Ks[sr][sc] = kr0; *(short8*)&Ks[sr][sc + 8] = kr1;
        *(short8*)&Vs[sr][sc] = vr0; *(short8*)&Vs[sr][sc + 8] = vr1;
        __syncthreads();
        // ---- QK^T from LDS ----
        float4v sa[4];
        __builtin_amdgcn_s_setprio(1);
#pragma unroll
        for (int f = 0; f < 4; f++) {
            short8 b0 = *(const short8*)&Ks[f * 16 + ln][quad * 8];
            short8 b1 = *(const short8*)&Ks[f * 16 + ln][32 + quad * 8];
            float4v tt = zero;
            tt = MFMA16(aq0, b0, tt);
            tt = MFMA16(aq1, b1, tt);
            sa[f] = tt;
        }
        __builtin_amdgcn_s_setprio(0);
        // ---- positional bias + exp2 (fixed max 0) ----
        int rel0 = q0 - kk;
        u32* prow0 = (u32*)&p_lds[w][quad * 4][0];
        if (rel0 >= 569 || rel0 <= -633) {
            // far: idx is constant 0 or 511; pv comes from the pre-extracted column.
            int idx = rel0 > 0 ? 511 : 0;
            const u16* pfb = pfar + (rel0 > 0 ? (size_t)(32 + bh) : (size_t)bh) * 2048 + kk;
            float cvr[4], pvf[4];
#pragma unroll
            for (int r = 0; r < 4; r++)
                cvr[r] = b2f(cvrow[r][idx]);
#pragma unroll
            for (int f = 0; f < 4; f++)
                pvf[f] = b2f(pfb[f * 16 + ln]);
#pragma unroll
            for (int u = 0; u < 2; u++) {
#pragma unroll
                for (int r = 0; r < 4; r++) {
                    float p0 = exp2f(sa[2 * u][r] * SC + cvr[r] + pvf[2 * u]);
                    float p1 = exp2f(sa[2 * u + 1][r] * SC + cvr[r] + pvf[2 * u + 1]);
                    lrw[r] += p0 + p1;
                    u32* prow = prow0 + r * 36;
                    prow[u * 16 + ln] = cvtpk(p0, p1);
                }
            }
        } else {
            // near: f-pair phasing — gather 8 bias floats, then exp2+cvtpk+b32 store.
            // (keeps liveness low: the round-3 bias[4][4] buffer spilled to scratch)
#pragma unroll
            for (int u = 0; u < 2; u++) {
                float ba0, ba1, ba2, ba3, bb0, bb1, bb2, bb3;
                GATHER_BIAS(2 * u, ba0, ba1, ba2, ba3);
                GATHER_BIAS(2 * u + 1, bb0, bb1, bb2, bb3);
                float p0, p1;
                p0 = exp2f(sa[2 * u][0] * SC + ba0);
                p1 = exp2f(sa[2 * u + 1][0] * SC + bb0);
                lrw[0] += p0 + p1;
                prow0[0 * 36 + u * 16 + ln] = cvtpk(p0, p1);
                p0 = exp2f(sa[2 * u][1] * SC + ba1);
                p1 = exp2f(sa[2 * u + 1][1] * SC + bb1);
                lrw[1] += p0 + p1;
                prow0[1 * 36 + u * 16 + ln] = cvtpk(p0, p1);
                p0 = exp2f(sa[2 * u][2] * SC + ba2);
                p1 = exp2f(sa[2 * u + 1][2] * SC + bb2);
                lrw[2] += p0 + p1;
                prow0[2 * 36 + u * 16 + ln] = cvtpk(p0, p1);
                p0 = exp2f(sa[2 * u][3] * SC + ba3);
                p1 = exp2f(sa[2 * u + 1][3] * SC + bb3);
                lrw[3] += p0 + p1;
                prow0[3 * 36 + u * 16 + ln] = cvtpk(p0, p1);
            }
        }
        // ---- PV from LDS (own-wave P slice, no extra barrier; pi2-consistent) ----
        short8 ap0 = *(const short8*)&p_lds[w][ln][quad * 8];
        short8 ap1 = *(const short8*)&p_lds[w][ln][32 + quad * 8];
        __builtin_amdgcn_s_setprio(1);
#pragma unroll
        for (int f = 0; f < 4; f++) {
            short8 v0 = *(const short8*)&Vs[f * 16 + ln][quad * 8];
            short8 v1 = *(const short8*)&Vs[f * 16 + ln][32 + quad * 8];
            o[f] = MFMA16(ap0, v0, o[f]);
            o[f] = MFMA16(ap1, v1, o[f]);
        }
        __builtin_amdgcn_s_setprio(0);
    }
    // ---- single end-of-loop l reduction (within 16-lane quad) ----
#pragma unroll
    for (int r = 0; r < 4; r++) {
        lrw[r] += __shfl_xor(lrw[r], 1, 16);
        lrw[r] += __shfl_xor(lrw[r], 2, 16);
        lrw[r] += __shfl_xor(lrw[r], 4, 16);
        lrw[r] += __shfl_xor(lrw[r], 8, 16);
    }
    if (SPLIT == 1) {
        float inv_l[4];
#pragma unroll
        for (int r = 0; r < 4; r++) inv_l[r] = 1.f / lrw[r];
#pragma unroll
        for (int f = 0; f < 4; f++)
#pragma unroll
            for (int r = 0; r < 4; r++) {
                int qi = qs + quad * 4 + r;
                ctx[(size_t)(b * S + qi) * H + h * 64 + f * 16 + ln] = f2b(o[f][r] * inv_l[r]);
            }
    } else {
        float* oH = oP + (size_t)half * SP_OHALF;
#pragma unroll
        for (int f = 0; f < 4; f++)
#pragma unroll
            for (int r = 0; r < 4; r++) {
                int qi = qs + quad * 4 + r;
                oH[((size_t)bh * S + qi) * 64 + f * 16 + ln] = o[f][r];
            }
        if (ln == 0) {
            float* lH = lP + (size_t)half * SP_LHALF;
#pragma unroll
            for (int r = 0; r < 4; r++)
                lH[(size_t)bh * S + qs + quad * 4 + r] = lrw[r];
        }
    }
}

// ---------------- merge split-K partials -> ctx bf16 ----------------
__global__ __launch_bounds__(256) void k_merge(const float* __restrict__ oP,
                                               const float* __restrict__ lP,
                                               u16* __restrict__ ctx) {
    int t = blockIdx.x * 256 + threadIdx.x;
    int d4 = (t & 15) * 4;
    int h  = (t >> 4) & 15;
    int qq = (t >> 8) & 2047;
    int b  = t >> 19;
    int bh = b * 16 + h;
    size_t base = ((size_t)bh * S + qq) * 64 + d4;
    float4 o0 = *(const float4*)(oP + base);
    float4 o1 = *(const float4*)(oP + SP_OHALF + base);
    float l0 = lP[(size_t)bh * S + qq];
    float l1 = lP[SP_LHALF + (size_t)bh * S + qq];
    float inv = 1.f / (l0 + l1);
    ushort4 r4;
    r4.x = f2b((o0.x + o1.x) * inv);
    r4.y = f2b((o0.y + o1.y) * inv);
    r4.z = f2b((o0.z + o1.z) * inv);
    r4.w = f2b((o0.w + o1.w) * inv);
    *(ushort4*)(ctx + (((size_t)(b * S + qq)) * 16 + h) * 64 + d4) = r4;
}

// ---------------- launch ----------------
extern "C" void kernel_launch(void* const* d_in, const int* in_sizes, int n_in,
                              void* d_out, int out_size, void* d_ws, size_t ws_size,
                              hipStream_t stream) {
    const float* hs  = (const float*)d_in[0];
    const float* Wq  = (const float*)d_in[1];
    const float* bq  = (const float*)d_in[2];
    const float* Wk  = (const float*)d_in[3];
    const float* bk  = (const float*)d_in[4];
    const float* Wv  = (const float*)d_in[5];
    const float* bv  = (const float*)d_in[6];
    const float* Wo  = (const float*)d_in[7];
    const float* bo  = (const float*)d_in[8];
    const float* Wpk = (const float*)d_in[9];
    const float* bpk = (const float*)d_in[10];
    const float* Wpq = (const float*)d_in[11];
    const float* bpq = (const float*)d_in[12];
    const float* rel = (const float*)d_in[13];
    const float* lng = (const float*)d_in[14];
    const float* lnb = (const float*)d_in[15];

    char* ws = (char*)d_ws;
    u16* re_b   = (u16*)(ws + OFF_REB);
    u16* hs_b   = (u16*)(ws + OFF_HSB);
    u16* wt0    = (u16*)(ws + OFF_WT);
    u16* wt1    = (u16*)(ws + OFF_WT + 2097152ull);
    u16* wt2    = (u16*)(ws + OFF_WT + 2ull * 2097152ull);
    u16* wt3    = (u16*)(ws + OFF_WT + 3ull * 2097152ull);
    u16* wt4    = (u16*)(ws + OFF_WT + 4ull * 2097152ull);
    u16* wt5    = (u16*)(ws + OFF_WT + 5ull * 2097152ull);
    u16* Q_b    = (u16*)(ws + OFF_QB);
    u16* K_b    = (u16*)(ws + OFF_KB);
    u16* VT_b   = (u16*)(ws + OFF_VT);
    u16* posk_b = (u16*)(ws + OFF_PKB);
    u16* posq_b = (u16*)(ws + OFF_PQB);
    u16* c2p_b  = (u16*)(ws + OFF_C2P);
    u16* p2cK_b = (u16*)(ws + OFF_P2CK);
    u16* ctx_b  = (u16*)(ws + OFF_CTX);
    short* idx_t = (short*)(ws + OFF_IDX);
    u16* pfar_b = (u16*)(ws + OFF_PF);
    float* oP   = (float*)(ws + OFF_SP);
    float* lP   = (float*)(ws + SP_LBASE);

    dim3 blk(256);
    // fused preprocessing (cast | wt6 | ln | idx) — one launch
    k_pre<<<dim3(6148), blk, 0, stream>>>(hs, hs_b, Wq, Wk, Wv, Wo, Wpk, Wpq,
                                          wt0, wt1, wt2, wt3, wt4, wt5,
                                          rel, lng, lnb, re_b, idx_t);

    // projections + positional-embedding GEMMs — one launch (pos fills idle CUs)
    k_qkvpos<<<dim3(32, 8, 5), blk, 0, stream>>>(hs_b, wt0, wt1, wt2, bq, bk, bv,
                                                 Q_b, K_b, VT_b,
                                                 re_b, wt4, wt5, bpk, bpq, posk_b, posq_b);

    // positional score tables (scale incl. log2e folded in)
    k_pos_both<<<dim3(16, 4, 64), blk, 0, stream>>>(Q_b, K_b, posk_b, posq_b, c2p_b, p2cK_b, pfar_b);

    // fused attention (split-K x2 interleaved when workspace allows)
    if (ws_size >= WS_NEED_SPLIT) {
        k_attn<2><<<dim3(64, 32), blk, 0, stream>>>(Q_b, K_b, VT_b, c2p_b, p2cK_b, pfar_b, idx_t, oP, lP, ctx_b);
        k_merge<<<dim3(4096), blk, 0, stream>>>(oP, lP, ctx_b);
    } else {
        k_attn<1><<<dim3(32, 32), blk, 0, stream>>>(Q_b, K_b, VT_b, c2p_b, p2cK_b, pfar_b, idx_t, oP, lP, ctx_b);
    }

    // output projection (fp32 out)
    k_gemm2<1><<<dim3(32, 8), blk, 0, stream>>>(ctx_b, wt3, bo, d_out, H, H);
}